// Round 1
// baseline (1758.851 us; speedup 1.0000x reference)
//
#include <hip/hip_runtime.h>
#include <hip/hip_bf16.h>
#include <string.h>

typedef __hip_bfloat16 bf16;
typedef __attribute__((ext_vector_type(8))) __bf16 bf16x8;
typedef __attribute__((ext_vector_type(4))) float f32x4;
typedef __attribute__((ext_vector_type(8))) unsigned short u16x8;

#define NN 4096
#define DD 512
#define MM 256
#define ROWS 32768

__device__ __forceinline__ float b2f(bf16 x) { return __bfloat162float(x); }
__device__ __forceinline__ float u2f(unsigned short u) {
  return __uint_as_float(((unsigned int)u) << 16);
}
__device__ __forceinline__ unsigned short f2bu(float v) {
  bf16 h = __float2bfloat16(v);
  return *reinterpret_cast<unsigned short*>(&h);
}
// adaptive input load / output store (f==1 -> float32, f==0 -> bf16)
__device__ __forceinline__ float ldf(const void* p, size_t i, int f) {
  return f ? ((const float*)p)[i] : __bfloat162float(((const bf16*)p)[i]);
}
__device__ __forceinline__ void stf(void* p, size_t i, float v, int f) {
  if (f) ((float*)p)[i] = v;
  else ((bf16*)p)[i] = __float2bfloat16(v);
}

// ---- dtype detection ----
__global__ void detect_kernel(const void* x, int* flag) {
  __shared__ int red[256];
  int tid = threadIdx.x;
  const unsigned short* u = (const unsigned short*)x;
  int local = 0;
  for (int i = 0; i < 32; i++) {
    unsigned short e = (u[tid * 32 + i] >> 7) & 0xFF;
    if (e >= 0xC8) local++;
  }
  red[tid] = local; __syncthreads();
  #pragma unroll
  for (int s = 128; s > 0; s >>= 1) {
    if (tid < s) red[tid] += red[tid + s];
    __syncthreads();
  }
  if (tid == 0) *flag = (red[0] > 32) ? 1 : 0;
}

// ---- block reductions ----
__device__ __forceinline__ float bred_max(float v, float* red) {
  int tid = threadIdx.x;
  red[tid] = v; __syncthreads();
  #pragma unroll
  for (int s = 128; s > 0; s >>= 1) {
    if (tid < s) red[tid] = fmaxf(red[tid], red[tid + s]);
    __syncthreads();
  }
  float r = red[0]; __syncthreads();
  return r;
}
__device__ __forceinline__ float bred_sum(float v, float* red) {
  int tid = threadIdx.x;
  red[tid] = v; __syncthreads();
  #pragma unroll
  for (int s = 128; s > 0; s >>= 1) {
    if (tid < s) red[tid] += red[tid + s];
    __syncthreads();
  }
  float r = red[0]; __syncthreads();
  return r;
}

// ---- LayerNorm stats ----
__global__ void ln_stats_kernel(const void* __restrict__ x, float* __restrict__ stats,
                                const int* dflag) {
  __shared__ float red[256];
  int f = *dflag;
  int row = blockIdx.x, tid = threadIdx.x;
  size_t base = (size_t)row * DD;
  float v0 = ldf(x, base + tid, f);
  float v1 = ldf(x, base + tid + 256, f);
  float mean = bred_sum(v0 + v1, red) * (1.0f / DD);
  float d0 = v0 - mean, d1 = v1 - mean;
  float var = bred_sum(d0 * d0 + d1 * d1, red) * (1.0f / DD);
  if (tid == 0) {
    stats[row * 2] = mean;
    stats[row * 2 + 1] = rsqrtf(var + 1e-5f);
  }
}

// ---- generic transpose -> bf16 out: out[b][c][r] = in[b][r][c] ----
__global__ void transpose_kernel(const void* __restrict__ in, bf16* __restrict__ out,
                                 int R, int Cc, long sIn, long sOut,
                                 const int* dflag, int ovr) {
  int f = (ovr >= 0) ? ovr : *dflag;
  size_t o = (size_t)blockIdx.x * 256 + threadIdx.x;
  size_t per = (size_t)R * Cc;
  size_t b = o / per, rem = o % per;
  size_t c = rem / R, r = rem % R;
  out[b * sOut + c * (size_t)R + r] = __float2bfloat16(ldf(in, b * sIn + r * (size_t)Cc + c, f));
}

// ---- QKV GEMM: MFMA, LN fused on A-stage, scatter epilogue ----
__global__ __launch_bounds__(256) void gemm_qkv(
    const void* __restrict__ x, const float* __restrict__ stats,
    const void* __restrict__ g, const void* __restrict__ bb,
    const bf16* __restrict__ wT,  // [768][512]
    bf16* __restrict__ q, bf16* __restrict__ k, bf16* __restrict__ v,
    const int* __restrict__ dflag) {
  __shared__ __align__(16) unsigned short As[128][40];
  __shared__ __align__(16) unsigned short Bs[128][40];
  int f = *dflag;
  int tid = threadIdx.x;
  int m0 = blockIdx.x * 128, n0 = blockIdx.y * 128;
  int sr = tid >> 1, sh = (tid & 1) * 16;
  int wave = tid >> 6, lane = tid & 63;
  int wm = (wave & 1) * 64, wn = (wave >> 1) * 64;
  int l15 = lane & 15, quad = lane >> 4;
  f32x4 acc[4][4] = {};
  for (int k0 = 0; k0 < 512; k0 += 32) {
    {
      int r = m0 + sr;
      float mu = stats[r * 2], rs = stats[r * 2 + 1];
      #pragma unroll
      for (int e = 0; e < 16; e++) {
        int c = k0 + sh + e;
        float xv = ldf(x, (size_t)r * DD + c, f);
        As[sr][sh + e] = f2bu((xv - mu) * rs * ldf(g, c, f) + ldf(bb, c, f));
      }
    }
    {
      const bf16* src = wT + (size_t)(n0 + sr) * 512 + k0 + sh;
      *(u16x8*)&Bs[sr][sh] = *(const u16x8*)src;
      *(u16x8*)&Bs[sr][sh + 8] = *(const u16x8*)(src + 8);
    }
    __syncthreads();
    bf16x8 af[4], bfr[4];
    #pragma unroll
    for (int i = 0; i < 4; i++) af[i] = *(const bf16x8*)&As[wm + i * 16 + l15][quad * 8];
    #pragma unroll
    for (int j = 0; j < 4; j++) bfr[j] = *(const bf16x8*)&Bs[wn + j * 16 + l15][quad * 8];
    #pragma unroll
    for (int i = 0; i < 4; i++)
      #pragma unroll
      for (int j = 0; j < 4; j++)
        acc[i][j] = __builtin_amdgcn_mfma_f32_16x16x32_bf16(af[i], bfr[j], acc[i][j], 0, 0, 0);
    __syncthreads();
  }
  #pragma unroll
  for (int i = 0; i < 4; i++)
    #pragma unroll
    for (int j = 0; j < 4; j++)
      #pragma unroll
      for (int reg = 0; reg < 4; reg++) {
        int row = m0 + wm + i * 16 + quad * 4 + reg;
        int c = n0 + wn + j * 16 + l15;
        int which = c >> 8, within = c & 255, h = within >> 6, d = within & 63;
        int b_ = row >> 12, n = row & 4095;
        size_t idx = ((size_t)(b_ * 4 + h) * NN + n) * 64 + d;
        float val = acc[i][j][reg];
        if (which == 0) q[idx] = __float2bfloat16(val * 0.125f);
        else if (which == 1) k[idx] = __float2bfloat16(val);
        else v[idx] = __float2bfloat16(val);
      }
}

// ---- generic batched MFMA GEMM: C = A[M x K] @ Bt[N x K]^T ----
// modes: 0=f32 store, 1=bf16 store, 2=f32 atomicAdd (split-K), 3=bias+residual+dtype store
__global__ __launch_bounds__(256) void gemm_bt(
    const bf16* __restrict__ A, long ldA, long sA,
    const bf16* __restrict__ Bt, long ldB, long sB,
    void* __restrict__ C, long ldC, long sC,
    int N, int kLen, int nTiles, int mode,
    const void* __restrict__ bias, const void* __restrict__ resid,
    const int* __restrict__ dflag) {
  __shared__ __align__(16) unsigned short As[128][40];
  __shared__ __align__(16) unsigned short Bs[128][40];
  int tid = threadIdx.x;
  int b = blockIdx.x;
  int m0 = blockIdx.y * 128;
  int nt = blockIdx.z % nTiles, ks = blockIdx.z / nTiles;
  int n0 = nt * 128;
  long k0b = (long)ks * kLen;
  const bf16* Ab = A + (size_t)b * sA;
  const bf16* Bb = Bt + (size_t)b * sB;
  int sr = tid >> 1, sh = (tid & 1) * 16;
  int wave = tid >> 6, lane = tid & 63;
  int wm = (wave & 1) * 64, wn = (wave >> 1) * 64;
  int l15 = lane & 15, quad = lane >> 4;
  f32x4 acc[4][4] = {};
  for (int kc = 0; kc < kLen; kc += 32) {
    long k0 = k0b + kc;
    {
      const bf16* src = Ab + (size_t)(m0 + sr) * ldA + k0 + sh;
      *(u16x8*)&As[sr][sh] = *(const u16x8*)src;
      *(u16x8*)&As[sr][sh + 8] = *(const u16x8*)(src + 8);
    }
    if (n0 + sr < N) {
      const bf16* src = Bb + (size_t)(n0 + sr) * ldB + k0 + sh;
      *(u16x8*)&Bs[sr][sh] = *(const u16x8*)src;
      *(u16x8*)&Bs[sr][sh + 8] = *(const u16x8*)(src + 8);
    } else {
      u16x8 z = {};
      *(u16x8*)&Bs[sr][sh] = z;
      *(u16x8*)&Bs[sr][sh + 8] = z;
    }
    __syncthreads();
    bf16x8 af[4], bfr[4];
    #pragma unroll
    for (int i = 0; i < 4; i++) af[i] = *(const bf16x8*)&As[wm + i * 16 + l15][quad * 8];
    #pragma unroll
    for (int j = 0; j < 4; j++) bfr[j] = *(const bf16x8*)&Bs[wn + j * 16 + l15][quad * 8];
    #pragma unroll
    for (int i = 0; i < 4; i++)
      #pragma unroll
      for (int j = 0; j < 4; j++)
        acc[i][j] = __builtin_amdgcn_mfma_f32_16x16x32_bf16(af[i], bfr[j], acc[i][j], 0, 0, 0);
    __syncthreads();
  }
  int f = (mode == 3) ? *dflag : 0;
  #pragma unroll
  for (int i = 0; i < 4; i++)
    #pragma unroll
    for (int j = 0; j < 4; j++)
      #pragma unroll
      for (int reg = 0; reg < 4; reg++) {
        int row = m0 + wm + i * 16 + quad * 4 + reg;
        int col = n0 + wn + j * 16 + l15;
        if (col < N) {
          float val = acc[i][j][reg];
          size_t off = (size_t)row * ldC + col;
          if (mode == 0) (((float*)C) + (size_t)b * sC)[off] = val;
          else if (mode == 1) (((bf16*)C) + (size_t)b * sC)[off] = __float2bfloat16(val);
          else if (mode == 2) atomicAdd(((float*)C) + (size_t)b * sC + off, val);
          else {
            val += ldf(bias, col, f) + ldf(resid, off, f);
            stf(C, off, val, f);
          }
        }
      }
}

// ---- landmark means: bf16 src -> f32 dst (for a2/pinv) AND bf16 dst (for MFMA) ----
__global__ void landmark_kernel(const bf16* __restrict__ src, float* __restrict__ dstf,
                                bf16* __restrict__ dstb) {
  int idx = blockIdx.x * 256 + threadIdx.x;  // 524288
  int d = idx & 63, j = (idx >> 6) & 255, bh = idx >> 14;
  const bf16* s = src + ((size_t)bh * NN + j * 16) * 64 + d;
  float a = 0;
  #pragma unroll
  for (int i = 0; i < 16; i++) a += b2f(s[i * 64]);
  a *= (1.0f / 16);
  dstf[idx] = a;
  dstb[idx] = __float2bfloat16(a);
}

// ---- a2 = softmax(ql @ kl^T) f32, f32 inputs (pinv-sensitive path) ----
__global__ void a2_kernel(const float* __restrict__ ql, const float* __restrict__ kl,
                          float* __restrict__ a2) {
  __shared__ float qs[64];
  __shared__ float red[256];
  int bh = blockIdx.x >> 8, i = blockIdx.x & 255, tid = threadIdx.x;
  if (tid < 64) qs[tid] = ql[((size_t)bh * MM + i) * 64 + tid];
  __syncthreads();
  const float* kr = kl + ((size_t)bh * MM + tid) * 64;
  float s = 0;
  #pragma unroll
  for (int d = 0; d < 64; d++) s += qs[d] * kr[d];
  float mx = bred_max(s, red);
  float e = __expf(s - mx);
  float sm = bred_sum(e, red);
  a2[((size_t)bh * MM + i) * MM + tid] = e / sm;
}

__global__ void a2_maxsum(const float* __restrict__ a2, float* __restrict__ gmax) {
  __shared__ float red[256];
  int tid = threadIdx.x, id = blockIdx.x;
  if (id < 8192) {
    int bh = id >> 8, i = id & 255;
    float tot = bred_sum(fabsf(a2[((size_t)bh * MM + i) * MM + tid]), red);
    if (tid == 0) atomicMax((int*)gmax, __float_as_int(tot));
  } else {
    id -= 8192;
    int bh = id >> 8, j = id & 255;
    float tot = bred_sum(fabsf(a2[((size_t)bh * MM + tid) * MM + j]), red);
    if (tid == 0) atomicMax((int*)gmax + 1, __float_as_int(tot));
  }
}

__global__ void zinit_kernel(const float* __restrict__ a2, const float* __restrict__ gmax,
                             float* __restrict__ z) {
  int idx = blockIdx.x * 256 + threadIdx.x;
  int j = idx & 255, i = (idx >> 8) & 255, bh = idx >> 16;
  float scale = 1.0f / (gmax[0] * gmax[1]);
  z[idx] = a2[((size_t)bh * MM + j) * MM + i] * scale;
}

// ---- fp32 batched 64x64-tile GEMM: C = alpha*I + beta*(A @ (gbA*I + gbB*B)) ----
// B-tile staging: 16 k-rows x 64 cols at col0 (rb=tid>>4, c4=(tid&15)*4).
// NOTE: round-6's "Nn-guard" indexing here was an LDS-OOB bug; do not reintroduce.
__global__ __launch_bounds__(256) void bmm64(
    const float* __restrict__ A, const float* __restrict__ B_,
    float* __restrict__ C,
    int Nn, int Kk, long sA, long sB, long sC,
    float alpha, float beta, float gbA, float gbB) {
  __shared__ __align__(16) float As[16][68];
  __shared__ __align__(16) float Bs[16][68];
  int bh = blockIdx.x;
  int row0 = blockIdx.y * 64, col0 = blockIdx.z * 64;
  const float* Ab = A + (size_t)bh * sA;
  const float* Bb = B_ + (size_t)bh * sB;
  int tid = threadIdx.x, tx = tid & 15, ty = tid >> 4;
  float c[4][4] = {};
  for (int k0 = 0; k0 < Kk; k0 += 16) {
    {
      int r = tid >> 2, k4 = (tid & 3) * 4;
      const float* src = Ab + (size_t)(row0 + r) * Kk + k0 + k4;
      float4 av = *(const float4*)src;
      As[k4 + 0][r] = av.x; As[k4 + 1][r] = av.y; As[k4 + 2][r] = av.z; As[k4 + 3][r] = av.w;
    }
    {
      int rb = tid >> 4, c4 = (tid & 15) * 4;
      const float* src = Bb + (size_t)(k0 + rb) * Nn + col0 + c4;
      float4 bv = *(const float4*)src;
      bv.x *= gbB; bv.y *= gbB; bv.z *= gbB; bv.w *= gbB;
      int kk = k0 + rb;
      if (kk == col0 + c4 + 0) bv.x += gbA;
      if (kk == col0 + c4 + 1) bv.y += gbA;
      if (kk == col0 + c4 + 2) bv.z += gbA;
      if (kk == col0 + c4 + 3) bv.w += gbA;
      *(float4*)&Bs[rb][c4] = bv;
    }
    __syncthreads();
    #pragma unroll
    for (int kk = 0; kk < 16; kk++) {
      float4 a = *(const float4*)&As[kk][ty * 4];
      float4 b = *(const float4*)&Bs[kk][tx * 4];
      float ar[4] = {a.x, a.y, a.z, a.w};
      float br[4] = {b.x, b.y, b.z, b.w};
      #pragma unroll
      for (int i = 0; i < 4; i++)
        #pragma unroll
        for (int j = 0; j < 4; j++) c[i][j] += ar[i] * br[j];
    }
    __syncthreads();
  }
  #pragma unroll
  for (int i = 0; i < 4; i++)
    #pragma unroll
    for (int j = 0; j < 4; j++) {
      int r = row0 + ty * 4 + i, cc = col0 + tx * 4 + j;
      C[(size_t)bh * sC + (size_t)r * Nn + cc] = alpha * (r == cc) + beta * c[i][j];
    }
}

// ---- softmax over rows of 4096 (bf16 in -> bf16 out) ----
__global__ void softmax3_kernel(const bf16* __restrict__ S, bf16* __restrict__ P) {
  __shared__ float red[256];
  int row = blockIdx.x, tid = threadIdx.x;
  const bf16* sr = S + (size_t)row * 4096 + tid * 16;
  u16x8 v0 = *(const u16x8*)sr;
  u16x8 v1 = *(const u16x8*)(sr + 8);
  float vals[16];
  #pragma unroll
  for (int e = 0; e < 8; e++) { vals[e] = u2f(v0[e]); vals[e + 8] = u2f(v1[e]); }
  float lm = -1e30f;
  #pragma unroll
  for (int e = 0; e < 16; e++) lm = fmaxf(lm, vals[e]);
  float mx = bred_max(lm, red);
  float ls = 0;
  #pragma unroll
  for (int e = 0; e < 16; e++) { vals[e] = __expf(vals[e] - mx); ls += vals[e]; }
  float inv = 1.0f / bred_sum(ls, red);
  bf16* pr = P + (size_t)row * 4096 + tid * 16;
  #pragma unroll
  for (int e = 0; e < 16; e++) pr[e] = __float2bfloat16(vals[e] * inv);
}

// ---- fused sim1 + softmax -> P1 f32 [4][4096][256] ----
__global__ __launch_bounds__(256) void attn1_kernel(
    const bf16* __restrict__ q, const bf16* __restrict__ klbf,
    float* __restrict__ P1, int bh0) {
  __shared__ __align__(16) unsigned short Qs[64][72];
  __shared__ __align__(16) unsigned short Ks[256][72];
  __shared__ float redm[4][64];
  __shared__ float reds[4][64];
  int tid = threadIdx.x;
  int bhl = blockIdx.y, bh = bh0 + bhl;
  int n0 = blockIdx.x * 64;
  const bf16* qb = q + ((size_t)bh * NN + n0) * 64;
  const bf16* kb = klbf + (size_t)bh * 16384;
  {
    int r = tid >> 2, s = (tid & 3) * 16;
    *(u16x8*)&Qs[r][s] = *(const u16x8*)(qb + (size_t)r * 64 + s);
    *(u16x8*)&Qs[r][s + 8] = *(const u16x8*)(qb + (size_t)r * 64 + s + 8);
  }
  {
    const bf16* src = kb + (size_t)tid * 64;
    #pragma unroll
    for (int s8 = 0; s8 < 8; s8++) *(u16x8*)&Ks[tid][s8 * 8] = *(const u16x8*)(src + s8 * 8);
  }
  __syncthreads();
  int wave = tid >> 6, lane = tid & 63, l15 = lane & 15, quad = lane >> 4;
  f32x4 acc[4][4] = {};
  #pragma unroll
  for (int kc = 0; kc < 64; kc += 32) {
    bf16x8 af[4], bfr[4];
    #pragma unroll
    for (int i = 0; i < 4; i++) af[i] = *(const bf16x8*)&Qs[i * 16 + l15][kc + quad * 8];
    #pragma unroll
    for (int j = 0; j < 4; j++) bfr[j] = *(const bf16x8*)&Ks[wave * 64 + j * 16 + l15][kc + quad * 8];
    #pragma unroll
    for (int i = 0; i < 4; i++)
      #pragma unroll
      for (int j = 0; j < 4; j++)
        acc[i][j] = __builtin_amdgcn_mfma_f32_16x16x32_bf16(af[i], bfr[j], acc[i][j], 0, 0, 0);
  }
  float lm[4][4], ls[4][4], rinv[4][4];
  #pragma unroll
  for (int i = 0; i < 4; i++)
    #pragma unroll
    for (int reg = 0; reg < 4; reg++) {
      float m = acc[i][0][reg];
      m = fmaxf(m, acc[i][1][reg]); m = fmaxf(m, acc[i][2][reg]); m = fmaxf(m, acc[i][3][reg]);
      lm[i][reg] = m;
    }
  #pragma unroll
  for (int off = 1; off < 16; off <<= 1)
    #pragma unroll
    for (int i = 0; i < 4; i++)
      #pragma unroll
      for (int reg = 0; reg < 4; reg++) lm[i][reg] = fmaxf(lm[i][reg], __shfl_xor(lm[i][reg], off));
  if (l15 == 0)
    #pragma unroll
    for (int i = 0; i < 4; i++)
      #pragma unroll
      for (int reg = 0; reg < 4; reg++) redm[wave][i * 16 + quad * 4 + reg] = lm[i][reg];
  __syncthreads();
  #pragma unroll
  for (int i = 0; i < 4; i++)
    #pragma unroll
    for (int reg = 0; reg < 4; reg++) {
      int r = i * 16 + quad * 4 + reg;
      rinv[i][reg] = fmaxf(fmaxf(redm[0][r], redm[1][r]), fmaxf(redm[2][r], redm[3][r]));
      ls[i][reg] = 0;
    }
  #pragma unroll
  for (int i = 0; i < 4; i++)
    #pragma unroll
    for (int j = 0; j < 4; j++)
      #pragma unroll
      for (int reg = 0; reg < 4; reg++) {
        float e = __expf(acc[i][j][reg] - rinv[i][reg]);
        acc[i][j][reg] = e;
        ls[i][reg] += e;
      }
  #pragma unroll
  for (int off = 1; off < 16; off <<= 1)
    #pragma unroll
    for (int i = 0; i < 4; i++)
      #pragma unroll
      for (int reg = 0; reg < 4; reg++) ls[i][reg] += __shfl_xor(ls[i][reg], off);
  if (l15 == 0)
    #pragma unroll
    for (int i = 0; i < 4; i++)
      #pragma unroll
      for (int reg = 0; reg < 4; reg++) reds[wave][i * 16 + quad * 4 + reg] = ls[i][reg];
  __syncthreads();
  #pragma unroll
  for (int i = 0; i < 4; i++)
    #pragma unroll
    for (int reg = 0; reg < 4; reg++) {
      int r = i * 16 + quad * 4 + reg;
      rinv[i][reg] = 1.0f / (reds[0][r] + reds[1][r] + reds[2][r] + reds[3][r]);
    }
  float* Pb = P1 + ((size_t)bhl * NN + n0) * 256;
  #pragma unroll
  for (int i = 0; i < 4; i++)
    #pragma unroll
    for (int j = 0; j < 4; j++)
      #pragma unroll
      for (int reg = 0; reg < 4; reg++) {
        int r = i * 16 + quad * 4 + reg;
        int col = wave * 64 + j * 16 + l15;
        Pb[(size_t)r * 256 + col] = acc[i][j][reg] * rinv[i][reg];
      }
}

// ---- depthwise conv (33) residual add: y = p1f32 + conv(v), 4-bh chunk ----
__global__ __launch_bounds__(256) void conv_add_kernel(
    const float* __restrict__ p1, const bf16* __restrict__ v,
    const void* __restrict__ wres, bf16* __restrict__ y, const int* __restrict__ dflag,
    int bh0) {
  __shared__ __align__(16) unsigned short Vs[96][64];
  int f = *dflag;
  int tid = threadIdx.x;
  int bhl = blockIdx.y, bh = bh0 + bhl;
  int n0 = blockIdx.x * 64;
  int h = bh & 3, b_ = bh >> 2;
  const bf16* vb = v + (size_t)bh * (NN * 64);
  for (int rr = tid; rr < 384; rr += 256) {
    int r = rr >> 2, s = (rr & 3) * 16;
    int n = n0 - 16 + r;
    if (n >= 0 && n < NN) {
      *(u16x8*)&Vs[r][s] = *(const u16x8*)(vb + (size_t)n * 64 + s);
      *(u16x8*)&Vs[r][s + 8] = *(const u16x8*)(vb + (size_t)n * 64 + s + 8);
    } else {
      u16x8 z = {};
      *(u16x8*)&Vs[r][s] = z; *(u16x8*)&Vs[r][s + 8] = z;
    }
  }
  float w33[33];
  #pragma unroll
  for (int kk = 0; kk < 33; kk++) w33[kk] = ldf(wres, h * 33 + kk, f);
  __syncthreads();
  int d = tid & 63, rb = tid >> 6;
  for (int ii = 0; ii < 16; ii++) {
    int nl = ii * 4 + rb;
    float cv = 0;
    #pragma unroll
    for (int kk = 0; kk < 33; kk++) cv += w33[kk] * u2f(Vs[nl + kk][d]);
    int n = n0 + nl;
    float pv = p1[((size_t)bhl * NN + n) * 64 + d];
    y[((size_t)b_ * NN + n) * 256 + h * 64 + d] = __float2bfloat16(pv + cv);
  }
}

extern "C" void kernel_launch(void* const* d_in, const int* in_sizes, int n_in,
                              void* d_out, int out_size, void* d_ws, size_t ws_size,
                              hipStream_t stream) {
  const void* x     = d_in[0];
  const void* ln_g  = d_in[1];
  const void* ln_b  = d_in[2];
  const void* w_qkv = d_in[3];
  const void* w_out = d_in[4];
  const void* b_out = d_in[5];
  const void* w_res = d_in[6];

  // ---- ws layout (~67.4 MiB; round-4 proved >= ~81 MiB available) ----
  float* ws    = (float*)d_ws;
  float* gmax  = ws;                                   // 2 f
  int*   dflag = (int*)(ws + 2);                       // 1 int
  float* stats = ws + 256;                             // 65536 f
  bf16*  woutT = (bf16*)(stats + 65536);               // 131072 bf16
  float* qlf   = (float*)(stats + 65536 + 65536);      // 524288 f
  float* klf   = qlf + 524288;                         // 524288 f
  bf16*  qlbf  = (bf16*)(klf + 524288);                // 524288 bf16
  bf16*  klbf  = qlbf + 524288;                        // 524288 bf16
  float* a3v   = (float*)(klbf + 524288);              // 524288 f
  float* Wm    = a3v + 524288;                         // 524288 f
  float* a2    = Wm + 524288;                          // 2097152 f (vT scratch alias)
  bf16*  q     = (bf16*)(a2 + 2097152);                // 8388608 bf16
  bf16*  k     = q + 8388608;                          // 8388608 bf16 (y alias)
  bf16*  v     = k + 8388608;                          // 8388608 bf16
  bf16*  y     = k;                                    // alias (k dead after sim3)
  bf16*  vTbuf = (bf16*)a2;                            // 4 MiB chunk scratch in a2 region

  // ---- d_out scratch (<= 32 MiB at all times) ----
  char* dob = (char*)d_out;
  bf16* wqkvT = (bf16*)dob;                            // phase A
  bf16* S3    = (bf16*)dob;                            // 16 MiB
  bf16* P3    = (bf16*)(dob + (16u << 20));            // 16 MiB
  float* W0   = (float*)dob;                           // pinv: 4 x 8 MiB
  float* W1   = (float*)(dob + (8u << 20));
  float* W2   = (float*)(dob + (16u << 20));
  float* W3   = (float*)(dob + (24u << 20));
  float* P1   = (float*)dob;                           // 16 MiB (4 bh chunk, f32)
  float* p1f  = (float*)(dob + (16u << 20));           // 4 MiB  (4 bh chunk, f32)

  detect_kernel<<<1, 256, 0, stream>>>(x, dflag);
  hipMemsetAsync(gmax, 0, 2 * sizeof(float), stream);
  ln_stats_kernel<<<ROWS, 256, 0, stream>>>(x, stats, dflag);

  // weight transposes
  transpose_kernel<<<1536, 256, 0, stream>>>(w_qkv, wqkvT, 512, 768, 0, 0, dflag, -1);
  transpose_kernel<<<512, 256, 0, stream>>>(w_out, woutT, 256, 512, 0, 0, dflag, -1);

  // QKV (LN fused)
  gemm_qkv<<<dim3(256, 6), 256, 0, stream>>>(x, stats, ln_g, ln_b, wqkvT, q, k, v, dflag);

  // landmarks (f32 + bf16)
  landmark_kernel<<<2048, 256, 0, stream>>>(q, qlf, qlbf);
  landmark_kernel<<<2048, 256, 0, stream>>>(k, klf, klbf);

  // sim3 -> softmax -> @v (4 chunks of 8 bh), a3v via split-K f32 atomics
  hipMemsetAsync(a3v, 0, 524288 * sizeof(float), stream);
  for (int c = 0; c < 4; c++) {
    transpose_kernel<<<8192, 256, 0, stream>>>(v + (size_t)c * 8 * 262144, vTbuf,
                                               4096, 64, 262144, 262144, dflag, 0);
    gemm_bt<<<dim3(8, 2, 32), 256, 0, stream>>>(
        qlbf + (size_t)c * 8 * 16384, 64, 16384,
        k + (size_t)c * 8 * 262144, 64, 262144,
        S3, 4096, 1048576, 4096, 64, 32, 1, nullptr, nullptr, dflag);
    softmax3_kernel<<<2048, 256, 0, stream>>>(S3, P3);
    gemm_bt<<<dim3(8, 2, 16), 256, 0, stream>>>(
        P3, 4096, 1048576, vTbuf, 4096, 262144,
        a3v + (size_t)c * 131072, 64, 16384, 64, 256, 1, 2, nullptr, nullptr, dflag);
  }

  // a2 path (f32 landmarks) + pinv in d_out
  a2_kernel<<<8192, 256, 0, stream>>>(qlf, klf, a2);
  a2_maxsum<<<16384, 256, 0, stream>>>(a2, gmax);
  zinit_kernel<<<8192, 256, 0, stream>>>(a2, gmax, W0);

  float* zi = W0; float* f1 = W1; float* f2 = W2; float* f3 = W3;
  for (int it = 0; it < 6; it++) {
    bmm64<<<dim3(32, 4, 4), 256, 0, stream>>>(a2, zi, f1, 256, 256, 65536, 65536, 65536, 0.f, 1.f, 0.f, 1.f);
    bmm64<<<dim3(32, 4, 4), 256, 0, stream>>>(f1, f1, f2, 256, 256, 65536, 65536, 65536, 15.f, -1.f, 7.f, -1.f);
    bmm64<<<dim3(32, 4, 4), 256, 0, stream>>>(f1, f2, f3, 256, 256, 65536, 65536, 65536, 13.f, -1.f, 0.f, 1.f);
    bmm64<<<dim3(32, 4, 4), 256, 0, stream>>>(zi, f3, f2, 256, 256, 65536, 65536, 65536, 0.f, 0.25f, 0.f, 1.f);
    float* nzi = f2; f2 = f1; f1 = zi; zi = nzi;
  }

  // Wm = z6 @ a3v -> f32 in ws (before d_out reuse)
  bmm64<<<dim3(32, 4, 1), 256, 0, stream>>>(zi, a3v, Wm, 64, 256, 65536, 16384, 16384, 0.f, 1.f, 0.f, 1.f);

  // a1 softmax (f32 P1) + f32 PV1 + conv residual, 8 chunks of 4 bh
  for (int c = 0; c < 8; c++) {
    attn1_kernel<<<dim3(64, 4), 256, 0, stream>>>(q, klbf, P1, c * 4);
    bmm64<<<dim3(4, 64, 1), 256, 0, stream>>>(
        P1, Wm + (size_t)c * 4 * 16384, p1f,
        64, 256, 1048576, 16384, 262144, 0.f, 1.f, 0.f, 1.f);
    conv_add_kernel<<<dim3(64, 4), 256, 0, stream>>>(p1f, v, w_res, y, dflag, c * 4);
  }

  // out = y @ w_out + b_out + x -> d_out (dtype-adaptive)
  gemm_bt<<<dim3(1, 256, 4), 256, 0, stream>>>(
      y, 256, 0, woutT, 256, 0,
      d_out, 512, 0, 512, 256, 4, 3, b_out, x, dflag);
}

// Round 2
// 1552.560 us; speedup vs baseline: 1.1329x; 1.1329x over previous
//
#include <hip/hip_runtime.h>
#include <hip/hip_bf16.h>
#include <string.h>

typedef __hip_bfloat16 bf16;
typedef __attribute__((ext_vector_type(8))) __bf16 bf16x8;
typedef __attribute__((ext_vector_type(4))) float f32x4;
typedef __attribute__((ext_vector_type(8))) unsigned short u16x8;

#define NN 4096
#define DD 512
#define MM 256
#define ROWS 32768

__device__ __forceinline__ float b2f(bf16 x) { return __bfloat162float(x); }
__device__ __forceinline__ float u2f(unsigned short u) {
  return __uint_as_float(((unsigned int)u) << 16);
}
__device__ __forceinline__ unsigned short f2bu(float v) {
  bf16 h = __float2bfloat16(v);
  return *reinterpret_cast<unsigned short*>(&h);
}
// adaptive input load / output store (f==1 -> float32, f==0 -> bf16)
__device__ __forceinline__ float ldf(const void* p, size_t i, int f) {
  return f ? ((const float*)p)[i] : __bfloat162float(((const bf16*)p)[i]);
}
__device__ __forceinline__ void stf(void* p, size_t i, float v, int f) {
  if (f) ((float*)p)[i] = v;
  else ((bf16*)p)[i] = __float2bfloat16(v);
}

// ---- dtype detection ----
__global__ void detect_kernel(const void* x, int* flag) {
  __shared__ int red[256];
  int tid = threadIdx.x;
  const unsigned short* u = (const unsigned short*)x;
  int local = 0;
  for (int i = 0; i < 32; i++) {
    unsigned short e = (u[tid * 32 + i] >> 7) & 0xFF;
    if (e >= 0xC8) local++;
  }
  red[tid] = local; __syncthreads();
  #pragma unroll
  for (int s = 128; s > 0; s >>= 1) {
    if (tid < s) red[tid] += red[tid + s];
    __syncthreads();
  }
  if (tid == 0) *flag = (red[0] > 32) ? 1 : 0;
}

// ---- block reductions ----
__device__ __forceinline__ float bred_max(float v, float* red) {
  int tid = threadIdx.x;
  red[tid] = v; __syncthreads();
  #pragma unroll
  for (int s = 128; s > 0; s >>= 1) {
    if (tid < s) red[tid] = fmaxf(red[tid], red[tid + s]);
    __syncthreads();
  }
  float r = red[0]; __syncthreads();
  return r;
}
__device__ __forceinline__ float bred_sum(float v, float* red) {
  int tid = threadIdx.x;
  red[tid] = v; __syncthreads();
  #pragma unroll
  for (int s = 128; s > 0; s >>= 1) {
    if (tid < s) red[tid] += red[tid + s];
    __syncthreads();
  }
  float r = red[0]; __syncthreads();
  return r;
}

// ---- LayerNorm stats ----
__global__ void ln_stats_kernel(const void* __restrict__ x, float* __restrict__ stats,
                                const int* dflag) {
  __shared__ float red[256];
  int f = *dflag;
  int row = blockIdx.x, tid = threadIdx.x;
  size_t base = (size_t)row * DD;
  float v0 = ldf(x, base + tid, f);
  float v1 = ldf(x, base + tid + 256, f);
  float mean = bred_sum(v0 + v1, red) * (1.0f / DD);
  float d0 = v0 - mean, d1 = v1 - mean;
  float var = bred_sum(d0 * d0 + d1 * d1, red) * (1.0f / DD);
  if (tid == 0) {
    stats[row * 2] = mean;
    stats[row * 2 + 1] = rsqrtf(var + 1e-5f);
  }
}

// ---- generic transpose -> bf16 out: out[b][c][r] = in[b][r][c] ----
__global__ void transpose_kernel(const void* __restrict__ in, bf16* __restrict__ out,
                                 int R, int Cc, long sIn, long sOut,
                                 const int* dflag, int ovr) {
  int f = (ovr >= 0) ? ovr : *dflag;
  size_t o = (size_t)blockIdx.x * 256 + threadIdx.x;
  size_t per = (size_t)R * Cc;
  size_t b = o / per, rem = o % per;
  size_t c = rem / R, r = rem % R;
  out[b * sOut + c * (size_t)R + r] = __float2bfloat16(ldf(in, b * sIn + r * (size_t)Cc + c, f));
}

// ---- QKV GEMM: MFMA, LN fused on A-stage (vectorized), scatter epilogue ----
__global__ __launch_bounds__(256) void gemm_qkv(
    const void* __restrict__ x, const float* __restrict__ stats,
    const void* __restrict__ g, const void* __restrict__ bb,
    const bf16* __restrict__ wT,  // [768][512]
    bf16* __restrict__ q, bf16* __restrict__ k, bf16* __restrict__ v,
    const int* __restrict__ dflag) {
  __shared__ __align__(16) unsigned short As[128][40];
  __shared__ __align__(16) unsigned short Bs[128][40];
  __shared__ __align__(16) float gls[512];
  __shared__ __align__(16) float bls[512];
  int f = *dflag;
  int tid = threadIdx.x;
  // one-time g/bb stage into LDS
  {
    int c0 = tid, c1 = tid + 256;
    gls[c0] = ldf(g, c0, f);  gls[c1] = ldf(g, c1, f);
    bls[c0] = ldf(bb, c0, f); bls[c1] = ldf(bb, c1, f);
  }
  int m0 = blockIdx.x * 128, n0 = blockIdx.y * 128;
  int sr = tid >> 1, sh = (tid & 1) * 16;
  int wave = tid >> 6, lane = tid & 63;
  int wm = (wave & 1) * 64, wn = (wave >> 1) * 64;
  int l15 = lane & 15, quad = lane >> 4;
  int r = m0 + sr;
  float mu = stats[r * 2], rs = stats[r * 2 + 1];   // loop-invariant
  const float* xf = (const float*)x + (size_t)r * DD;
  const bf16*  xb = (const bf16*)x  + (size_t)r * DD;
  __syncthreads();  // gls/bls ready
  f32x4 acc[4][4] = {};
  for (int k0 = 0; k0 < 512; k0 += 32) {
    {
      // vectorized x load
      float xv[16];
      if (f) {
        const float* src = xf + k0 + sh;
        float4 t0 = *(const float4*)(src);
        float4 t1 = *(const float4*)(src + 4);
        float4 t2 = *(const float4*)(src + 8);
        float4 t3 = *(const float4*)(src + 12);
        xv[0] = t0.x; xv[1] = t0.y; xv[2]  = t0.z; xv[3]  = t0.w;
        xv[4] = t1.x; xv[5] = t1.y; xv[6]  = t1.z; xv[7]  = t1.w;
        xv[8] = t2.x; xv[9] = t2.y; xv[10] = t2.z; xv[11] = t2.w;
        xv[12] = t3.x; xv[13] = t3.y; xv[14] = t3.z; xv[15] = t3.w;
      } else {
        const bf16* src = xb + k0 + sh;
        u16x8 t0 = *(const u16x8*)(src);
        u16x8 t1 = *(const u16x8*)(src + 8);
        #pragma unroll
        for (int e = 0; e < 8; e++) { xv[e] = u2f(t0[e]); xv[8 + e] = u2f(t1[e]); }
      }
      // LN as 2 FMA/elem: a = rs*g;  out = x*a + (bb - mu*a)
      float gv[16], bv[16];
      {
        const float* gp = &gls[k0 + sh];
        const float* bp = &bls[k0 + sh];
        #pragma unroll
        for (int e4 = 0; e4 < 4; e4++) {
          float4 gt = *(const float4*)(gp + e4 * 4);
          float4 bt = *(const float4*)(bp + e4 * 4);
          gv[e4 * 4 + 0] = gt.x; gv[e4 * 4 + 1] = gt.y; gv[e4 * 4 + 2] = gt.z; gv[e4 * 4 + 3] = gt.w;
          bv[e4 * 4 + 0] = bt.x; bv[e4 * 4 + 1] = bt.y; bv[e4 * 4 + 2] = bt.z; bv[e4 * 4 + 3] = bt.w;
        }
      }
      u16x8 w0, w1;
      #pragma unroll
      for (int e = 0; e < 8; e++) {
        float a0 = rs * gv[e];
        float a1 = rs * gv[e + 8];
        w0[e] = f2bu(xv[e] * a0 + (bv[e] - mu * a0));
        w1[e] = f2bu(xv[e + 8] * a1 + (bv[e + 8] - mu * a1));
      }
      *(u16x8*)&As[sr][sh] = w0;
      *(u16x8*)&As[sr][sh + 8] = w1;
    }
    {
      const bf16* src = wT + (size_t)(n0 + sr) * 512 + k0 + sh;
      *(u16x8*)&Bs[sr][sh] = *(const u16x8*)src;
      *(u16x8*)&Bs[sr][sh + 8] = *(const u16x8*)(src + 8);
    }
    __syncthreads();
    bf16x8 af[4], bfr[4];
    #pragma unroll
    for (int i = 0; i < 4; i++) af[i] = *(const bf16x8*)&As[wm + i * 16 + l15][quad * 8];
    #pragma unroll
    for (int j = 0; j < 4; j++) bfr[j] = *(const bf16x8*)&Bs[wn + j * 16 + l15][quad * 8];
    #pragma unroll
    for (int i = 0; i < 4; i++)
      #pragma unroll
      for (int j = 0; j < 4; j++)
        acc[i][j] = __builtin_amdgcn_mfma_f32_16x16x32_bf16(af[i], bfr[j], acc[i][j], 0, 0, 0);
    __syncthreads();
  }
  #pragma unroll
  for (int i = 0; i < 4; i++)
    #pragma unroll
    for (int j = 0; j < 4; j++)
      #pragma unroll
      for (int reg = 0; reg < 4; reg++) {
        int row = m0 + wm + i * 16 + quad * 4 + reg;
        int c = n0 + wn + j * 16 + l15;
        int which = c >> 8, within = c & 255, h = within >> 6, d = within & 63;
        int b_ = row >> 12, n = row & 4095;
        size_t idx = ((size_t)(b_ * 4 + h) * NN + n) * 64 + d;
        float val = acc[i][j][reg];
        if (which == 0) q[idx] = __float2bfloat16(val * 0.125f);
        else if (which == 1) k[idx] = __float2bfloat16(val);
        else v[idx] = __float2bfloat16(val);
      }
}

// ---- generic batched MFMA GEMM: C = A[M x K] @ Bt[N x K]^T ----
// modes: 0=f32 store, 1=bf16 store, 2=f32 atomicAdd (split-K), 3=bias+residual+dtype store
__global__ __launch_bounds__(256) void gemm_bt(
    const bf16* __restrict__ A, long ldA, long sA,
    const bf16* __restrict__ Bt, long ldB, long sB,
    void* __restrict__ C, long ldC, long sC,
    int N, int kLen, int nTiles, int mode,
    const void* __restrict__ bias, const void* __restrict__ resid,
    const int* __restrict__ dflag) {
  __shared__ __align__(16) unsigned short As[128][40];
  __shared__ __align__(16) unsigned short Bs[128][40];
  int tid = threadIdx.x;
  int b = blockIdx.x;
  int m0 = blockIdx.y * 128;
  int nt = blockIdx.z % nTiles, ks = blockIdx.z / nTiles;
  int n0 = nt * 128;
  long k0b = (long)ks * kLen;
  const bf16* Ab = A + (size_t)b * sA;
  const bf16* Bb = Bt + (size_t)b * sB;
  int sr = tid >> 1, sh = (tid & 1) * 16;
  int wave = tid >> 6, lane = tid & 63;
  int wm = (wave & 1) * 64, wn = (wave >> 1) * 64;
  int l15 = lane & 15, quad = lane >> 4;
  f32x4 acc[4][4] = {};
  for (int kc = 0; kc < kLen; kc += 32) {
    long k0 = k0b + kc;
    {
      const bf16* src = Ab + (size_t)(m0 + sr) * ldA + k0 + sh;
      *(u16x8*)&As[sr][sh] = *(const u16x8*)src;
      *(u16x8*)&As[sr][sh + 8] = *(const u16x8*)(src + 8);
    }
    if (n0 + sr < N) {
      const bf16* src = Bb + (size_t)(n0 + sr) * ldB + k0 + sh;
      *(u16x8*)&Bs[sr][sh] = *(const u16x8*)src;
      *(u16x8*)&Bs[sr][sh + 8] = *(const u16x8*)(src + 8);
    } else {
      u16x8 z = {};
      *(u16x8*)&Bs[sr][sh] = z;
      *(u16x8*)&Bs[sr][sh + 8] = z;
    }
    __syncthreads();
    bf16x8 af[4], bfr[4];
    #pragma unroll
    for (int i = 0; i < 4; i++) af[i] = *(const bf16x8*)&As[wm + i * 16 + l15][quad * 8];
    #pragma unroll
    for (int j = 0; j < 4; j++) bfr[j] = *(const bf16x8*)&Bs[wn + j * 16 + l15][quad * 8];
    #pragma unroll
    for (int i = 0; i < 4; i++)
      #pragma unroll
      for (int j = 0; j < 4; j++)
        acc[i][j] = __builtin_amdgcn_mfma_f32_16x16x32_bf16(af[i], bfr[j], acc[i][j], 0, 0, 0);
    __syncthreads();
  }
  int f = (mode == 3) ? *dflag : 0;
  #pragma unroll
  for (int i = 0; i < 4; i++)
    #pragma unroll
    for (int j = 0; j < 4; j++)
      #pragma unroll
      for (int reg = 0; reg < 4; reg++) {
        int row = m0 + wm + i * 16 + quad * 4 + reg;
        int col = n0 + wn + j * 16 + l15;
        if (col < N) {
          float val = acc[i][j][reg];
          size_t off = (size_t)row * ldC + col;
          if (mode == 0) (((float*)C) + (size_t)b * sC)[off] = val;
          else if (mode == 1) (((bf16*)C) + (size_t)b * sC)[off] = __float2bfloat16(val);
          else if (mode == 2) atomicAdd(((float*)C) + (size_t)b * sC + off, val);
          else {
            val += ldf(bias, col, f) + ldf(resid, off, f);
            stf(C, off, val, f);
          }
        }
      }
}

// ---- landmark means: bf16 src -> f32 dst (for a2/pinv) AND bf16 dst (for MFMA) ----
__global__ void landmark_kernel(const bf16* __restrict__ src, float* __restrict__ dstf,
                                bf16* __restrict__ dstb) {
  int idx = blockIdx.x * 256 + threadIdx.x;  // 524288
  int d = idx & 63, j = (idx >> 6) & 255, bh = idx >> 14;
  const bf16* s = src + ((size_t)bh * NN + j * 16) * 64 + d;
  float a = 0;
  #pragma unroll
  for (int i = 0; i < 16; i++) a += b2f(s[i * 64]);
  a *= (1.0f / 16);
  dstf[idx] = a;
  dstb[idx] = __float2bfloat16(a);
}

// ---- a2 = softmax(ql @ kl^T) f32, f32 inputs (pinv-sensitive path) ----
__global__ void a2_kernel(const float* __restrict__ ql, const float* __restrict__ kl,
                          float* __restrict__ a2) {
  __shared__ float qs[64];
  __shared__ float red[256];
  int bh = blockIdx.x >> 8, i = blockIdx.x & 255, tid = threadIdx.x;
  if (tid < 64) qs[tid] = ql[((size_t)bh * MM + i) * 64 + tid];
  __syncthreads();
  const float* kr = kl + ((size_t)bh * MM + tid) * 64;
  float s = 0;
  #pragma unroll
  for (int d = 0; d < 64; d++) s += qs[d] * kr[d];
  float mx = bred_max(s, red);
  float e = __expf(s - mx);
  float sm = bred_sum(e, red);
  a2[((size_t)bh * MM + i) * MM + tid] = e / sm;
}

__global__ void a2_maxsum(const float* __restrict__ a2, float* __restrict__ gmax) {
  __shared__ float red[256];
  int tid = threadIdx.x, id = blockIdx.x;
  if (id < 8192) {
    int bh = id >> 8, i = id & 255;
    float tot = bred_sum(fabsf(a2[((size_t)bh * MM + i) * MM + tid]), red);
    if (tid == 0) atomicMax((int*)gmax, __float_as_int(tot));
  } else {
    id -= 8192;
    int bh = id >> 8, j = id & 255;
    float tot = bred_sum(fabsf(a2[((size_t)bh * MM + tid) * MM + j]), red);
    if (tid == 0) atomicMax((int*)gmax + 1, __float_as_int(tot));
  }
}

__global__ void zinit_kernel(const float* __restrict__ a2, const float* __restrict__ gmax,
                             float* __restrict__ z) {
  int idx = blockIdx.x * 256 + threadIdx.x;
  int j = idx & 255, i = (idx >> 8) & 255, bh = idx >> 16;
  float scale = 1.0f / (gmax[0] * gmax[1]);
  z[idx] = a2[((size_t)bh * MM + j) * MM + i] * scale;
}

// ---- fp32 batched 64x64-tile GEMM: C = alpha*I + beta*(A @ (gbA*I + gbB*B)) ----
// B-tile staging: 16 k-rows x 64 cols at col0 (rb=tid>>4, c4=(tid&15)*4).
// NOTE: round-6's "Nn-guard" indexing here was an LDS-OOB bug; do not reintroduce.
__global__ __launch_bounds__(256) void bmm64(
    const float* __restrict__ A, const float* __restrict__ B_,
    float* __restrict__ C,
    int Nn, int Kk, long sA, long sB, long sC,
    float alpha, float beta, float gbA, float gbB) {
  __shared__ __align__(16) float As[16][68];
  __shared__ __align__(16) float Bs[16][68];
  int bh = blockIdx.x;
  int row0 = blockIdx.y * 64, col0 = blockIdx.z * 64;
  const float* Ab = A + (size_t)bh * sA;
  const float* Bb = B_ + (size_t)bh * sB;
  int tid = threadIdx.x, tx = tid & 15, ty = tid >> 4;
  float c[4][4] = {};
  for (int k0 = 0; k0 < Kk; k0 += 16) {
    {
      int r = tid >> 2, k4 = (tid & 3) * 4;
      const float* src = Ab + (size_t)(row0 + r) * Kk + k0 + k4;
      float4 av = *(const float4*)src;
      As[k4 + 0][r] = av.x; As[k4 + 1][r] = av.y; As[k4 + 2][r] = av.z; As[k4 + 3][r] = av.w;
    }
    {
      int rb = tid >> 4, c4 = (tid & 15) * 4;
      const float* src = Bb + (size_t)(k0 + rb) * Nn + col0 + c4;
      float4 bv = *(const float4*)src;
      bv.x *= gbB; bv.y *= gbB; bv.z *= gbB; bv.w *= gbB;
      int kk = k0 + rb;
      if (kk == col0 + c4 + 0) bv.x += gbA;
      if (kk == col0 + c4 + 1) bv.y += gbA;
      if (kk == col0 + c4 + 2) bv.z += gbA;
      if (kk == col0 + c4 + 3) bv.w += gbA;
      *(float4*)&Bs[rb][c4] = bv;
    }
    __syncthreads();
    #pragma unroll
    for (int kk = 0; kk < 16; kk++) {
      float4 a = *(const float4*)&As[kk][ty * 4];
      float4 b = *(const float4*)&Bs[kk][tx * 4];
      float ar[4] = {a.x, a.y, a.z, a.w};
      float br[4] = {b.x, b.y, b.z, b.w};
      #pragma unroll
      for (int i = 0; i < 4; i++)
        #pragma unroll
        for (int j = 0; j < 4; j++) c[i][j] += ar[i] * br[j];
    }
    __syncthreads();
  }
  #pragma unroll
  for (int i = 0; i < 4; i++)
    #pragma unroll
    for (int j = 0; j < 4; j++) {
      int r = row0 + ty * 4 + i, cc = col0 + tx * 4 + j;
      C[(size_t)bh * sC + (size_t)r * Nn + cc] = alpha * (r == cc) + beta * c[i][j];
    }
}

// ---- softmax over rows of 4096 (bf16 in -> bf16 out) ----
__global__ void softmax3_kernel(const bf16* __restrict__ S, bf16* __restrict__ P) {
  __shared__ float red[256];
  int row = blockIdx.x, tid = threadIdx.x;
  const bf16* sr = S + (size_t)row * 4096 + tid * 16;
  u16x8 v0 = *(const u16x8*)sr;
  u16x8 v1 = *(const u16x8*)(sr + 8);
  float vals[16];
  #pragma unroll
  for (int e = 0; e < 8; e++) { vals[e] = u2f(v0[e]); vals[e + 8] = u2f(v1[e]); }
  float lm = -1e30f;
  #pragma unroll
  for (int e = 0; e < 16; e++) lm = fmaxf(lm, vals[e]);
  float mx = bred_max(lm, red);
  float ls = 0;
  #pragma unroll
  for (int e = 0; e < 16; e++) { vals[e] = __expf(vals[e] - mx); ls += vals[e]; }
  float inv = 1.0f / bred_sum(ls, red);
  bf16* pr = P + (size_t)row * 4096 + tid * 16;
  #pragma unroll
  for (int e = 0; e < 16; e++) pr[e] = __float2bfloat16(vals[e] * inv);
}

// ---- fused sim1 + softmax -> P1 f32 [4][4096][256] ----
__global__ __launch_bounds__(256) void attn1_kernel(
    const bf16* __restrict__ q, const bf16* __restrict__ klbf,
    float* __restrict__ P1, int bh0) {
  __shared__ __align__(16) unsigned short Qs[64][72];
  __shared__ __align__(16) unsigned short Ks[256][72];
  __shared__ float redm[4][64];
  __shared__ float reds[4][64];
  int tid = threadIdx.x;
  int bhl = blockIdx.y, bh = bh0 + bhl;
  int n0 = blockIdx.x * 64;
  const bf16* qb = q + ((size_t)bh * NN + n0) * 64;
  const bf16* kb = klbf + (size_t)bh * 16384;
  {
    int r = tid >> 2, s = (tid & 3) * 16;
    *(u16x8*)&Qs[r][s] = *(const u16x8*)(qb + (size_t)r * 64 + s);
    *(u16x8*)&Qs[r][s + 8] = *(const u16x8*)(qb + (size_t)r * 64 + s + 8);
  }
  {
    const bf16* src = kb + (size_t)tid * 64;
    #pragma unroll
    for (int s8 = 0; s8 < 8; s8++) *(u16x8*)&Ks[tid][s8 * 8] = *(const u16x8*)(src + s8 * 8);
  }
  __syncthreads();
  int wave = tid >> 6, lane = tid & 63, l15 = lane & 15, quad = lane >> 4;
  f32x4 acc[4][4] = {};
  #pragma unroll
  for (int kc = 0; kc < 64; kc += 32) {
    bf16x8 af[4], bfr[4];
    #pragma unroll
    for (int i = 0; i < 4; i++) af[i] = *(const bf16x8*)&Qs[i * 16 + l15][kc + quad * 8];
    #pragma unroll
    for (int j = 0; j < 4; j++) bfr[j] = *(const bf16x8*)&Ks[wave * 64 + j * 16 + l15][kc + quad * 8];
    #pragma unroll
    for (int i = 0; i < 4; i++)
      #pragma unroll
      for (int j = 0; j < 4; j++)
        acc[i][j] = __builtin_amdgcn_mfma_f32_16x16x32_bf16(af[i], bfr[j], acc[i][j], 0, 0, 0);
  }
  float lm[4][4], ls[4][4], rinv[4][4];
  #pragma unroll
  for (int i = 0; i < 4; i++)
    #pragma unroll
    for (int reg = 0; reg < 4; reg++) {
      float m = acc[i][0][reg];
      m = fmaxf(m, acc[i][1][reg]); m = fmaxf(m, acc[i][2][reg]); m = fmaxf(m, acc[i][3][reg]);
      lm[i][reg] = m;
    }
  #pragma unroll
  for (int off = 1; off < 16; off <<= 1)
    #pragma unroll
    for (int i = 0; i < 4; i++)
      #pragma unroll
      for (int reg = 0; reg < 4; reg++) lm[i][reg] = fmaxf(lm[i][reg], __shfl_xor(lm[i][reg], off));
  if (l15 == 0)
    #pragma unroll
    for (int i = 0; i < 4; i++)
      #pragma unroll
      for (int reg = 0; reg < 4; reg++) redm[wave][i * 16 + quad * 4 + reg] = lm[i][reg];
  __syncthreads();
  #pragma unroll
  for (int i = 0; i < 4; i++)
    #pragma unroll
    for (int reg = 0; reg < 4; reg++) {
      int r = i * 16 + quad * 4 + reg;
      rinv[i][reg] = fmaxf(fmaxf(redm[0][r], redm[1][r]), fmaxf(redm[2][r], redm[3][r]));
      ls[i][reg] = 0;
    }
  #pragma unroll
  for (int i = 0; i < 4; i++)
    #pragma unroll
    for (int j = 0; j < 4; j++)
      #pragma unroll
      for (int reg = 0; reg < 4; reg++) {
        float e = __expf(acc[i][j][reg] - rinv[i][reg]);
        acc[i][j][reg] = e;
        ls[i][reg] += e;
      }
  #pragma unroll
  for (int off = 1; off < 16; off <<= 1)
    #pragma unroll
    for (int i = 0; i < 4; i++)
      #pragma unroll
      for (int reg = 0; reg < 4; reg++) ls[i][reg] += __shfl_xor(ls[i][reg], off);
  if (l15 == 0)
    #pragma unroll
    for (int i = 0; i < 4; i++)
      #pragma unroll
      for (int reg = 0; reg < 4; reg++) reds[wave][i * 16 + quad * 4 + reg] = ls[i][reg];
  __syncthreads();
  #pragma unroll
  for (int i = 0; i < 4; i++)
    #pragma unroll
    for (int reg = 0; reg < 4; reg++) {
      int r = i * 16 + quad * 4 + reg;
      rinv[i][reg] = 1.0f / (reds[0][r] + reds[1][r] + reds[2][r] + reds[3][r]);
    }
  float* Pb = P1 + ((size_t)bhl * NN + n0) * 256;
  #pragma unroll
  for (int i = 0; i < 4; i++)
    #pragma unroll
    for (int j = 0; j < 4; j++)
      #pragma unroll
      for (int reg = 0; reg < 4; reg++) {
        int r = i * 16 + quad * 4 + reg;
        int col = wave * 64 + j * 16 + l15;
        Pb[(size_t)r * 256 + col] = acc[i][j][reg] * rinv[i][reg];
      }
}

// ---- depthwise conv (33) residual add: y = p1f32 + conv(v), 4-bh chunk ----
__global__ __launch_bounds__(256) void conv_add_kernel(
    const float* __restrict__ p1, const bf16* __restrict__ v,
    const void* __restrict__ wres, bf16* __restrict__ y, const int* __restrict__ dflag,
    int bh0) {
  __shared__ __align__(16) unsigned short Vs[96][64];
  int f = *dflag;
  int tid = threadIdx.x;
  int bhl = blockIdx.y, bh = bh0 + bhl;
  int n0 = blockIdx.x * 64;
  int h = bh & 3, b_ = bh >> 2;
  const bf16* vb = v + (size_t)bh * (NN * 64);
  for (int rr = tid; rr < 384; rr += 256) {
    int r = rr >> 2, s = (rr & 3) * 16;
    int n = n0 - 16 + r;
    if (n >= 0 && n < NN) {
      *(u16x8*)&Vs[r][s] = *(const u16x8*)(vb + (size_t)n * 64 + s);
      *(u16x8*)&Vs[r][s + 8] = *(const u16x8*)(vb + (size_t)n * 64 + s + 8);
    } else {
      u16x8 z = {};
      *(u16x8*)&Vs[r][s] = z; *(u16x8*)&Vs[r][s + 8] = z;
    }
  }
  float w33[33];
  #pragma unroll
  for (int kk = 0; kk < 33; kk++) w33[kk] = ldf(wres, h * 33 + kk, f);
  __syncthreads();
  int d = tid & 63, rb = tid >> 6;
  for (int ii = 0; ii < 16; ii++) {
    int nl = ii * 4 + rb;
    float cv = 0;
    #pragma unroll
    for (int kk = 0; kk < 33; kk++) cv += w33[kk] * u2f(Vs[nl + kk][d]);
    int n = n0 + nl;
    float pv = p1[((size_t)bhl * NN + n) * 64 + d];
    y[((size_t)b_ * NN + n) * 256 + h * 64 + d] = __float2bfloat16(pv + cv);
  }
}

extern "C" void kernel_launch(void* const* d_in, const int* in_sizes, int n_in,
                              void* d_out, int out_size, void* d_ws, size_t ws_size,
                              hipStream_t stream) {
  const void* x     = d_in[0];
  const void* ln_g  = d_in[1];
  const void* ln_b  = d_in[2];
  const void* w_qkv = d_in[3];
  const void* w_out = d_in[4];
  const void* b_out = d_in[5];
  const void* w_res = d_in[6];

  // ---- ws layout (~67.4 MiB; round-4 proved >= ~81 MiB available) ----
  float* ws    = (float*)d_ws;
  float* gmax  = ws;                                   // 2 f
  int*   dflag = (int*)(ws + 2);                       // 1 int
  float* stats = ws + 256;                             // 65536 f
  bf16*  woutT = (bf16*)(stats + 65536);               // 131072 bf16
  float* qlf   = (float*)(stats + 65536 + 65536);      // 524288 f
  float* klf   = qlf + 524288;                         // 524288 f
  bf16*  qlbf  = (bf16*)(klf + 524288);                // 524288 bf16
  bf16*  klbf  = qlbf + 524288;                        // 524288 bf16
  float* a3v   = (float*)(klbf + 524288);              // 524288 f
  float* Wm    = a3v + 524288;                         // 524288 f
  float* a2    = Wm + 524288;                          // 2097152 f (vT scratch alias)
  bf16*  q     = (bf16*)(a2 + 2097152);                // 8388608 bf16
  bf16*  k     = q + 8388608;                          // 8388608 bf16 (y alias)
  bf16*  v     = k + 8388608;                          // 8388608 bf16
  bf16*  y     = k;                                    // alias (k dead after sim3)
  bf16*  vTbuf = (bf16*)a2;                            // 4 MiB chunk scratch in a2 region

  // ---- d_out scratch (<= 32 MiB at all times) ----
  char* dob = (char*)d_out;
  bf16* wqkvT = (bf16*)dob;                            // phase A
  bf16* S3    = (bf16*)dob;                            // 16 MiB
  bf16* P3    = (bf16*)(dob + (16u << 20));            // 16 MiB
  float* W0   = (float*)dob;                           // pinv: 4 x 8 MiB
  float* W1   = (float*)(dob + (8u << 20));
  float* W2   = (float*)(dob + (16u << 20));
  float* W3   = (float*)(dob + (24u << 20));
  float* P1   = (float*)dob;                           // 16 MiB (4 bh chunk, f32)
  float* p1f  = (float*)(dob + (16u << 20));           // 4 MiB  (4 bh chunk, f32)

  detect_kernel<<<1, 256, 0, stream>>>(x, dflag);
  hipMemsetAsync(gmax, 0, 2 * sizeof(float), stream);
  ln_stats_kernel<<<ROWS, 256, 0, stream>>>(x, stats, dflag);

  // weight transposes
  transpose_kernel<<<1536, 256, 0, stream>>>(w_qkv, wqkvT, 512, 768, 0, 0, dflag, -1);
  transpose_kernel<<<512, 256, 0, stream>>>(w_out, woutT, 256, 512, 0, 0, dflag, -1);

  // QKV (LN fused)
  gemm_qkv<<<dim3(256, 6), 256, 0, stream>>>(x, stats, ln_g, ln_b, wqkvT, q, k, v, dflag);

  // landmarks (f32 + bf16)
  landmark_kernel<<<2048, 256, 0, stream>>>(q, qlf, qlbf);
  landmark_kernel<<<2048, 256, 0, stream>>>(k, klf, klbf);

  // sim3 -> softmax -> @v (4 chunks of 8 bh), a3v via split-K f32 atomics
  hipMemsetAsync(a3v, 0, 524288 * sizeof(float), stream);
  for (int c = 0; c < 4; c++) {
    transpose_kernel<<<8192, 256, 0, stream>>>(v + (size_t)c * 8 * 262144, vTbuf,
                                               4096, 64, 262144, 262144, dflag, 0);
    gemm_bt<<<dim3(8, 2, 32), 256, 0, stream>>>(
        qlbf + (size_t)c * 8 * 16384, 64, 16384,
        k + (size_t)c * 8 * 262144, 64, 262144,
        S3, 4096, 1048576, 4096, 64, 32, 1, nullptr, nullptr, dflag);
    softmax3_kernel<<<2048, 256, 0, stream>>>(S3, P3);
    gemm_bt<<<dim3(8, 2, 16), 256, 0, stream>>>(
        P3, 4096, 1048576, vTbuf, 4096, 262144,
        a3v + (size_t)c * 131072, 64, 16384, 64, 256, 1, 2, nullptr, nullptr, dflag);
  }

  // a2 path (f32 landmarks) + pinv in d_out
  a2_kernel<<<8192, 256, 0, stream>>>(qlf, klf, a2);
  a2_maxsum<<<16384, 256, 0, stream>>>(a2, gmax);
  zinit_kernel<<<8192, 256, 0, stream>>>(a2, gmax, W0);

  float* zi = W0; float* f1 = W1; float* f2 = W2; float* f3 = W3;
  for (int it = 0; it < 6; it++) {
    bmm64<<<dim3(32, 4, 4), 256, 0, stream>>>(a2, zi, f1, 256, 256, 65536, 65536, 65536, 0.f, 1.f, 0.f, 1.f);
    bmm64<<<dim3(32, 4, 4), 256, 0, stream>>>(f1, f1, f2, 256, 256, 65536, 65536, 65536, 15.f, -1.f, 7.f, -1.f);
    bmm64<<<dim3(32, 4, 4), 256, 0, stream>>>(f1, f2, f3, 256, 256, 65536, 65536, 65536, 13.f, -1.f, 0.f, 1.f);
    bmm64<<<dim3(32, 4, 4), 256, 0, stream>>>(zi, f3, f2, 256, 256, 65536, 65536, 65536, 0.f, 0.25f, 0.f, 1.f);
    float* nzi = f2; f2 = f1; f1 = zi; zi = nzi;
  }

  // Wm = z6 @ a3v -> f32 in ws (before d_out reuse)
  bmm64<<<dim3(32, 4, 1), 256, 0, stream>>>(zi, a3v, Wm, 64, 256, 65536, 16384, 16384, 0.f, 1.f, 0.f, 1.f);

  // a1 softmax (f32 P1) + f32 PV1 + conv residual, 8 chunks of 4 bh
  for (int c = 0; c < 8; c++) {
    attn1_kernel<<<dim3(64, 4), 256, 0, stream>>>(q, klbf, P1, c * 4);
    bmm64<<<dim3(4, 64, 1), 256, 0, stream>>>(
        P1, Wm + (size_t)c * 4 * 16384, p1f,
        64, 256, 1048576, 16384, 262144, 0.f, 1.f, 0.f, 1.f);
    conv_add_kernel<<<dim3(64, 4), 256, 0, stream>>>(p1f, v, w_res, y, dflag, c * 4);
  }

  // out = y @ w_out + b_out + x -> d_out (dtype-adaptive)
  gemm_bt<<<dim3(1, 256, 4), 256, 0, stream>>>(
      y, 256, 0, woutT, 256, 0,
      d_out, 512, 0, 512, 256, 4, 3, b_out, x, dflag);
}

// Round 3
// 1374.424 us; speedup vs baseline: 1.2797x; 1.1296x over previous
//
#include <hip/hip_runtime.h>
#include <hip/hip_bf16.h>
#include <string.h>

typedef __hip_bfloat16 bf16;
typedef __attribute__((ext_vector_type(8))) __bf16 bf16x8;
typedef __attribute__((ext_vector_type(4))) float f32x4;
typedef __attribute__((ext_vector_type(8))) unsigned short u16x8;

#define NN 4096
#define DD 512
#define MM 256
#define ROWS 32768

__device__ __forceinline__ float b2f(bf16 x) { return __bfloat162float(x); }
__device__ __forceinline__ float u2f(unsigned short u) {
  return __uint_as_float(((unsigned int)u) << 16);
}
__device__ __forceinline__ unsigned short f2bu(float v) {
  bf16 h = __float2bfloat16(v);
  return *reinterpret_cast<unsigned short*>(&h);
}
// adaptive input load / output store (f==1 -> float32, f==0 -> bf16)
__device__ __forceinline__ float ldf(const void* p, size_t i, int f) {
  return f ? ((const float*)p)[i] : __bfloat162float(((const bf16*)p)[i]);
}
__device__ __forceinline__ void stf(void* p, size_t i, float v, int f) {
  if (f) ((float*)p)[i] = v;
  else ((bf16*)p)[i] = __float2bfloat16(v);
}

// ---- dtype detection ----
__global__ void detect_kernel(const void* x, int* flag) {
  __shared__ int red[256];
  int tid = threadIdx.x;
  const unsigned short* u = (const unsigned short*)x;
  int local = 0;
  for (int i = 0; i < 32; i++) {
    unsigned short e = (u[tid * 32 + i] >> 7) & 0xFF;
    if (e >= 0xC8) local++;
  }
  red[tid] = local; __syncthreads();
  #pragma unroll
  for (int s = 128; s > 0; s >>= 1) {
    if (tid < s) red[tid] += red[tid + s];
    __syncthreads();
  }
  if (tid == 0) *flag = (red[0] > 32) ? 1 : 0;
}

// ---- block reductions ----
__device__ __forceinline__ float bred_max(float v, float* red) {
  int tid = threadIdx.x;
  red[tid] = v; __syncthreads();
  #pragma unroll
  for (int s = 128; s > 0; s >>= 1) {
    if (tid < s) red[tid] = fmaxf(red[tid], red[tid + s]);
    __syncthreads();
  }
  float r = red[0]; __syncthreads();
  return r;
}
__device__ __forceinline__ float bred_sum(float v, float* red) {
  int tid = threadIdx.x;
  red[tid] = v; __syncthreads();
  #pragma unroll
  for (int s = 128; s > 0; s >>= 1) {
    if (tid < s) red[tid] += red[tid + s];
    __syncthreads();
  }
  float r = red[0]; __syncthreads();
  return r;
}

// ---- LayerNorm stats ----
__global__ void ln_stats_kernel(const void* __restrict__ x, float* __restrict__ stats,
                                const int* dflag) {
  __shared__ float red[256];
  int f = *dflag;
  int row = blockIdx.x, tid = threadIdx.x;
  size_t base = (size_t)row * DD;
  float v0 = ldf(x, base + tid, f);
  float v1 = ldf(x, base + tid + 256, f);
  float mean = bred_sum(v0 + v1, red) * (1.0f / DD);
  float d0 = v0 - mean, d1 = v1 - mean;
  float var = bred_sum(d0 * d0 + d1 * d1, red) * (1.0f / DD);
  if (tid == 0) {
    stats[row * 2] = mean;
    stats[row * 2 + 1] = rsqrtf(var + 1e-5f);
  }
}

// ---- generic transpose -> bf16 out: out[b][c][r] = in[b][r][c] ----
__global__ void transpose_kernel(const void* __restrict__ in, bf16* __restrict__ out,
                                 int R, int Cc, long sIn, long sOut,
                                 const int* dflag, int ovr) {
  int f = (ovr >= 0) ? ovr : *dflag;
  size_t o = (size_t)blockIdx.x * 256 + threadIdx.x;
  size_t per = (size_t)R * Cc;
  size_t b = o / per, rem = o % per;
  size_t c = rem / R, r = rem % R;
  out[b * sOut + c * (size_t)R + r] = __float2bfloat16(ldf(in, b * sIn + r * (size_t)Cc + c, f));
}

// ---- QKV GEMM: MFMA, LN fused on A-stage (vectorized), scatter epilogue ----
__global__ __launch_bounds__(256) void gemm_qkv(
    const void* __restrict__ x, const float* __restrict__ stats,
    const void* __restrict__ g, const void* __restrict__ bb,
    const bf16* __restrict__ wT,  // [768][512]
    bf16* __restrict__ q, bf16* __restrict__ k, bf16* __restrict__ v,
    const int* __restrict__ dflag) {
  __shared__ __align__(16) unsigned short As[128][40];
  __shared__ __align__(16) unsigned short Bs[128][40];
  __shared__ __align__(16) float gls[512];
  __shared__ __align__(16) float bls[512];
  int f = *dflag;
  int tid = threadIdx.x;
  // one-time g/bb stage into LDS
  {
    int c0 = tid, c1 = tid + 256;
    gls[c0] = ldf(g, c0, f);  gls[c1] = ldf(g, c1, f);
    bls[c0] = ldf(bb, c0, f); bls[c1] = ldf(bb, c1, f);
  }
  int m0 = blockIdx.x * 128, n0 = blockIdx.y * 128;
  int sr = tid >> 1, sh = (tid & 1) * 16;
  int wave = tid >> 6, lane = tid & 63;
  int wm = (wave & 1) * 64, wn = (wave >> 1) * 64;
  int l15 = lane & 15, quad = lane >> 4;
  int r = m0 + sr;
  float mu = stats[r * 2], rs = stats[r * 2 + 1];   // loop-invariant
  const float* xf = (const float*)x + (size_t)r * DD;
  const bf16*  xb = (const bf16*)x  + (size_t)r * DD;
  __syncthreads();  // gls/bls ready
  f32x4 acc[4][4] = {};
  for (int k0 = 0; k0 < 512; k0 += 32) {
    {
      // vectorized x load
      float xv[16];
      if (f) {
        const float* src = xf + k0 + sh;
        float4 t0 = *(const float4*)(src);
        float4 t1 = *(const float4*)(src + 4);
        float4 t2 = *(const float4*)(src + 8);
        float4 t3 = *(const float4*)(src + 12);
        xv[0] = t0.x; xv[1] = t0.y; xv[2]  = t0.z; xv[3]  = t0.w;
        xv[4] = t1.x; xv[5] = t1.y; xv[6]  = t1.z; xv[7]  = t1.w;
        xv[8] = t2.x; xv[9] = t2.y; xv[10] = t2.z; xv[11] = t2.w;
        xv[12] = t3.x; xv[13] = t3.y; xv[14] = t3.z; xv[15] = t3.w;
      } else {
        const bf16* src = xb + k0 + sh;
        u16x8 t0 = *(const u16x8*)(src);
        u16x8 t1 = *(const u16x8*)(src + 8);
        #pragma unroll
        for (int e = 0; e < 8; e++) { xv[e] = u2f(t0[e]); xv[8 + e] = u2f(t1[e]); }
      }
      // LN as 2 FMA/elem: a = rs*g;  out = x*a + (bb - mu*a)
      float gv[16], bv[16];
      {
        const float* gp = &gls[k0 + sh];
        const float* bp = &bls[k0 + sh];
        #pragma unroll
        for (int e4 = 0; e4 < 4; e4++) {
          float4 gt = *(const float4*)(gp + e4 * 4);
          float4 bt = *(const float4*)(bp + e4 * 4);
          gv[e4 * 4 + 0] = gt.x; gv[e4 * 4 + 1] = gt.y; gv[e4 * 4 + 2] = gt.z; gv[e4 * 4 + 3] = gt.w;
          bv[e4 * 4 + 0] = bt.x; bv[e4 * 4 + 1] = bt.y; bv[e4 * 4 + 2] = bt.z; bv[e4 * 4 + 3] = bt.w;
        }
      }
      u16x8 w0, w1;
      #pragma unroll
      for (int e = 0; e < 8; e++) {
        float a0 = rs * gv[e];
        float a1 = rs * gv[e + 8];
        w0[e] = f2bu(xv[e] * a0 + (bv[e] - mu * a0));
        w1[e] = f2bu(xv[e + 8] * a1 + (bv[e + 8] - mu * a1));
      }
      *(u16x8*)&As[sr][sh] = w0;
      *(u16x8*)&As[sr][sh + 8] = w1;
    }
    {
      const bf16* src = wT + (size_t)(n0 + sr) * 512 + k0 + sh;
      *(u16x8*)&Bs[sr][sh] = *(const u16x8*)src;
      *(u16x8*)&Bs[sr][sh + 8] = *(const u16x8*)(src + 8);
    }
    __syncthreads();
    bf16x8 af[4], bfr[4];
    #pragma unroll
    for (int i = 0; i < 4; i++) af[i] = *(const bf16x8*)&As[wm + i * 16 + l15][quad * 8];
    #pragma unroll
    for (int j = 0; j < 4; j++) bfr[j] = *(const bf16x8*)&Bs[wn + j * 16 + l15][quad * 8];
    #pragma unroll
    for (int i = 0; i < 4; i++)
      #pragma unroll
      for (int j = 0; j < 4; j++)
        acc[i][j] = __builtin_amdgcn_mfma_f32_16x16x32_bf16(af[i], bfr[j], acc[i][j], 0, 0, 0);
    __syncthreads();
  }
  #pragma unroll
  for (int i = 0; i < 4; i++)
    #pragma unroll
    for (int j = 0; j < 4; j++)
      #pragma unroll
      for (int reg = 0; reg < 4; reg++) {
        int row = m0 + wm + i * 16 + quad * 4 + reg;
        int c = n0 + wn + j * 16 + l15;
        int which = c >> 8, within = c & 255, h = within >> 6, d = within & 63;
        int b_ = row >> 12, n = row & 4095;
        size_t idx = ((size_t)(b_ * 4 + h) * NN + n) * 64 + d;
        float val = acc[i][j][reg];
        if (which == 0) q[idx] = __float2bfloat16(val * 0.125f);
        else if (which == 1) k[idx] = __float2bfloat16(val);
        else v[idx] = __float2bfloat16(val);
      }
}

// ---- generic batched MFMA GEMM: C = A[M x K] @ Bt[N x K]^T ----
// modes: 0=f32 store, 1=bf16 store, 2=f32 atomicAdd (split-K), 3=bias+residual+dtype store
__global__ __launch_bounds__(256) void gemm_bt(
    const bf16* __restrict__ A, long ldA, long sA,
    const bf16* __restrict__ Bt, long ldB, long sB,
    void* __restrict__ C, long ldC, long sC,
    int N, int kLen, int nTiles, int mode,
    const void* __restrict__ bias, const void* __restrict__ resid,
    const int* __restrict__ dflag) {
  __shared__ __align__(16) unsigned short As[128][40];
  __shared__ __align__(16) unsigned short Bs[128][40];
  int tid = threadIdx.x;
  int b = blockIdx.x;
  int m0 = blockIdx.y * 128;
  int nt = blockIdx.z % nTiles, ks = blockIdx.z / nTiles;
  int n0 = nt * 128;
  long k0b = (long)ks * kLen;
  const bf16* Ab = A + (size_t)b * sA;
  const bf16* Bb = Bt + (size_t)b * sB;
  int sr = tid >> 1, sh = (tid & 1) * 16;
  int wave = tid >> 6, lane = tid & 63;
  int wm = (wave & 1) * 64, wn = (wave >> 1) * 64;
  int l15 = lane & 15, quad = lane >> 4;
  f32x4 acc[4][4] = {};
  for (int kc = 0; kc < kLen; kc += 32) {
    long k0 = k0b + kc;
    {
      const bf16* src = Ab + (size_t)(m0 + sr) * ldA + k0 + sh;
      *(u16x8*)&As[sr][sh] = *(const u16x8*)src;
      *(u16x8*)&As[sr][sh + 8] = *(const u16x8*)(src + 8);
    }
    if (n0 + sr < N) {
      const bf16* src = Bb + (size_t)(n0 + sr) * ldB + k0 + sh;
      *(u16x8*)&Bs[sr][sh] = *(const u16x8*)src;
      *(u16x8*)&Bs[sr][sh + 8] = *(const u16x8*)(src + 8);
    } else {
      u16x8 z = {};
      *(u16x8*)&Bs[sr][sh] = z;
      *(u16x8*)&Bs[sr][sh + 8] = z;
    }
    __syncthreads();
    bf16x8 af[4], bfr[4];
    #pragma unroll
    for (int i = 0; i < 4; i++) af[i] = *(const bf16x8*)&As[wm + i * 16 + l15][quad * 8];
    #pragma unroll
    for (int j = 0; j < 4; j++) bfr[j] = *(const bf16x8*)&Bs[wn + j * 16 + l15][quad * 8];
    #pragma unroll
    for (int i = 0; i < 4; i++)
      #pragma unroll
      for (int j = 0; j < 4; j++)
        acc[i][j] = __builtin_amdgcn_mfma_f32_16x16x32_bf16(af[i], bfr[j], acc[i][j], 0, 0, 0);
    __syncthreads();
  }
  int f = (mode == 3) ? *dflag : 0;
  #pragma unroll
  for (int i = 0; i < 4; i++)
    #pragma unroll
    for (int j = 0; j < 4; j++)
      #pragma unroll
      for (int reg = 0; reg < 4; reg++) {
        int row = m0 + wm + i * 16 + quad * 4 + reg;
        int col = n0 + wn + j * 16 + l15;
        if (col < N) {
          float val = acc[i][j][reg];
          size_t off = (size_t)row * ldC + col;
          if (mode == 0) (((float*)C) + (size_t)b * sC)[off] = val;
          else if (mode == 1) (((bf16*)C) + (size_t)b * sC)[off] = __float2bfloat16(val);
          else if (mode == 2) atomicAdd(((float*)C) + (size_t)b * sC + off, val);
          else {
            val += ldf(bias, col, f) + ldf(resid, off, f);
            stf(C, off, val, f);
          }
        }
      }
}

// ---- landmark means: bf16 src -> f32 dst (for a2/pinv) AND bf16 dst (for MFMA) ----
__global__ void landmark_kernel(const bf16* __restrict__ src, float* __restrict__ dstf,
                                bf16* __restrict__ dstb) {
  int idx = blockIdx.x * 256 + threadIdx.x;  // 524288
  int d = idx & 63, j = (idx >> 6) & 255, bh = idx >> 14;
  const bf16* s = src + ((size_t)bh * NN + j * 16) * 64 + d;
  float a = 0;
  #pragma unroll
  for (int i = 0; i < 16; i++) a += b2f(s[i * 64]);
  a *= (1.0f / 16);
  dstf[idx] = a;
  dstb[idx] = __float2bfloat16(a);
}

// ---- a2 = softmax(ql @ kl^T) f32, f32 inputs (pinv-sensitive path) ----
__global__ void a2_kernel(const float* __restrict__ ql, const float* __restrict__ kl,
                          float* __restrict__ a2) {
  __shared__ float qs[64];
  __shared__ float red[256];
  int bh = blockIdx.x >> 8, i = blockIdx.x & 255, tid = threadIdx.x;
  if (tid < 64) qs[tid] = ql[((size_t)bh * MM + i) * 64 + tid];
  __syncthreads();
  const float* kr = kl + ((size_t)bh * MM + tid) * 64;
  float s = 0;
  #pragma unroll
  for (int d = 0; d < 64; d++) s += qs[d] * kr[d];
  float mx = bred_max(s, red);
  float e = __expf(s - mx);
  float sm = bred_sum(e, red);
  a2[((size_t)bh * MM + i) * MM + tid] = e / sm;
}

// ---- max over column-sums of a2 (row-sums of softmax are exactly 1, skipped) ----
// 32 blocks (one per bh); thread j owns column j (coalesced); 1 atomic per block.
__global__ void colsum_max_kernel(const float* __restrict__ a2, float* __restrict__ gmax) {
  __shared__ float red[256];
  int bh = blockIdx.x, tid = threadIdx.x;
  const float* base = a2 + (size_t)bh * MM * MM + tid;
  float s0 = 0, s1 = 0, s2 = 0, s3 = 0, s4 = 0, s5 = 0, s6 = 0, s7 = 0;
  for (int i = 0; i < 256; i += 8) {
    s0 += base[(size_t)(i + 0) * MM];
    s1 += base[(size_t)(i + 1) * MM];
    s2 += base[(size_t)(i + 2) * MM];
    s3 += base[(size_t)(i + 3) * MM];
    s4 += base[(size_t)(i + 4) * MM];
    s5 += base[(size_t)(i + 5) * MM];
    s6 += base[(size_t)(i + 6) * MM];
    s7 += base[(size_t)(i + 7) * MM];
  }
  float tot = ((s0 + s1) + (s2 + s3)) + ((s4 + s5) + (s6 + s7));
  float mx = bred_max(tot, red);
  if (tid == 0) atomicMax((int*)gmax + 1, __float_as_int(mx));
}

__global__ void zinit_kernel(const float* __restrict__ a2, const float* __restrict__ gmax,
                             float* __restrict__ z) {
  int idx = blockIdx.x * 256 + threadIdx.x;
  int j = idx & 255, i = (idx >> 8) & 255, bh = idx >> 16;
  float scale = 1.0f / gmax[1];   // max(row-sums) == 1 exactly (softmax rows)
  z[idx] = a2[((size_t)bh * MM + j) * MM + i] * scale;
}

// ---- fp32 batched 64x64-tile GEMM: C = alpha*I + beta*(A @ (gbA*I + gbB*B)) ----
// B-tile staging: 16 k-rows x 64 cols at col0 (rb=tid>>4, c4=(tid&15)*4).
// NOTE: round-6's "Nn-guard" indexing here was an LDS-OOB bug; do not reintroduce.
__global__ __launch_bounds__(256) void bmm64(
    const float* __restrict__ A, const float* __restrict__ B_,
    float* __restrict__ C,
    int Nn, int Kk, long sA, long sB, long sC,
    float alpha, float beta, float gbA, float gbB) {
  __shared__ __align__(16) float As[16][68];
  __shared__ __align__(16) float Bs[16][68];
  int bh = blockIdx.x;
  int row0 = blockIdx.y * 64, col0 = blockIdx.z * 64;
  const float* Ab = A + (size_t)bh * sA;
  const float* Bb = B_ + (size_t)bh * sB;
  int tid = threadIdx.x, tx = tid & 15, ty = tid >> 4;
  float c[4][4] = {};
  for (int k0 = 0; k0 < Kk; k0 += 16) {
    {
      int r = tid >> 2, k4 = (tid & 3) * 4;
      const float* src = Ab + (size_t)(row0 + r) * Kk + k0 + k4;
      float4 av = *(const float4*)src;
      As[k4 + 0][r] = av.x; As[k4 + 1][r] = av.y; As[k4 + 2][r] = av.z; As[k4 + 3][r] = av.w;
    }
    {
      int rb = tid >> 4, c4 = (tid & 15) * 4;
      const float* src = Bb + (size_t)(k0 + rb) * Nn + col0 + c4;
      float4 bv = *(const float4*)src;
      bv.x *= gbB; bv.y *= gbB; bv.z *= gbB; bv.w *= gbB;
      int kk = k0 + rb;
      if (kk == col0 + c4 + 0) bv.x += gbA;
      if (kk == col0 + c4 + 1) bv.y += gbA;
      if (kk == col0 + c4 + 2) bv.z += gbA;
      if (kk == col0 + c4 + 3) bv.w += gbA;
      *(float4*)&Bs[rb][c4] = bv;
    }
    __syncthreads();
    #pragma unroll
    for (int kk = 0; kk < 16; kk++) {
      float4 a = *(const float4*)&As[kk][ty * 4];
      float4 b = *(const float4*)&Bs[kk][tx * 4];
      float ar[4] = {a.x, a.y, a.z, a.w};
      float br[4] = {b.x, b.y, b.z, b.w};
      #pragma unroll
      for (int i = 0; i < 4; i++)
        #pragma unroll
        for (int j = 0; j < 4; j++) c[i][j] += ar[i] * br[j];
    }
    __syncthreads();
  }
  #pragma unroll
  for (int i = 0; i < 4; i++)
    #pragma unroll
    for (int j = 0; j < 4; j++) {
      int r = row0 + ty * 4 + i, cc = col0 + tx * 4 + j;
      C[(size_t)bh * sC + (size_t)r * Nn + cc] = alpha * (r == cc) + beta * c[i][j];
    }
}

// ---- softmax over rows of 4096 (bf16 in -> bf16 out) ----
__global__ void softmax3_kernel(const bf16* __restrict__ S, bf16* __restrict__ P) {
  __shared__ float red[256];
  int row = blockIdx.x, tid = threadIdx.x;
  const bf16* sr = S + (size_t)row * 4096 + tid * 16;
  u16x8 v0 = *(const u16x8*)sr;
  u16x8 v1 = *(const u16x8*)(sr + 8);
  float vals[16];
  #pragma unroll
  for (int e = 0; e < 8; e++) { vals[e] = u2f(v0[e]); vals[e + 8] = u2f(v1[e]); }
  float lm = -1e30f;
  #pragma unroll
  for (int e = 0; e < 16; e++) lm = fmaxf(lm, vals[e]);
  float mx = bred_max(lm, red);
  float ls = 0;
  #pragma unroll
  for (int e = 0; e < 16; e++) { vals[e] = __expf(vals[e] - mx); ls += vals[e]; }
  float inv = 1.0f / bred_sum(ls, red);
  bf16* pr = P + (size_t)row * 4096 + tid * 16;
  #pragma unroll
  for (int e = 0; e < 16; e++) pr[e] = __float2bfloat16(vals[e] * inv);
}

// ---- fused sim1 + softmax -> P1 f32 [4][4096][256] ----
__global__ __launch_bounds__(256) void attn1_kernel(
    const bf16* __restrict__ q, const bf16* __restrict__ klbf,
    float* __restrict__ P1, int bh0) {
  __shared__ __align__(16) unsigned short Qs[64][72];
  __shared__ __align__(16) unsigned short Ks[256][72];
  __shared__ float redm[4][64];
  __shared__ float reds[4][64];
  int tid = threadIdx.x;
  int bhl = blockIdx.y, bh = bh0 + bhl;
  int n0 = blockIdx.x * 64;
  const bf16* qb = q + ((size_t)bh * NN + n0) * 64;
  const bf16* kb = klbf + (size_t)bh * 16384;
  {
    int r = tid >> 2, s = (tid & 3) * 16;
    *(u16x8*)&Qs[r][s] = *(const u16x8*)(qb + (size_t)r * 64 + s);
    *(u16x8*)&Qs[r][s + 8] = *(const u16x8*)(qb + (size_t)r * 64 + s + 8);
  }
  {
    const bf16* src = kb + (size_t)tid * 64;
    #pragma unroll
    for (int s8 = 0; s8 < 8; s8++) *(u16x8*)&Ks[tid][s8 * 8] = *(const u16x8*)(src + s8 * 8);
  }
  __syncthreads();
  int wave = tid >> 6, lane = tid & 63, l15 = lane & 15, quad = lane >> 4;
  f32x4 acc[4][4] = {};
  #pragma unroll
  for (int kc = 0; kc < 64; kc += 32) {
    bf16x8 af[4], bfr[4];
    #pragma unroll
    for (int i = 0; i < 4; i++) af[i] = *(const bf16x8*)&Qs[i * 16 + l15][kc + quad * 8];
    #pragma unroll
    for (int j = 0; j < 4; j++) bfr[j] = *(const bf16x8*)&Ks[wave * 64 + j * 16 + l15][kc + quad * 8];
    #pragma unroll
    for (int i = 0; i < 4; i++)
      #pragma unroll
      for (int j = 0; j < 4; j++)
        acc[i][j] = __builtin_amdgcn_mfma_f32_16x16x32_bf16(af[i], bfr[j], acc[i][j], 0, 0, 0);
  }
  float lm[4][4], ls[4][4], rinv[4][4];
  #pragma unroll
  for (int i = 0; i < 4; i++)
    #pragma unroll
    for (int reg = 0; reg < 4; reg++) {
      float m = acc[i][0][reg];
      m = fmaxf(m, acc[i][1][reg]); m = fmaxf(m, acc[i][2][reg]); m = fmaxf(m, acc[i][3][reg]);
      lm[i][reg] = m;
    }
  #pragma unroll
  for (int off = 1; off < 16; off <<= 1)
    #pragma unroll
    for (int i = 0; i < 4; i++)
      #pragma unroll
      for (int reg = 0; reg < 4; reg++) lm[i][reg] = fmaxf(lm[i][reg], __shfl_xor(lm[i][reg], off));
  if (l15 == 0)
    #pragma unroll
    for (int i = 0; i < 4; i++)
      #pragma unroll
      for (int reg = 0; reg < 4; reg++) redm[wave][i * 16 + quad * 4 + reg] = lm[i][reg];
  __syncthreads();
  #pragma unroll
  for (int i = 0; i < 4; i++)
    #pragma unroll
    for (int reg = 0; reg < 4; reg++) {
      int r = i * 16 + quad * 4 + reg;
      rinv[i][reg] = fmaxf(fmaxf(redm[0][r], redm[1][r]), fmaxf(redm[2][r], redm[3][r]));
      ls[i][reg] = 0;
    }
  #pragma unroll
  for (int i = 0; i < 4; i++)
    #pragma unroll
    for (int j = 0; j < 4; j++)
      #pragma unroll
      for (int reg = 0; reg < 4; reg++) {
        float e = __expf(acc[i][j][reg] - rinv[i][reg]);
        acc[i][j][reg] = e;
        ls[i][reg] += e;
      }
  #pragma unroll
  for (int off = 1; off < 16; off <<= 1)
    #pragma unroll
    for (int i = 0; i < 4; i++)
      #pragma unroll
      for (int reg = 0; reg < 4; reg++) ls[i][reg] += __shfl_xor(ls[i][reg], off);
  if (l15 == 0)
    #pragma unroll
    for (int i = 0; i < 4; i++)
      #pragma unroll
      for (int reg = 0; reg < 4; reg++) reds[wave][i * 16 + quad * 4 + reg] = ls[i][reg];
  __syncthreads();
  #pragma unroll
  for (int i = 0; i < 4; i++)
    #pragma unroll
    for (int reg = 0; reg < 4; reg++) {
      int r = i * 16 + quad * 4 + reg;
      rinv[i][reg] = 1.0f / (reds[0][r] + reds[1][r] + reds[2][r] + reds[3][r]);
    }
  float* Pb = P1 + ((size_t)bhl * NN + n0) * 256;
  #pragma unroll
  for (int i = 0; i < 4; i++)
    #pragma unroll
    for (int j = 0; j < 4; j++)
      #pragma unroll
      for (int reg = 0; reg < 4; reg++) {
        int r = i * 16 + quad * 4 + reg;
        int col = wave * 64 + j * 16 + l15;
        Pb[(size_t)r * 256 + col] = acc[i][j][reg] * rinv[i][reg];
      }
}

// ---- depthwise conv (33) residual add: y = p1f32 + conv(v), 4-bh chunk ----
__global__ __launch_bounds__(256) void conv_add_kernel(
    const float* __restrict__ p1, const bf16* __restrict__ v,
    const void* __restrict__ wres, bf16* __restrict__ y, const int* __restrict__ dflag,
    int bh0) {
  __shared__ __align__(16) unsigned short Vs[96][64];
  int f = *dflag;
  int tid = threadIdx.x;
  int bhl = blockIdx.y, bh = bh0 + bhl;
  int n0 = blockIdx.x * 64;
  int h = bh & 3, b_ = bh >> 2;
  const bf16* vb = v + (size_t)bh * (NN * 64);
  for (int rr = tid; rr < 384; rr += 256) {
    int r = rr >> 2, s = (rr & 3) * 16;
    int n = n0 - 16 + r;
    if (n >= 0 && n < NN) {
      *(u16x8*)&Vs[r][s] = *(const u16x8*)(vb + (size_t)n * 64 + s);
      *(u16x8*)&Vs[r][s + 8] = *(const u16x8*)(vb + (size_t)n * 64 + s + 8);
    } else {
      u16x8 z = {};
      *(u16x8*)&Vs[r][s] = z; *(u16x8*)&Vs[r][s + 8] = z;
    }
  }
  float w33[33];
  #pragma unroll
  for (int kk = 0; kk < 33; kk++) w33[kk] = ldf(wres, h * 33 + kk, f);
  __syncthreads();
  int d = tid & 63, rb = tid >> 6;
  for (int ii = 0; ii < 16; ii++) {
    int nl = ii * 4 + rb;
    float cv = 0;
    #pragma unroll
    for (int kk = 0; kk < 33; kk++) cv += w33[kk] * u2f(Vs[nl + kk][d]);
    int n = n0 + nl;
    float pv = p1[((size_t)bhl * NN + n) * 64 + d];
    y[((size_t)b_ * NN + n) * 256 + h * 64 + d] = __float2bfloat16(pv + cv);
  }
}

extern "C" void kernel_launch(void* const* d_in, const int* in_sizes, int n_in,
                              void* d_out, int out_size, void* d_ws, size_t ws_size,
                              hipStream_t stream) {
  const void* x     = d_in[0];
  const void* ln_g  = d_in[1];
  const void* ln_b  = d_in[2];
  const void* w_qkv = d_in[3];
  const void* w_out = d_in[4];
  const void* b_out = d_in[5];
  const void* w_res = d_in[6];

  // ---- ws layout (~67.4 MiB; round-4 proved >= ~81 MiB available) ----
  float* ws    = (float*)d_ws;
  float* gmax  = ws;                                   // 2 f
  int*   dflag = (int*)(ws + 2);                       // 1 int
  float* stats = ws + 256;                             // 65536 f
  bf16*  woutT = (bf16*)(stats + 65536);               // 131072 bf16
  float* qlf   = (float*)(stats + 65536 + 65536);      // 524288 f
  float* klf   = qlf + 524288;                         // 524288 f
  bf16*  qlbf  = (bf16*)(klf + 524288);                // 524288 bf16
  bf16*  klbf  = qlbf + 524288;                        // 524288 bf16
  float* a3v   = (float*)(klbf + 524288);              // 524288 f
  float* Wm    = a3v + 524288;                         // 524288 f
  float* a2    = Wm + 524288;                          // 2097152 f (vT scratch alias)
  bf16*  q     = (bf16*)(a2 + 2097152);                // 8388608 bf16
  bf16*  k     = q + 8388608;                          // 8388608 bf16 (y alias)
  bf16*  v     = k + 8388608;                          // 8388608 bf16
  bf16*  y     = k;                                    // alias (k dead after sim3)
  bf16*  vTbuf = (bf16*)a2;                            // 4 MiB chunk scratch in a2 region

  // ---- d_out scratch (<= 32 MiB at all times) ----
  char* dob = (char*)d_out;
  bf16* wqkvT = (bf16*)dob;                            // phase A
  bf16* S3    = (bf16*)dob;                            // 16 MiB
  bf16* P3    = (bf16*)(dob + (16u << 20));            // 16 MiB
  float* W0   = (float*)dob;                           // pinv: 4 x 8 MiB
  float* W1   = (float*)(dob + (8u << 20));
  float* W2   = (float*)(dob + (16u << 20));
  float* W3   = (float*)(dob + (24u << 20));
  float* P1   = (float*)dob;                           // 16 MiB (4 bh chunk, f32)
  float* p1f  = (float*)(dob + (16u << 20));           // 4 MiB  (4 bh chunk, f32)

  detect_kernel<<<1, 256, 0, stream>>>(x, dflag);
  hipMemsetAsync(gmax, 0, 2 * sizeof(float), stream);
  ln_stats_kernel<<<ROWS, 256, 0, stream>>>(x, stats, dflag);

  // weight transposes
  transpose_kernel<<<1536, 256, 0, stream>>>(w_qkv, wqkvT, 512, 768, 0, 0, dflag, -1);
  transpose_kernel<<<512, 256, 0, stream>>>(w_out, woutT, 256, 512, 0, 0, dflag, -1);

  // QKV (LN fused)
  gemm_qkv<<<dim3(256, 6), 256, 0, stream>>>(x, stats, ln_g, ln_b, wqkvT, q, k, v, dflag);

  // landmarks (f32 + bf16)
  landmark_kernel<<<2048, 256, 0, stream>>>(q, qlf, qlbf);
  landmark_kernel<<<2048, 256, 0, stream>>>(k, klf, klbf);

  // sim3 -> softmax -> @v (4 chunks of 8 bh), a3v via split-K f32 atomics
  hipMemsetAsync(a3v, 0, 524288 * sizeof(float), stream);
  for (int c = 0; c < 4; c++) {
    transpose_kernel<<<8192, 256, 0, stream>>>(v + (size_t)c * 8 * 262144, vTbuf,
                                               4096, 64, 262144, 262144, dflag, 0);
    gemm_bt<<<dim3(8, 2, 32), 256, 0, stream>>>(
        qlbf + (size_t)c * 8 * 16384, 64, 16384,
        k + (size_t)c * 8 * 262144, 64, 262144,
        S3, 4096, 1048576, 4096, 64, 32, 1, nullptr, nullptr, dflag);
    softmax3_kernel<<<2048, 256, 0, stream>>>(S3, P3);
    gemm_bt<<<dim3(8, 2, 16), 256, 0, stream>>>(
        P3, 4096, 1048576, vTbuf, 4096, 262144,
        a3v + (size_t)c * 131072, 64, 16384, 64, 256, 1, 2, nullptr, nullptr, dflag);
  }

  // a2 path (f32 landmarks) + pinv in d_out
  a2_kernel<<<8192, 256, 0, stream>>>(qlf, klf, a2);
  colsum_max_kernel<<<32, 256, 0, stream>>>(a2, gmax);
  zinit_kernel<<<8192, 256, 0, stream>>>(a2, gmax, W0);

  float* zi = W0; float* f1 = W1; float* f2 = W2; float* f3 = W3;
  for (int it = 0; it < 6; it++) {
    bmm64<<<dim3(32, 4, 4), 256, 0, stream>>>(a2, zi, f1, 256, 256, 65536, 65536, 65536, 0.f, 1.f, 0.f, 1.f);
    bmm64<<<dim3(32, 4, 4), 256, 0, stream>>>(f1, f1, f2, 256, 256, 65536, 65536, 65536, 15.f, -1.f, 7.f, -1.f);
    bmm64<<<dim3(32, 4, 4), 256, 0, stream>>>(f1, f2, f3, 256, 256, 65536, 65536, 65536, 13.f, -1.f, 0.f, 1.f);
    bmm64<<<dim3(32, 4, 4), 256, 0, stream>>>(zi, f3, f2, 256, 256, 65536, 65536, 65536, 0.f, 0.25f, 0.f, 1.f);
    float* nzi = f2; f2 = f1; f1 = zi; zi = nzi;
  }

  // Wm = z6 @ a3v -> f32 in ws (before d_out reuse)
  bmm64<<<dim3(32, 4, 1), 256, 0, stream>>>(zi, a3v, Wm, 64, 256, 65536, 16384, 16384, 0.f, 1.f, 0.f, 1.f);

  // a1 softmax (f32 P1) + f32 PV1 + conv residual, 8 chunks of 4 bh
  for (int c = 0; c < 8; c++) {
    attn1_kernel<<<dim3(64, 4), 256, 0, stream>>>(q, klbf, P1, c * 4);
    bmm64<<<dim3(4, 64, 1), 256, 0, stream>>>(
        P1, Wm + (size_t)c * 4 * 16384, p1f,
        64, 256, 1048576, 16384, 262144, 0.f, 1.f, 0.f, 1.f);
    conv_add_kernel<<<dim3(64, 4), 256, 0, stream>>>(p1f, v, w_res, y, dflag, c * 4);
  }

  // out = y @ w_out + b_out + x -> d_out (dtype-adaptive)
  gemm_bt<<<dim3(1, 256, 4), 256, 0, stream>>>(
      y, 256, 0, woutT, 256, 0,
      d_out, 512, 0, 512, 256, 4, 3, b_out, x, dflag);
}

// Round 4
// 1219.002 us; speedup vs baseline: 1.4429x; 1.1275x over previous
//
#include <hip/hip_runtime.h>
#include <hip/hip_bf16.h>
#include <string.h>

typedef __hip_bfloat16 bf16;
typedef __attribute__((ext_vector_type(8))) __bf16 bf16x8;
typedef __attribute__((ext_vector_type(4))) float f32x4;
typedef __attribute__((ext_vector_type(8))) unsigned short u16x8;

#define NN 4096
#define DD 512
#define MM 256
#define ROWS 32768

__device__ __forceinline__ float b2f(bf16 x) { return __bfloat162float(x); }
__device__ __forceinline__ float u2f(unsigned short u) {
  return __uint_as_float(((unsigned int)u) << 16);
}
__device__ __forceinline__ unsigned short f2bu(float v) {
  bf16 h = __float2bfloat16(v);
  return *reinterpret_cast<unsigned short*>(&h);
}
// adaptive input load / output store (f==1 -> float32, f==0 -> bf16)
__device__ __forceinline__ float ldf(const void* p, size_t i, int f) {
  return f ? ((const float*)p)[i] : __bfloat162float(((const bf16*)p)[i]);
}
__device__ __forceinline__ void stf(void* p, size_t i, float v, int f) {
  if (f) ((float*)p)[i] = v;
  else ((bf16*)p)[i] = __float2bfloat16(v);
}

// ---- dtype detection ----
__global__ void detect_kernel(const void* x, int* flag) {
  __shared__ int red[256];
  int tid = threadIdx.x;
  const unsigned short* u = (const unsigned short*)x;
  int local = 0;
  for (int i = 0; i < 32; i++) {
    unsigned short e = (u[tid * 32 + i] >> 7) & 0xFF;
    if (e >= 0xC8) local++;
  }
  red[tid] = local; __syncthreads();
  #pragma unroll
  for (int s = 128; s > 0; s >>= 1) {
    if (tid < s) red[tid] += red[tid + s];
    __syncthreads();
  }
  if (tid == 0) *flag = (red[0] > 32) ? 1 : 0;
}

// ---- block reductions ----
__device__ __forceinline__ float bred_max(float v, float* red) {
  int tid = threadIdx.x;
  red[tid] = v; __syncthreads();
  #pragma unroll
  for (int s = 128; s > 0; s >>= 1) {
    if (tid < s) red[tid] = fmaxf(red[tid], red[tid + s]);
    __syncthreads();
  }
  float r = red[0]; __syncthreads();
  return r;
}
__device__ __forceinline__ float bred_sum(float v, float* red) {
  int tid = threadIdx.x;
  red[tid] = v; __syncthreads();
  #pragma unroll
  for (int s = 128; s > 0; s >>= 1) {
    if (tid < s) red[tid] += red[tid + s];
    __syncthreads();
  }
  float r = red[0]; __syncthreads();
  return r;
}

// ---- LayerNorm stats ----
__global__ void ln_stats_kernel(const void* __restrict__ x, float* __restrict__ stats,
                                const int* dflag) {
  __shared__ float red[256];
  int f = *dflag;
  int row = blockIdx.x, tid = threadIdx.x;
  size_t base = (size_t)row * DD;
  float v0 = ldf(x, base + tid, f);
  float v1 = ldf(x, base + tid + 256, f);
  float mean = bred_sum(v0 + v1, red) * (1.0f / DD);
  float d0 = v0 - mean, d1 = v1 - mean;
  float var = bred_sum(d0 * d0 + d1 * d1, red) * (1.0f / DD);
  if (tid == 0) {
    stats[row * 2] = mean;
    stats[row * 2 + 1] = rsqrtf(var + 1e-5f);
  }
}

// ---- generic transpose -> bf16 out: out[b][c][r] = in[b][r][c] ----
__global__ void transpose_kernel(const void* __restrict__ in, bf16* __restrict__ out,
                                 int R, int Cc, long sIn, long sOut,
                                 const int* dflag, int ovr) {
  int f = (ovr >= 0) ? ovr : *dflag;
  size_t o = (size_t)blockIdx.x * 256 + threadIdx.x;
  size_t per = (size_t)R * Cc;
  size_t b = o / per, rem = o % per;
  size_t c = rem / R, r = rem % R;
  out[b * sOut + c * (size_t)R + r] = __float2bfloat16(ldf(in, b * sIn + r * (size_t)Cc + c, f));
}

// ---- QKV GEMM: MFMA, LN fused on A-stage (vectorized), scatter epilogue ----
__global__ __launch_bounds__(256) void gemm_qkv(
    const void* __restrict__ x, const float* __restrict__ stats,
    const void* __restrict__ g, const void* __restrict__ bb,
    const bf16* __restrict__ wT,  // [768][512]
    bf16* __restrict__ q, bf16* __restrict__ k, bf16* __restrict__ v,
    const int* __restrict__ dflag) {
  __shared__ __align__(16) unsigned short As[128][40];
  __shared__ __align__(16) unsigned short Bs[128][40];
  __shared__ __align__(16) float gls[512];
  __shared__ __align__(16) float bls[512];
  int f = *dflag;
  int tid = threadIdx.x;
  // one-time g/bb stage into LDS
  {
    int c0 = tid, c1 = tid + 256;
    gls[c0] = ldf(g, c0, f);  gls[c1] = ldf(g, c1, f);
    bls[c0] = ldf(bb, c0, f); bls[c1] = ldf(bb, c1, f);
  }
  int m0 = blockIdx.x * 128, n0 = blockIdx.y * 128;
  int sr = tid >> 1, sh = (tid & 1) * 16;
  int wave = tid >> 6, lane = tid & 63;
  int wm = (wave & 1) * 64, wn = (wave >> 1) * 64;
  int l15 = lane & 15, quad = lane >> 4;
  int r = m0 + sr;
  float mu = stats[r * 2], rs = stats[r * 2 + 1];   // loop-invariant
  const float* xf = (const float*)x + (size_t)r * DD;
  const bf16*  xb = (const bf16*)x  + (size_t)r * DD;
  __syncthreads();  // gls/bls ready
  f32x4 acc[4][4] = {};
  for (int k0 = 0; k0 < 512; k0 += 32) {
    {
      // vectorized x load
      float xv[16];
      if (f) {
        const float* src = xf + k0 + sh;
        float4 t0 = *(const float4*)(src);
        float4 t1 = *(const float4*)(src + 4);
        float4 t2 = *(const float4*)(src + 8);
        float4 t3 = *(const float4*)(src + 12);
        xv[0] = t0.x; xv[1] = t0.y; xv[2]  = t0.z; xv[3]  = t0.w;
        xv[4] = t1.x; xv[5] = t1.y; xv[6]  = t1.z; xv[7]  = t1.w;
        xv[8] = t2.x; xv[9] = t2.y; xv[10] = t2.z; xv[11] = t2.w;
        xv[12] = t3.x; xv[13] = t3.y; xv[14] = t3.z; xv[15] = t3.w;
      } else {
        const bf16* src = xb + k0 + sh;
        u16x8 t0 = *(const u16x8*)(src);
        u16x8 t1 = *(const u16x8*)(src + 8);
        #pragma unroll
        for (int e = 0; e < 8; e++) { xv[e] = u2f(t0[e]); xv[8 + e] = u2f(t1[e]); }
      }
      // LN as 2 FMA/elem: a = rs*g;  out = x*a + (bb - mu*a)
      float gv[16], bv[16];
      {
        const float* gp = &gls[k0 + sh];
        const float* bp = &bls[k0 + sh];
        #pragma unroll
        for (int e4 = 0; e4 < 4; e4++) {
          float4 gt = *(const float4*)(gp + e4 * 4);
          float4 bt = *(const float4*)(bp + e4 * 4);
          gv[e4 * 4 + 0] = gt.x; gv[e4 * 4 + 1] = gt.y; gv[e4 * 4 + 2] = gt.z; gv[e4 * 4 + 3] = gt.w;
          bv[e4 * 4 + 0] = bt.x; bv[e4 * 4 + 1] = bt.y; bv[e4 * 4 + 2] = bt.z; bv[e4 * 4 + 3] = bt.w;
        }
      }
      u16x8 w0, w1;
      #pragma unroll
      for (int e = 0; e < 8; e++) {
        float a0 = rs * gv[e];
        float a1 = rs * gv[e + 8];
        w0[e] = f2bu(xv[e] * a0 + (bv[e] - mu * a0));
        w1[e] = f2bu(xv[e + 8] * a1 + (bv[e + 8] - mu * a1));
      }
      *(u16x8*)&As[sr][sh] = w0;
      *(u16x8*)&As[sr][sh + 8] = w1;
    }
    {
      const bf16* src = wT + (size_t)(n0 + sr) * 512 + k0 + sh;
      *(u16x8*)&Bs[sr][sh] = *(const u16x8*)src;
      *(u16x8*)&Bs[sr][sh + 8] = *(const u16x8*)(src + 8);
    }
    __syncthreads();
    bf16x8 af[4], bfr[4];
    #pragma unroll
    for (int i = 0; i < 4; i++) af[i] = *(const bf16x8*)&As[wm + i * 16 + l15][quad * 8];
    #pragma unroll
    for (int j = 0; j < 4; j++) bfr[j] = *(const bf16x8*)&Bs[wn + j * 16 + l15][quad * 8];
    #pragma unroll
    for (int i = 0; i < 4; i++)
      #pragma unroll
      for (int j = 0; j < 4; j++)
        acc[i][j] = __builtin_amdgcn_mfma_f32_16x16x32_bf16(af[i], bfr[j], acc[i][j], 0, 0, 0);
    __syncthreads();
  }
  #pragma unroll
  for (int i = 0; i < 4; i++)
    #pragma unroll
    for (int j = 0; j < 4; j++)
      #pragma unroll
      for (int reg = 0; reg < 4; reg++) {
        int row = m0 + wm + i * 16 + quad * 4 + reg;
        int c = n0 + wn + j * 16 + l15;
        int which = c >> 8, within = c & 255, h = within >> 6, d = within & 63;
        int b_ = row >> 12, n = row & 4095;
        size_t idx = ((size_t)(b_ * 4 + h) * NN + n) * 64 + d;
        float val = acc[i][j][reg];
        if (which == 0) q[idx] = __float2bfloat16(val * 0.125f);
        else if (which == 1) k[idx] = __float2bfloat16(val);
        else v[idx] = __float2bfloat16(val);
      }
}

// ---- generic batched MFMA GEMM: C = A[M x K] @ Bt[N x K]^T ----
// modes: 0=f32 store, 1=bf16 store, 2=f32 atomicAdd (split-K), 3=bias+residual+dtype store
__global__ __launch_bounds__(256) void gemm_bt(
    const bf16* __restrict__ A, long ldA, long sA,
    const bf16* __restrict__ Bt, long ldB, long sB,
    void* __restrict__ C, long ldC, long sC,
    int N, int kLen, int nTiles, int mode,
    const void* __restrict__ bias, const void* __restrict__ resid,
    const int* __restrict__ dflag) {
  __shared__ __align__(16) unsigned short As[128][40];
  __shared__ __align__(16) unsigned short Bs[128][40];
  int tid = threadIdx.x;
  int b = blockIdx.x;
  int m0 = blockIdx.y * 128;
  int nt = blockIdx.z % nTiles, ks = blockIdx.z / nTiles;
  int n0 = nt * 128;
  long k0b = (long)ks * kLen;
  const bf16* Ab = A + (size_t)b * sA;
  const bf16* Bb = Bt + (size_t)b * sB;
  int sr = tid >> 1, sh = (tid & 1) * 16;
  int wave = tid >> 6, lane = tid & 63;
  int wm = (wave & 1) * 64, wn = (wave >> 1) * 64;
  int l15 = lane & 15, quad = lane >> 4;
  f32x4 acc[4][4] = {};
  for (int kc = 0; kc < kLen; kc += 32) {
    long k0 = k0b + kc;
    {
      const bf16* src = Ab + (size_t)(m0 + sr) * ldA + k0 + sh;
      *(u16x8*)&As[sr][sh] = *(const u16x8*)src;
      *(u16x8*)&As[sr][sh + 8] = *(const u16x8*)(src + 8);
    }
    if (n0 + sr < N) {
      const bf16* src = Bb + (size_t)(n0 + sr) * ldB + k0 + sh;
      *(u16x8*)&Bs[sr][sh] = *(const u16x8*)src;
      *(u16x8*)&Bs[sr][sh + 8] = *(const u16x8*)(src + 8);
    } else {
      u16x8 z = {};
      *(u16x8*)&Bs[sr][sh] = z;
      *(u16x8*)&Bs[sr][sh + 8] = z;
    }
    __syncthreads();
    bf16x8 af[4], bfr[4];
    #pragma unroll
    for (int i = 0; i < 4; i++) af[i] = *(const bf16x8*)&As[wm + i * 16 + l15][quad * 8];
    #pragma unroll
    for (int j = 0; j < 4; j++) bfr[j] = *(const bf16x8*)&Bs[wn + j * 16 + l15][quad * 8];
    #pragma unroll
    for (int i = 0; i < 4; i++)
      #pragma unroll
      for (int j = 0; j < 4; j++)
        acc[i][j] = __builtin_amdgcn_mfma_f32_16x16x32_bf16(af[i], bfr[j], acc[i][j], 0, 0, 0);
    __syncthreads();
  }
  int f = (mode == 3) ? *dflag : 0;
  #pragma unroll
  for (int i = 0; i < 4; i++)
    #pragma unroll
    for (int j = 0; j < 4; j++)
      #pragma unroll
      for (int reg = 0; reg < 4; reg++) {
        int row = m0 + wm + i * 16 + quad * 4 + reg;
        int col = n0 + wn + j * 16 + l15;
        if (col < N) {
          float val = acc[i][j][reg];
          size_t off = (size_t)row * ldC + col;
          if (mode == 0) (((float*)C) + (size_t)b * sC)[off] = val;
          else if (mode == 1) (((bf16*)C) + (size_t)b * sC)[off] = __float2bfloat16(val);
          else if (mode == 2) atomicAdd(((float*)C) + (size_t)b * sC + off, val);
          else {
            val += ldf(bias, col, f) + ldf(resid, off, f);
            stf(C, off, val, f);
          }
        }
      }
}

// ---- landmark means: bf16 src -> f32 dst (for a2/pinv) AND bf16 dst (for MFMA) ----
__global__ void landmark_kernel(const bf16* __restrict__ src, float* __restrict__ dstf,
                                bf16* __restrict__ dstb) {
  int idx = blockIdx.x * 256 + threadIdx.x;  // 524288
  int d = idx & 63, j = (idx >> 6) & 255, bh = idx >> 14;
  const bf16* s = src + ((size_t)bh * NN + j * 16) * 64 + d;
  float a = 0;
  #pragma unroll
  for (int i = 0; i < 16; i++) a += b2f(s[i * 64]);
  a *= (1.0f / 16);
  dstf[idx] = a;
  dstb[idx] = __float2bfloat16(a);
}

// ---- a2 = softmax(ql @ kl^T) f32, f32 inputs (pinv-sensitive path) ----
__global__ void a2_kernel(const float* __restrict__ ql, const float* __restrict__ kl,
                          float* __restrict__ a2) {
  __shared__ float qs[64];
  __shared__ float red[256];
  int bh = blockIdx.x >> 8, i = blockIdx.x & 255, tid = threadIdx.x;
  if (tid < 64) qs[tid] = ql[((size_t)bh * MM + i) * 64 + tid];
  __syncthreads();
  const float* kr = kl + ((size_t)bh * MM + tid) * 64;
  float s = 0;
  #pragma unroll
  for (int d = 0; d < 64; d++) s += qs[d] * kr[d];
  float mx = bred_max(s, red);
  float e = __expf(s - mx);
  float sm = bred_sum(e, red);
  a2[((size_t)bh * MM + i) * MM + tid] = e / sm;
}

// ---- max over column-sums of a2 (row-sums of softmax are exactly 1, skipped) ----
// 32 blocks (one per bh); thread j owns column j (coalesced); 1 atomic per block.
__global__ void colsum_max_kernel(const float* __restrict__ a2, float* __restrict__ gmax) {
  __shared__ float red[256];
  int bh = blockIdx.x, tid = threadIdx.x;
  const float* base = a2 + (size_t)bh * MM * MM + tid;
  float s0 = 0, s1 = 0, s2 = 0, s3 = 0, s4 = 0, s5 = 0, s6 = 0, s7 = 0;
  for (int i = 0; i < 256; i += 8) {
    s0 += base[(size_t)(i + 0) * MM];
    s1 += base[(size_t)(i + 1) * MM];
    s2 += base[(size_t)(i + 2) * MM];
    s3 += base[(size_t)(i + 3) * MM];
    s4 += base[(size_t)(i + 4) * MM];
    s5 += base[(size_t)(i + 5) * MM];
    s6 += base[(size_t)(i + 6) * MM];
    s7 += base[(size_t)(i + 7) * MM];
  }
  float tot = ((s0 + s1) + (s2 + s3)) + ((s4 + s5) + (s6 + s7));
  float mx = bred_max(tot, red);
  if (tid == 0) atomicMax((int*)gmax + 1, __float_as_int(mx));
}

__global__ void zinit_kernel(const float* __restrict__ a2, const float* __restrict__ gmax,
                             float* __restrict__ z) {
  int idx = blockIdx.x * 256 + threadIdx.x;
  int j = idx & 255, i = (idx >> 8) & 255, bh = idx >> 16;
  float scale = 1.0f / gmax[1];   // max(row-sums) == 1 exactly (softmax rows)
  z[idx] = a2[((size_t)bh * MM + j) * MM + i] * scale;
}

// ---- MFMA split-bf16 batched 64x64-tile GEMM (drop-in replacement for bmm64) ----
// C = alpha*I + beta*(A @ (gbA*I + gbB*B)); A [M][Kk] f32 row-major (ld=Kk),
// B [Kk][Nn] f32 row-major (ld=Nn). Split-3 bf16 MFMA: A=Ah+Al, B'=Bh+Bl,
// acc += Ah*Bh + Ah*Bl + Al*Bh  (dropped Al*Bl ~2^-18 rel => f32-class accuracy).
// B transposed into LDS at stage time (scalar b16 writes).
// NOTE (historical): a round-6 "Nn-guard" here was an LDS-OOB bug; do not reintroduce.
__global__ __launch_bounds__(256) void bmm64_mfma(
    const float* __restrict__ A, const float* __restrict__ B_,
    float* __restrict__ C,
    int Nn, int Kk, long sA, long sB, long sC,
    float alpha, float beta, float gbA, float gbB) {
  __shared__ __align__(16) unsigned short Ah[64][40];
  __shared__ __align__(16) unsigned short Al[64][40];
  __shared__ __align__(16) unsigned short Bh[64][40];
  __shared__ __align__(16) unsigned short Bl[64][40];
  int bh = blockIdx.x;
  int row0 = blockIdx.y * 64, col0 = blockIdx.z * 64;
  const float* Ab = A + (size_t)bh * sA;
  const float* Bb = B_ + (size_t)bh * sB;
  int tid = threadIdx.x;
  int wave = tid >> 6, lane = tid & 63, l15 = lane & 15, quad = lane >> 4;
  int wm = (wave & 1) * 32, wn = (wave >> 1) * 32;
  int ar2 = tid >> 2, kq = (tid & 3) * 8;   // A-stage: 64 rows x 32 k
  int kr = tid >> 3, n8 = (tid & 7) * 8;    // B-stage: 32 k-rows x 64 n
  f32x4 acc[2][2] = {};
  for (int k0 = 0; k0 < Kk; k0 += 32) {
    {
      const float* src = Ab + (size_t)(row0 + ar2) * Kk + k0 + kq;
      u16x8 hi, lo;
      #pragma unroll
      for (int e = 0; e < 8; e++) {
        float a = src[e];
        unsigned short h = f2bu(a);
        hi[e] = h;
        lo[e] = f2bu(a - u2f(h));
      }
      *(u16x8*)&Ah[ar2][kq] = hi;
      *(u16x8*)&Al[ar2][kq] = lo;
    }
    {
      const float* src = Bb + (size_t)(k0 + kr) * Nn + col0 + n8;
      int kk = k0 + kr;
      #pragma unroll
      for (int e = 0; e < 8; e++) {
        float b = gbB * src[e];
        if (kk == col0 + n8 + e) b += gbA;
        unsigned short h = f2bu(b);
        Bh[n8 + e][kr] = h;
        Bl[n8 + e][kr] = f2bu(b - u2f(h));
      }
    }
    __syncthreads();
    bf16x8 ah[2], al[2], bhf[2], blf[2];
    #pragma unroll
    for (int i = 0; i < 2; i++) {
      ah[i]  = *(const bf16x8*)&Ah[wm + i * 16 + l15][quad * 8];
      al[i]  = *(const bf16x8*)&Al[wm + i * 16 + l15][quad * 8];
      bhf[i] = *(const bf16x8*)&Bh[wn + i * 16 + l15][quad * 8];
      blf[i] = *(const bf16x8*)&Bl[wn + i * 16 + l15][quad * 8];
    }
    #pragma unroll
    for (int i = 0; i < 2; i++)
      #pragma unroll
      for (int j = 0; j < 2; j++) {
        acc[i][j] = __builtin_amdgcn_mfma_f32_16x16x32_bf16(ah[i], bhf[j], acc[i][j], 0, 0, 0);
        acc[i][j] = __builtin_amdgcn_mfma_f32_16x16x32_bf16(ah[i], blf[j], acc[i][j], 0, 0, 0);
        acc[i][j] = __builtin_amdgcn_mfma_f32_16x16x32_bf16(al[i], bhf[j], acc[i][j], 0, 0, 0);
      }
    __syncthreads();
  }
  #pragma unroll
  for (int i = 0; i < 2; i++)
    #pragma unroll
    for (int j = 0; j < 2; j++)
      #pragma unroll
      for (int reg = 0; reg < 4; reg++) {
        int r = row0 + wm + i * 16 + quad * 4 + reg;
        int cc = col0 + wn + j * 16 + l15;
        C[(size_t)bh * sC + (size_t)r * Nn + cc] = alpha * (r == cc) + beta * acc[i][j][reg];
      }
}

// ---- softmax over rows of 4096 (bf16 in -> bf16 out) ----
__global__ void softmax3_kernel(const bf16* __restrict__ S, bf16* __restrict__ P) {
  __shared__ float red[256];
  int row = blockIdx.x, tid = threadIdx.x;
  const bf16* sr = S + (size_t)row * 4096 + tid * 16;
  u16x8 v0 = *(const u16x8*)sr;
  u16x8 v1 = *(const u16x8*)(sr + 8);
  float vals[16];
  #pragma unroll
  for (int e = 0; e < 8; e++) { vals[e] = u2f(v0[e]); vals[e + 8] = u2f(v1[e]); }
  float lm = -1e30f;
  #pragma unroll
  for (int e = 0; e < 16; e++) lm = fmaxf(lm, vals[e]);
  float mx = bred_max(lm, red);
  float ls = 0;
  #pragma unroll
  for (int e = 0; e < 16; e++) { vals[e] = __expf(vals[e] - mx); ls += vals[e]; }
  float inv = 1.0f / bred_sum(ls, red);
  bf16* pr = P + (size_t)row * 4096 + tid * 16;
  #pragma unroll
  for (int e = 0; e < 16; e++) pr[e] = __float2bfloat16(vals[e] * inv);
}

// ---- fused sim1 + softmax -> P1 f32 [4][4096][256] ----
__global__ __launch_bounds__(256) void attn1_kernel(
    const bf16* __restrict__ q, const bf16* __restrict__ klbf,
    float* __restrict__ P1, int bh0) {
  __shared__ __align__(16) unsigned short Qs[64][72];
  __shared__ __align__(16) unsigned short Ks[256][72];
  __shared__ float redm[4][64];
  __shared__ float reds[4][64];
  int tid = threadIdx.x;
  int bhl = blockIdx.y, bh = bh0 + bhl;
  int n0 = blockIdx.x * 64;
  const bf16* qb = q + ((size_t)bh * NN + n0) * 64;
  const bf16* kb = klbf + (size_t)bh * 16384;
  {
    int r = tid >> 2, s = (tid & 3) * 16;
    *(u16x8*)&Qs[r][s] = *(const u16x8*)(qb + (size_t)r * 64 + s);
    *(u16x8*)&Qs[r][s + 8] = *(const u16x8*)(qb + (size_t)r * 64 + s + 8);
  }
  {
    const bf16* src = kb + (size_t)tid * 64;
    #pragma unroll
    for (int s8 = 0; s8 < 8; s8++) *(u16x8*)&Ks[tid][s8 * 8] = *(const u16x8*)(src + s8 * 8);
  }
  __syncthreads();
  int wave = tid >> 6, lane = tid & 63, l15 = lane & 15, quad = lane >> 4;
  f32x4 acc[4][4] = {};
  #pragma unroll
  for (int kc = 0; kc < 64; kc += 32) {
    bf16x8 af[4], bfr[4];
    #pragma unroll
    for (int i = 0; i < 4; i++) af[i] = *(const bf16x8*)&Qs[i * 16 + l15][kc + quad * 8];
    #pragma unroll
    for (int j = 0; j < 4; j++) bfr[j] = *(const bf16x8*)&Ks[wave * 64 + j * 16 + l15][kc + quad * 8];
    #pragma unroll
    for (int i = 0; i < 4; i++)
      #pragma unroll
      for (int j = 0; j < 4; j++)
        acc[i][j] = __builtin_amdgcn_mfma_f32_16x16x32_bf16(af[i], bfr[j], acc[i][j], 0, 0, 0);
  }
  float lm[4][4], ls[4][4], rinv[4][4];
  #pragma unroll
  for (int i = 0; i < 4; i++)
    #pragma unroll
    for (int reg = 0; reg < 4; reg++) {
      float m = acc[i][0][reg];
      m = fmaxf(m, acc[i][1][reg]); m = fmaxf(m, acc[i][2][reg]); m = fmaxf(m, acc[i][3][reg]);
      lm[i][reg] = m;
    }
  #pragma unroll
  for (int off = 1; off < 16; off <<= 1)
    #pragma unroll
    for (int i = 0; i < 4; i++)
      #pragma unroll
      for (int reg = 0; reg < 4; reg++) lm[i][reg] = fmaxf(lm[i][reg], __shfl_xor(lm[i][reg], off));
  if (l15 == 0)
    #pragma unroll
    for (int i = 0; i < 4; i++)
      #pragma unroll
      for (int reg = 0; reg < 4; reg++) redm[wave][i * 16 + quad * 4 + reg] = lm[i][reg];
  __syncthreads();
  #pragma unroll
  for (int i = 0; i < 4; i++)
    #pragma unroll
    for (int reg = 0; reg < 4; reg++) {
      int r = i * 16 + quad * 4 + reg;
      rinv[i][reg] = fmaxf(fmaxf(redm[0][r], redm[1][r]), fmaxf(redm[2][r], redm[3][r]));
      ls[i][reg] = 0;
    }
  #pragma unroll
  for (int i = 0; i < 4; i++)
    #pragma unroll
    for (int j = 0; j < 4; j++)
      #pragma unroll
      for (int reg = 0; reg < 4; reg++) {
        float e = __expf(acc[i][j][reg] - rinv[i][reg]);
        acc[i][j][reg] = e;
        ls[i][reg] += e;
      }
  #pragma unroll
  for (int off = 1; off < 16; off <<= 1)
    #pragma unroll
    for (int i = 0; i < 4; i++)
      #pragma unroll
      for (int reg = 0; reg < 4; reg++) ls[i][reg] += __shfl_xor(ls[i][reg], off);
  if (l15 == 0)
    #pragma unroll
    for (int i = 0; i < 4; i++)
      #pragma unroll
      for (int reg = 0; reg < 4; reg++) reds[wave][i * 16 + quad * 4 + reg] = ls[i][reg];
  __syncthreads();
  #pragma unroll
  for (int i = 0; i < 4; i++)
    #pragma unroll
    for (int reg = 0; reg < 4; reg++) {
      int r = i * 16 + quad * 4 + reg;
      rinv[i][reg] = 1.0f / (reds[0][r] + reds[1][r] + reds[2][r] + reds[3][r]);
    }
  float* Pb = P1 + ((size_t)bhl * NN + n0) * 256;
  #pragma unroll
  for (int i = 0; i < 4; i++)
    #pragma unroll
    for (int j = 0; j < 4; j++)
      #pragma unroll
      for (int reg = 0; reg < 4; reg++) {
        int r = i * 16 + quad * 4 + reg;
        int col = wave * 64 + j * 16 + l15;
        Pb[(size_t)r * 256 + col] = acc[i][j][reg] * rinv[i][reg];
      }
}

// ---- depthwise conv (33) residual add: y = p1f32 + conv(v), 4-bh chunk ----
__global__ __launch_bounds__(256) void conv_add_kernel(
    const float* __restrict__ p1, const bf16* __restrict__ v,
    const void* __restrict__ wres, bf16* __restrict__ y, const int* __restrict__ dflag,
    int bh0) {
  __shared__ __align__(16) unsigned short Vs[96][64];
  int f = *dflag;
  int tid = threadIdx.x;
  int bhl = blockIdx.y, bh = bh0 + bhl;
  int n0 = blockIdx.x * 64;
  int h = bh & 3, b_ = bh >> 2;
  const bf16* vb = v + (size_t)bh * (NN * 64);
  for (int rr = tid; rr < 384; rr += 256) {
    int r = rr >> 2, s = (rr & 3) * 16;
    int n = n0 - 16 + r;
    if (n >= 0 && n < NN) {
      *(u16x8*)&Vs[r][s] = *(const u16x8*)(vb + (size_t)n * 64 + s);
      *(u16x8*)&Vs[r][s + 8] = *(const u16x8*)(vb + (size_t)n * 64 + s + 8);
    } else {
      u16x8 z = {};
      *(u16x8*)&Vs[r][s] = z; *(u16x8*)&Vs[r][s + 8] = z;
    }
  }
  float w33[33];
  #pragma unroll
  for (int kk = 0; kk < 33; kk++) w33[kk] = ldf(wres, h * 33 + kk, f);
  __syncthreads();
  int d = tid & 63, rb = tid >> 6;
  for (int ii = 0; ii < 16; ii++) {
    int nl = ii * 4 + rb;
    float cv = 0;
    #pragma unroll
    for (int kk = 0; kk < 33; kk++) cv += w33[kk] * u2f(Vs[nl + kk][d]);
    int n = n0 + nl;
    float pv = p1[((size_t)bhl * NN + n) * 64 + d];
    y[((size_t)b_ * NN + n) * 256 + h * 64 + d] = __float2bfloat16(pv + cv);
  }
}

extern "C" void kernel_launch(void* const* d_in, const int* in_sizes, int n_in,
                              void* d_out, int out_size, void* d_ws, size_t ws_size,
                              hipStream_t stream) {
  const void* x     = d_in[0];
  const void* ln_g  = d_in[1];
  const void* ln_b  = d_in[2];
  const void* w_qkv = d_in[3];
  const void* w_out = d_in[4];
  const void* b_out = d_in[5];
  const void* w_res = d_in[6];

  // ---- ws layout (~67.4 MiB; round-4 proved >= ~81 MiB available) ----
  float* ws    = (float*)d_ws;
  float* gmax  = ws;                                   // 2 f
  int*   dflag = (int*)(ws + 2);                       // 1 int
  float* stats = ws + 256;                             // 65536 f
  bf16*  woutT = (bf16*)(stats + 65536);               // 131072 bf16
  float* qlf   = (float*)(stats + 65536 + 65536);      // 524288 f
  float* klf   = qlf + 524288;                         // 524288 f
  bf16*  qlbf  = (bf16*)(klf + 524288);                // 524288 bf16
  bf16*  klbf  = qlbf + 524288;                        // 524288 bf16
  float* a3v   = (float*)(klbf + 524288);              // 524288 f
  float* Wm    = a3v + 524288;                         // 524288 f
  float* a2    = Wm + 524288;                          // 2097152 f (vT scratch alias)
  bf16*  q     = (bf16*)(a2 + 2097152);                // 8388608 bf16
  bf16*  k     = q + 8388608;                          // 8388608 bf16 (y alias)
  bf16*  v     = k + 8388608;                          // 8388608 bf16
  bf16*  y     = k;                                    // alias (k dead after sim3)
  bf16*  vTbuf = (bf16*)a2;                            // 4 MiB chunk scratch in a2 region

  // ---- d_out scratch (<= 32 MiB at all times) ----
  char* dob = (char*)d_out;
  bf16* wqkvT = (bf16*)dob;                            // phase A
  bf16* S3    = (bf16*)dob;                            // 16 MiB
  bf16* P3    = (bf16*)(dob + (16u << 20));            // 16 MiB
  float* W0   = (float*)dob;                           // pinv: 4 x 8 MiB
  float* W1   = (float*)(dob + (8u << 20));
  float* W2   = (float*)(dob + (16u << 20));
  float* W3   = (float*)(dob + (24u << 20));
  float* P1   = (float*)dob;                           // 16 MiB (4 bh chunk, f32)
  float* p1f  = (float*)(dob + (16u << 20));           // 4 MiB  (4 bh chunk, f32)

  detect_kernel<<<1, 256, 0, stream>>>(x, dflag);
  hipMemsetAsync(gmax, 0, 2 * sizeof(float), stream);
  ln_stats_kernel<<<ROWS, 256, 0, stream>>>(x, stats, dflag);

  // weight transposes
  transpose_kernel<<<1536, 256, 0, stream>>>(w_qkv, wqkvT, 512, 768, 0, 0, dflag, -1);
  transpose_kernel<<<512, 256, 0, stream>>>(w_out, woutT, 256, 512, 0, 0, dflag, -1);

  // QKV (LN fused)
  gemm_qkv<<<dim3(256, 6), 256, 0, stream>>>(x, stats, ln_g, ln_b, wqkvT, q, k, v, dflag);

  // landmarks (f32 + bf16)
  landmark_kernel<<<2048, 256, 0, stream>>>(q, qlf, qlbf);
  landmark_kernel<<<2048, 256, 0, stream>>>(k, klf, klbf);

  // sim3 -> softmax -> @v (4 chunks of 8 bh), a3v via split-K f32 atomics
  hipMemsetAsync(a3v, 0, 524288 * sizeof(float), stream);
  for (int c = 0; c < 4; c++) {
    transpose_kernel<<<8192, 256, 0, stream>>>(v + (size_t)c * 8 * 262144, vTbuf,
                                               4096, 64, 262144, 262144, dflag, 0);
    gemm_bt<<<dim3(8, 2, 32), 256, 0, stream>>>(
        qlbf + (size_t)c * 8 * 16384, 64, 16384,
        k + (size_t)c * 8 * 262144, 64, 262144,
        S3, 4096, 1048576, 4096, 64, 32, 1, nullptr, nullptr, dflag);
    softmax3_kernel<<<2048, 256, 0, stream>>>(S3, P3);
    gemm_bt<<<dim3(8, 2, 16), 256, 0, stream>>>(
        P3, 4096, 1048576, vTbuf, 4096, 262144,
        a3v + (size_t)c * 131072, 64, 16384, 64, 256, 1, 2, nullptr, nullptr, dflag);
  }

  // a2 path (f32 landmarks) + pinv in d_out
  a2_kernel<<<8192, 256, 0, stream>>>(qlf, klf, a2);
  colsum_max_kernel<<<32, 256, 0, stream>>>(a2, gmax);
  zinit_kernel<<<8192, 256, 0, stream>>>(a2, gmax, W0);

  float* zi = W0; float* f1 = W1; float* f2 = W2; float* f3 = W3;
  for (int it = 0; it < 6; it++) {
    bmm64_mfma<<<dim3(32, 4, 4), 256, 0, stream>>>(a2, zi, f1, 256, 256, 65536, 65536, 65536, 0.f, 1.f, 0.f, 1.f);
    bmm64_mfma<<<dim3(32, 4, 4), 256, 0, stream>>>(f1, f1, f2, 256, 256, 65536, 65536, 65536, 15.f, -1.f, 7.f, -1.f);
    bmm64_mfma<<<dim3(32, 4, 4), 256, 0, stream>>>(f1, f2, f3, 256, 256, 65536, 65536, 65536, 13.f, -1.f, 0.f, 1.f);
    bmm64_mfma<<<dim3(32, 4, 4), 256, 0, stream>>>(zi, f3, f2, 256, 256, 65536, 65536, 65536, 0.f, 0.25f, 0.f, 1.f);
    float* nzi = f2; f2 = f1; f1 = zi; zi = nzi;
  }

  // Wm = z6 @ a3v -> f32 in ws (before d_out reuse)
  bmm64_mfma<<<dim3(32, 4, 1), 256, 0, stream>>>(zi, a3v, Wm, 64, 256, 65536, 16384, 16384, 0.f, 1.f, 0.f, 1.f);

  // a1 softmax (f32 P1) + f32 PV1 + conv residual, 8 chunks of 4 bh
  for (int c = 0; c < 8; c++) {
    attn1_kernel<<<dim3(64, 4), 256, 0, stream>>>(q, klbf, P1, c * 4);
    bmm64_mfma<<<dim3(4, 64, 1), 256, 0, stream>>>(
        P1, Wm + (size_t)c * 4 * 16384, p1f,
        64, 256, 1048576, 16384, 262144, 0.f, 1.f, 0.f, 1.f);
    conv_add_kernel<<<dim3(64, 4), 256, 0, stream>>>(p1f, v, w_res, y, dflag, c * 4);
  }

  // out = y @ w_out + b_out + x -> d_out (dtype-adaptive)
  gemm_bt<<<dim3(1, 256, 4), 256, 0, stream>>>(
      y, 256, 0, woutT, 256, 0,
      d_out, 512, 0, 512, 256, 4, 3, b_out, x, dflag);
}

// Round 5
// 1121.118 us; speedup vs baseline: 1.5688x; 1.0873x over previous
//
#include <hip/hip_runtime.h>
#include <hip/hip_bf16.h>
#include <string.h>

typedef __hip_bfloat16 bf16;
typedef __attribute__((ext_vector_type(8))) __bf16 bf16x8;
typedef __attribute__((ext_vector_type(4))) float f32x4;
typedef __attribute__((ext_vector_type(8))) unsigned short u16x8;

#define NN 4096
#define DD 512
#define MM 256
#define ROWS 32768

__device__ __forceinline__ float b2f(bf16 x) { return __bfloat162float(x); }
__device__ __forceinline__ float u2f(unsigned short u) {
  return __uint_as_float(((unsigned int)u) << 16);
}
__device__ __forceinline__ unsigned short f2bu(float v) {
  bf16 h = __float2bfloat16(v);
  return *reinterpret_cast<unsigned short*>(&h);
}
// adaptive input load / output store (f==1 -> float32, f==0 -> bf16)
__device__ __forceinline__ float ldf(const void* p, size_t i, int f) {
  return f ? ((const float*)p)[i] : __bfloat162float(((const bf16*)p)[i]);
}
__device__ __forceinline__ void stf(void* p, size_t i, float v, int f) {
  if (f) ((float*)p)[i] = v;
  else ((bf16*)p)[i] = __float2bfloat16(v);
}

// ---- dtype detection ----
__global__ void detect_kernel(const void* x, int* flag) {
  __shared__ int red[256];
  int tid = threadIdx.x;
  const unsigned short* u = (const unsigned short*)x;
  int local = 0;
  for (int i = 0; i < 32; i++) {
    unsigned short e = (u[tid * 32 + i] >> 7) & 0xFF;
    if (e >= 0xC8) local++;
  }
  red[tid] = local; __syncthreads();
  #pragma unroll
  for (int s = 128; s > 0; s >>= 1) {
    if (tid < s) red[tid] += red[tid + s];
    __syncthreads();
  }
  if (tid == 0) *flag = (red[0] > 32) ? 1 : 0;
}

// ---- block reductions ----
__device__ __forceinline__ float bred_max(float v, float* red) {
  int tid = threadIdx.x;
  red[tid] = v; __syncthreads();
  #pragma unroll
  for (int s = 128; s > 0; s >>= 1) {
    if (tid < s) red[tid] = fmaxf(red[tid], red[tid + s]);
    __syncthreads();
  }
  float r = red[0]; __syncthreads();
  return r;
}
__device__ __forceinline__ float bred_sum(float v, float* red) {
  int tid = threadIdx.x;
  red[tid] = v; __syncthreads();
  #pragma unroll
  for (int s = 128; s > 0; s >>= 1) {
    if (tid < s) red[tid] += red[tid + s];
    __syncthreads();
  }
  float r = red[0]; __syncthreads();
  return r;
}

// ---- LayerNorm stats ----
__global__ void ln_stats_kernel(const void* __restrict__ x, float* __restrict__ stats,
                                const int* dflag) {
  __shared__ float red[256];
  int f = *dflag;
  int row = blockIdx.x, tid = threadIdx.x;
  size_t base = (size_t)row * DD;
  float v0 = ldf(x, base + tid, f);
  float v1 = ldf(x, base + tid + 256, f);
  float mean = bred_sum(v0 + v1, red) * (1.0f / DD);
  float d0 = v0 - mean, d1 = v1 - mean;
  float var = bred_sum(d0 * d0 + d1 * d1, red) * (1.0f / DD);
  if (tid == 0) {
    stats[row * 2] = mean;
    stats[row * 2 + 1] = rsqrtf(var + 1e-5f);
  }
}

// ---- generic transpose -> bf16 out: out[b][c][r] = in[b][r][c] ----
__global__ void transpose_kernel(const void* __restrict__ in, bf16* __restrict__ out,
                                 int R, int Cc, long sIn, long sOut,
                                 const int* dflag, int ovr) {
  int f = (ovr >= 0) ? ovr : *dflag;
  size_t o = (size_t)blockIdx.x * 256 + threadIdx.x;
  size_t per = (size_t)R * Cc;
  size_t b = o / per, rem = o % per;
  size_t c = rem / R, r = rem % R;
  out[b * sOut + c * (size_t)R + r] = __float2bfloat16(ldf(in, b * sIn + r * (size_t)Cc + c, f));
}

// ---- QKV GEMM: MFMA, LN fused on A-stage (vectorized), scatter epilogue ----
__global__ __launch_bounds__(256) void gemm_qkv(
    const void* __restrict__ x, const float* __restrict__ stats,
    const void* __restrict__ g, const void* __restrict__ bb,
    const bf16* __restrict__ wT,  // [768][512]
    bf16* __restrict__ q, bf16* __restrict__ k, bf16* __restrict__ v,
    const int* __restrict__ dflag) {
  __shared__ __align__(16) unsigned short As[128][40];
  __shared__ __align__(16) unsigned short Bs[128][40];
  __shared__ __align__(16) float gls[512];
  __shared__ __align__(16) float bls[512];
  int f = *dflag;
  int tid = threadIdx.x;
  // one-time g/bb stage into LDS
  {
    int c0 = tid, c1 = tid + 256;
    gls[c0] = ldf(g, c0, f);  gls[c1] = ldf(g, c1, f);
    bls[c0] = ldf(bb, c0, f); bls[c1] = ldf(bb, c1, f);
  }
  int m0 = blockIdx.x * 128, n0 = blockIdx.y * 128;
  int sr = tid >> 1, sh = (tid & 1) * 16;
  int wave = tid >> 6, lane = tid & 63;
  int wm = (wave & 1) * 64, wn = (wave >> 1) * 64;
  int l15 = lane & 15, quad = lane >> 4;
  int r = m0 + sr;
  float mu = stats[r * 2], rs = stats[r * 2 + 1];   // loop-invariant
  const float* xf = (const float*)x + (size_t)r * DD;
  const bf16*  xb = (const bf16*)x  + (size_t)r * DD;
  __syncthreads();  // gls/bls ready
  f32x4 acc[4][4] = {};
  for (int k0 = 0; k0 < 512; k0 += 32) {
    {
      // vectorized x load
      float xv[16];
      if (f) {
        const float* src = xf + k0 + sh;
        float4 t0 = *(const float4*)(src);
        float4 t1 = *(const float4*)(src + 4);
        float4 t2 = *(const float4*)(src + 8);
        float4 t3 = *(const float4*)(src + 12);
        xv[0] = t0.x; xv[1] = t0.y; xv[2]  = t0.z; xv[3]  = t0.w;
        xv[4] = t1.x; xv[5] = t1.y; xv[6]  = t1.z; xv[7]  = t1.w;
        xv[8] = t2.x; xv[9] = t2.y; xv[10] = t2.z; xv[11] = t2.w;
        xv[12] = t3.x; xv[13] = t3.y; xv[14] = t3.z; xv[15] = t3.w;
      } else {
        const bf16* src = xb + k0 + sh;
        u16x8 t0 = *(const u16x8*)(src);
        u16x8 t1 = *(const u16x8*)(src + 8);
        #pragma unroll
        for (int e = 0; e < 8; e++) { xv[e] = u2f(t0[e]); xv[8 + e] = u2f(t1[e]); }
      }
      // LN as 2 FMA/elem: a = rs*g;  out = x*a + (bb - mu*a)
      float gv[16], bv[16];
      {
        const float* gp = &gls[k0 + sh];
        const float* bp = &bls[k0 + sh];
        #pragma unroll
        for (int e4 = 0; e4 < 4; e4++) {
          float4 gt = *(const float4*)(gp + e4 * 4);
          float4 bt = *(const float4*)(bp + e4 * 4);
          gv[e4 * 4 + 0] = gt.x; gv[e4 * 4 + 1] = gt.y; gv[e4 * 4 + 2] = gt.z; gv[e4 * 4 + 3] = gt.w;
          bv[e4 * 4 + 0] = bt.x; bv[e4 * 4 + 1] = bt.y; bv[e4 * 4 + 2] = bt.z; bv[e4 * 4 + 3] = bt.w;
        }
      }
      u16x8 w0, w1;
      #pragma unroll
      for (int e = 0; e < 8; e++) {
        float a0 = rs * gv[e];
        float a1 = rs * gv[e + 8];
        w0[e] = f2bu(xv[e] * a0 + (bv[e] - mu * a0));
        w1[e] = f2bu(xv[e + 8] * a1 + (bv[e + 8] - mu * a1));
      }
      *(u16x8*)&As[sr][sh] = w0;
      *(u16x8*)&As[sr][sh + 8] = w1;
    }
    {
      const bf16* src = wT + (size_t)(n0 + sr) * 512 + k0 + sh;
      *(u16x8*)&Bs[sr][sh] = *(const u16x8*)src;
      *(u16x8*)&Bs[sr][sh + 8] = *(const u16x8*)(src + 8);
    }
    __syncthreads();
    bf16x8 af[4], bfr[4];
    #pragma unroll
    for (int i = 0; i < 4; i++) af[i] = *(const bf16x8*)&As[wm + i * 16 + l15][quad * 8];
    #pragma unroll
    for (int j = 0; j < 4; j++) bfr[j] = *(const bf16x8*)&Bs[wn + j * 16 + l15][quad * 8];
    #pragma unroll
    for (int i = 0; i < 4; i++)
      #pragma unroll
      for (int j = 0; j < 4; j++)
        acc[i][j] = __builtin_amdgcn_mfma_f32_16x16x32_bf16(af[i], bfr[j], acc[i][j], 0, 0, 0);
    __syncthreads();
  }
  #pragma unroll
  for (int i = 0; i < 4; i++)
    #pragma unroll
    for (int j = 0; j < 4; j++)
      #pragma unroll
      for (int reg = 0; reg < 4; reg++) {
        int row = m0 + wm + i * 16 + quad * 4 + reg;
        int c = n0 + wn + j * 16 + l15;
        int which = c >> 8, within = c & 255, h = within >> 6, d = within & 63;
        int b_ = row >> 12, n = row & 4095;
        size_t idx = ((size_t)(b_ * 4 + h) * NN + n) * 64 + d;
        float val = acc[i][j][reg];
        if (which == 0) q[idx] = __float2bfloat16(val * 0.125f);
        else if (which == 1) k[idx] = __float2bfloat16(val);
        else v[idx] = __float2bfloat16(val);
      }
}

// ---- generic batched MFMA GEMM: C = A[M x K] @ Bt[N x K]^T ----
// modes: 0=f32 store, 1=bf16 store, 2=f32 atomicAdd (split-K), 3=bias+residual+dtype store
__global__ __launch_bounds__(256) void gemm_bt(
    const bf16* __restrict__ A, long ldA, long sA,
    const bf16* __restrict__ Bt, long ldB, long sB,
    void* __restrict__ C, long ldC, long sC,
    int N, int kLen, int nTiles, int mode,
    const void* __restrict__ bias, const void* __restrict__ resid,
    const int* __restrict__ dflag) {
  __shared__ __align__(16) unsigned short As[128][40];
  __shared__ __align__(16) unsigned short Bs[128][40];
  int tid = threadIdx.x;
  int b = blockIdx.x;
  int m0 = blockIdx.y * 128;
  int nt = blockIdx.z % nTiles, ks = blockIdx.z / nTiles;
  int n0 = nt * 128;
  long k0b = (long)ks * kLen;
  const bf16* Ab = A + (size_t)b * sA;
  const bf16* Bb = Bt + (size_t)b * sB;
  int sr = tid >> 1, sh = (tid & 1) * 16;
  int wave = tid >> 6, lane = tid & 63;
  int wm = (wave & 1) * 64, wn = (wave >> 1) * 64;
  int l15 = lane & 15, quad = lane >> 4;
  f32x4 acc[4][4] = {};
  for (int kc = 0; kc < kLen; kc += 32) {
    long k0 = k0b + kc;
    {
      const bf16* src = Ab + (size_t)(m0 + sr) * ldA + k0 + sh;
      *(u16x8*)&As[sr][sh] = *(const u16x8*)src;
      *(u16x8*)&As[sr][sh + 8] = *(const u16x8*)(src + 8);
    }
    if (n0 + sr < N) {
      const bf16* src = Bb + (size_t)(n0 + sr) * ldB + k0 + sh;
      *(u16x8*)&Bs[sr][sh] = *(const u16x8*)src;
      *(u16x8*)&Bs[sr][sh + 8] = *(const u16x8*)(src + 8);
    } else {
      u16x8 z = {};
      *(u16x8*)&Bs[sr][sh] = z;
      *(u16x8*)&Bs[sr][sh + 8] = z;
    }
    __syncthreads();
    bf16x8 af[4], bfr[4];
    #pragma unroll
    for (int i = 0; i < 4; i++) af[i] = *(const bf16x8*)&As[wm + i * 16 + l15][quad * 8];
    #pragma unroll
    for (int j = 0; j < 4; j++) bfr[j] = *(const bf16x8*)&Bs[wn + j * 16 + l15][quad * 8];
    #pragma unroll
    for (int i = 0; i < 4; i++)
      #pragma unroll
      for (int j = 0; j < 4; j++)
        acc[i][j] = __builtin_amdgcn_mfma_f32_16x16x32_bf16(af[i], bfr[j], acc[i][j], 0, 0, 0);
    __syncthreads();
  }
  int f = (mode == 3) ? *dflag : 0;
  #pragma unroll
  for (int i = 0; i < 4; i++)
    #pragma unroll
    for (int j = 0; j < 4; j++)
      #pragma unroll
      for (int reg = 0; reg < 4; reg++) {
        int row = m0 + wm + i * 16 + quad * 4 + reg;
        int col = n0 + wn + j * 16 + l15;
        if (col < N) {
          float val = acc[i][j][reg];
          size_t off = (size_t)row * ldC + col;
          if (mode == 0) (((float*)C) + (size_t)b * sC)[off] = val;
          else if (mode == 1) (((bf16*)C) + (size_t)b * sC)[off] = __float2bfloat16(val);
          else if (mode == 2) atomicAdd(((float*)C) + (size_t)b * sC + off, val);
          else {
            val += ldf(bias, col, f) + ldf(resid, off, f);
            stf(C, off, val, f);
          }
        }
      }
}

// ---- landmark means: bf16 src -> f32 dst (for a2/pinv) AND bf16 dst (for MFMA) ----
__global__ void landmark_kernel(const bf16* __restrict__ src, float* __restrict__ dstf,
                                bf16* __restrict__ dstb) {
  int idx = blockIdx.x * 256 + threadIdx.x;  // 524288
  int d = idx & 63, j = (idx >> 6) & 255, bh = idx >> 14;
  const bf16* s = src + ((size_t)bh * NN + j * 16) * 64 + d;
  float a = 0;
  #pragma unroll
  for (int i = 0; i < 16; i++) a += b2f(s[i * 64]);
  a *= (1.0f / 16);
  dstf[idx] = a;
  dstb[idx] = __float2bfloat16(a);
}

// ---- a2 = softmax(ql @ kl^T) f32, f32 inputs (pinv-sensitive path) ----
__global__ void a2_kernel(const float* __restrict__ ql, const float* __restrict__ kl,
                          float* __restrict__ a2) {
  __shared__ float qs[64];
  __shared__ float red[256];
  int bh = blockIdx.x >> 8, i = blockIdx.x & 255, tid = threadIdx.x;
  if (tid < 64) qs[tid] = ql[((size_t)bh * MM + i) * 64 + tid];
  __syncthreads();
  const float* kr = kl + ((size_t)bh * MM + tid) * 64;
  float s = 0;
  #pragma unroll
  for (int d = 0; d < 64; d++) s += qs[d] * kr[d];
  float mx = bred_max(s, red);
  float e = __expf(s - mx);
  float sm = bred_sum(e, red);
  a2[((size_t)bh * MM + i) * MM + tid] = e / sm;
}

// ---- max over column-sums of a2 (row-sums of softmax are exactly 1, skipped) ----
// 32 blocks (one per bh); thread j owns column j (coalesced); 1 atomic per block.
__global__ void colsum_max_kernel(const float* __restrict__ a2, float* __restrict__ gmax) {
  __shared__ float red[256];
  int bh = blockIdx.x, tid = threadIdx.x;
  const float* base = a2 + (size_t)bh * MM * MM + tid;
  float s0 = 0, s1 = 0, s2 = 0, s3 = 0, s4 = 0, s5 = 0, s6 = 0, s7 = 0;
  for (int i = 0; i < 256; i += 8) {
    s0 += base[(size_t)(i + 0) * MM];
    s1 += base[(size_t)(i + 1) * MM];
    s2 += base[(size_t)(i + 2) * MM];
    s3 += base[(size_t)(i + 3) * MM];
    s4 += base[(size_t)(i + 4) * MM];
    s5 += base[(size_t)(i + 5) * MM];
    s6 += base[(size_t)(i + 6) * MM];
    s7 += base[(size_t)(i + 7) * MM];
  }
  float tot = ((s0 + s1) + (s2 + s3)) + ((s4 + s5) + (s6 + s7));
  float mx = bred_max(tot, red);
  if (tid == 0) atomicMax((int*)gmax + 1, __float_as_int(mx));
}

__global__ void zinit_kernel(const float* __restrict__ a2, const float* __restrict__ gmax,
                             float* __restrict__ z) {
  int idx = blockIdx.x * 256 + threadIdx.x;
  int j = idx & 255, i = (idx >> 8) & 255, bh = idx >> 16;
  float scale = 1.0f / gmax[1];   // max(row-sums) == 1 exactly (softmax rows)
  z[idx] = a2[((size_t)bh * MM + j) * MM + i] * scale;
}

// ---- MFMA split-bf16 batched 64x64-tile GEMM (drop-in replacement for bmm64) ----
// C = alpha*I + beta*(A @ (gbA*I + gbB*B)); A [M][Kk] f32 row-major (ld=Kk),
// B [Kk][Nn] f32 row-major (ld=Nn). Split-3 bf16 MFMA: A=Ah+Al, B'=Bh+Bl,
// acc += Ah*Bh + Ah*Bl + Al*Bh  (dropped Al*Bl ~2^-18 rel => f32-class accuracy).
// B transposed into LDS at stage time (scalar b16 writes).
// NOTE (historical): a round-6 "Nn-guard" here was an LDS-OOB bug; do not reintroduce.
__global__ __launch_bounds__(256) void bmm64_mfma(
    const float* __restrict__ A, const float* __restrict__ B_,
    float* __restrict__ C,
    int Nn, int Kk, long sA, long sB, long sC,
    float alpha, float beta, float gbA, float gbB) {
  __shared__ __align__(16) unsigned short Ah[64][40];
  __shared__ __align__(16) unsigned short Al[64][40];
  __shared__ __align__(16) unsigned short Bh[64][40];
  __shared__ __align__(16) unsigned short Bl[64][40];
  int bh = blockIdx.x;
  int row0 = blockIdx.y * 64, col0 = blockIdx.z * 64;
  const float* Ab = A + (size_t)bh * sA;
  const float* Bb = B_ + (size_t)bh * sB;
  int tid = threadIdx.x;
  int wave = tid >> 6, lane = tid & 63, l15 = lane & 15, quad = lane >> 4;
  int wm = (wave & 1) * 32, wn = (wave >> 1) * 32;
  int ar2 = tid >> 2, kq = (tid & 3) * 8;   // A-stage: 64 rows x 32 k
  int kr = tid >> 3, n8 = (tid & 7) * 8;    // B-stage: 32 k-rows x 64 n
  f32x4 acc[2][2] = {};
  for (int k0 = 0; k0 < Kk; k0 += 32) {
    {
      const float* src = Ab + (size_t)(row0 + ar2) * Kk + k0 + kq;
      u16x8 hi, lo;
      #pragma unroll
      for (int e = 0; e < 8; e++) {
        float a = src[e];
        unsigned short h = f2bu(a);
        hi[e] = h;
        lo[e] = f2bu(a - u2f(h));
      }
      *(u16x8*)&Ah[ar2][kq] = hi;
      *(u16x8*)&Al[ar2][kq] = lo;
    }
    {
      const float* src = Bb + (size_t)(k0 + kr) * Nn + col0 + n8;
      int kk = k0 + kr;
      #pragma unroll
      for (int e = 0; e < 8; e++) {
        float b = gbB * src[e];
        if (kk == col0 + n8 + e) b += gbA;
        unsigned short h = f2bu(b);
        Bh[n8 + e][kr] = h;
        Bl[n8 + e][kr] = f2bu(b - u2f(h));
      }
    }
    __syncthreads();
    bf16x8 ah[2], al[2], bhf[2], blf[2];
    #pragma unroll
    for (int i = 0; i < 2; i++) {
      ah[i]  = *(const bf16x8*)&Ah[wm + i * 16 + l15][quad * 8];
      al[i]  = *(const bf16x8*)&Al[wm + i * 16 + l15][quad * 8];
      bhf[i] = *(const bf16x8*)&Bh[wn + i * 16 + l15][quad * 8];
      blf[i] = *(const bf16x8*)&Bl[wn + i * 16 + l15][quad * 8];
    }
    #pragma unroll
    for (int i = 0; i < 2; i++)
      #pragma unroll
      for (int j = 0; j < 2; j++) {
        acc[i][j] = __builtin_amdgcn_mfma_f32_16x16x32_bf16(ah[i], bhf[j], acc[i][j], 0, 0, 0);
        acc[i][j] = __builtin_amdgcn_mfma_f32_16x16x32_bf16(ah[i], blf[j], acc[i][j], 0, 0, 0);
        acc[i][j] = __builtin_amdgcn_mfma_f32_16x16x32_bf16(al[i], bhf[j], acc[i][j], 0, 0, 0);
      }
    __syncthreads();
  }
  #pragma unroll
  for (int i = 0; i < 2; i++)
    #pragma unroll
    for (int j = 0; j < 2; j++)
      #pragma unroll
      for (int reg = 0; reg < 4; reg++) {
        int r = row0 + wm + i * 16 + quad * 4 + reg;
        int cc = col0 + wn + j * 16 + l15;
        C[(size_t)bh * sC + (size_t)r * Nn + cc] = alpha * (r == cc) + beta * acc[i][j][reg];
      }
}

// ---- Wm split: f32 [bh][c=256][d=64] -> transposed hi/lo bf16 [bh][d][c] ----
__global__ void wmsplit_kernel(const float* __restrict__ Wm, bf16* __restrict__ h,
                               bf16* __restrict__ l) {
  int o = blockIdx.x * 256 + threadIdx.x;  // 524288
  int c = o & 255, d = (o >> 8) & 63, bh = o >> 14;
  float w = Wm[(((size_t)bh << 8) + c) * 64 + d];
  unsigned short hh = f2bu(w);
  h[o] = __float2bfloat16(w);  // == hh bits
  l[o] = __float2bfloat16(w - u2f(hh));
}

// ---- softmax over rows of 4096 (bf16 in -> bf16 out) ----
__global__ void softmax3_kernel(const bf16* __restrict__ S, bf16* __restrict__ P) {
  __shared__ float red[256];
  int row = blockIdx.x, tid = threadIdx.x;
  const bf16* sr = S + (size_t)row * 4096 + tid * 16;
  u16x8 v0 = *(const u16x8*)sr;
  u16x8 v1 = *(const u16x8*)(sr + 8);
  float vals[16];
  #pragma unroll
  for (int e = 0; e < 8; e++) { vals[e] = u2f(v0[e]); vals[e + 8] = u2f(v1[e]); }
  float lm = -1e30f;
  #pragma unroll
  for (int e = 0; e < 16; e++) lm = fmaxf(lm, vals[e]);
  float mx = bred_max(lm, red);
  float ls = 0;
  #pragma unroll
  for (int e = 0; e < 16; e++) { vals[e] = __expf(vals[e] - mx); ls += vals[e]; }
  float inv = 1.0f / bred_sum(ls, red);
  bf16* pr = P + (size_t)row * 4096 + tid * 16;
  #pragma unroll
  for (int e = 0; e < 16; e++) pr[e] = __float2bfloat16(vals[e] * inv);
}

// ---- FUSED sim1 + softmax + PV (P @ Wm) -> p1f f32 [4][4096][64] ----
// QBLK=32 rows per block. P (32x256) built in registers, split hi/lo bf16 into
// LDS (overlaying dead Ks buffer), then MFMA vs precomputed WmT hi/lo tiles.
// 3-term split => same 2^-17 error class as bmm64_mfma.
__global__ __launch_bounds__(256) void attn1_pv_kernel(
    const bf16* __restrict__ q, const bf16* __restrict__ klbf,
    const bf16* __restrict__ wmt_h, const bf16* __restrict__ wmt_l,
    float* __restrict__ p1f, int bh0) {
  __shared__ __align__(16) unsigned short Qs[32][72];
  __shared__ __align__(16) unsigned short Ks[256][72];   // Ph/Pl overlay after QK^T
  __shared__ __align__(16) unsigned short Wh[64][40];
  __shared__ __align__(16) unsigned short Wl[64][40];
  __shared__ float redm[4][32];
  __shared__ float reds[4][32];
  int tid = threadIdx.x;
  int bhl = blockIdx.y, bh = bh0 + bhl;
  int n0 = blockIdx.x * 32;
  const bf16* qb = q + ((size_t)bh * NN + n0) * 64;
  const bf16* kb = klbf + (size_t)bh * 16384;
  {
    int r = tid >> 3, s = (tid & 7) * 8;
    *(u16x8*)&Qs[r][s] = *(const u16x8*)(qb + (size_t)r * 64 + s);
  }
  {
    const bf16* src = kb + (size_t)tid * 64;
    #pragma unroll
    for (int s8 = 0; s8 < 8; s8++) *(u16x8*)&Ks[tid][s8 * 8] = *(const u16x8*)(src + s8 * 8);
  }
  __syncthreads();
  int wave = tid >> 6, lane = tid & 63, l15 = lane & 15, quad = lane >> 4;
  // ---- QK^T: 32 rows x 256 landmark cols (wave owns 64 cols) ----
  f32x4 acc[2][4] = {};
  #pragma unroll
  for (int kc = 0; kc < 64; kc += 32) {
    bf16x8 af[2], bfr[4];
    #pragma unroll
    for (int i = 0; i < 2; i++) af[i] = *(const bf16x8*)&Qs[i * 16 + l15][kc + quad * 8];
    #pragma unroll
    for (int j = 0; j < 4; j++) bfr[j] = *(const bf16x8*)&Ks[wave * 64 + j * 16 + l15][kc + quad * 8];
    #pragma unroll
    for (int i = 0; i < 2; i++)
      #pragma unroll
      for (int j = 0; j < 4; j++)
        acc[i][j] = __builtin_amdgcn_mfma_f32_16x16x32_bf16(af[i], bfr[j], acc[i][j], 0, 0, 0);
  }
  // ---- softmax over 256 cols ----
  float lm[2][4], ls[2][4], rinv[2][4];
  #pragma unroll
  for (int i = 0; i < 2; i++)
    #pragma unroll
    for (int reg = 0; reg < 4; reg++)
      lm[i][reg] = fmaxf(fmaxf(acc[i][0][reg], acc[i][1][reg]),
                         fmaxf(acc[i][2][reg], acc[i][3][reg]));
  #pragma unroll
  for (int off = 1; off < 16; off <<= 1)
    #pragma unroll
    for (int i = 0; i < 2; i++)
      #pragma unroll
      for (int reg = 0; reg < 4; reg++) lm[i][reg] = fmaxf(lm[i][reg], __shfl_xor(lm[i][reg], off));
  if (l15 == 0)
    #pragma unroll
    for (int i = 0; i < 2; i++)
      #pragma unroll
      for (int reg = 0; reg < 4; reg++) redm[wave][i * 16 + quad * 4 + reg] = lm[i][reg];
  __syncthreads();
  #pragma unroll
  for (int i = 0; i < 2; i++)
    #pragma unroll
    for (int reg = 0; reg < 4; reg++) {
      int r = i * 16 + quad * 4 + reg;
      rinv[i][reg] = fmaxf(fmaxf(redm[0][r], redm[1][r]), fmaxf(redm[2][r], redm[3][r]));
      ls[i][reg] = 0;
    }
  #pragma unroll
  for (int i = 0; i < 2; i++)
    #pragma unroll
    for (int j = 0; j < 4; j++)
      #pragma unroll
      for (int reg = 0; reg < 4; reg++) {
        float e = __expf(acc[i][j][reg] - rinv[i][reg]);
        acc[i][j][reg] = e;
        ls[i][reg] += e;
      }
  #pragma unroll
  for (int off = 1; off < 16; off <<= 1)
    #pragma unroll
    for (int i = 0; i < 2; i++)
      #pragma unroll
      for (int reg = 0; reg < 4; reg++) ls[i][reg] += __shfl_xor(ls[i][reg], off);
  if (l15 == 0)
    #pragma unroll
    for (int i = 0; i < 2; i++)
      #pragma unroll
      for (int reg = 0; reg < 4; reg++) reds[wave][i * 16 + quad * 4 + reg] = ls[i][reg];
  __syncthreads();
  #pragma unroll
  for (int i = 0; i < 2; i++)
    #pragma unroll
    for (int reg = 0; reg < 4; reg++) {
      int r = i * 16 + quad * 4 + reg;
      rinv[i][reg] = 1.0f / (reds[0][r] + reds[1][r] + reds[2][r] + reds[3][r]);
    }
  // ---- write P hi/lo bf16 into Ks overlay: Ph[32][264], Pl at +8448 u16 ----
  unsigned short* Pb = &Ks[0][0];
  #pragma unroll
  for (int i = 0; i < 2; i++)
    #pragma unroll
    for (int j = 0; j < 4; j++)
      #pragma unroll
      for (int reg = 0; reg < 4; reg++) {
        float pv = acc[i][j][reg] * rinv[i][reg];
        unsigned short h = f2bu(pv);
        int row = i * 16 + quad * 4 + reg;
        int col = wave * 64 + j * 16 + l15;
        Pb[row * 264 + col] = h;
        Pb[8448 + row * 264 + col] = f2bu(pv - u2f(h));
      }
  // ---- PV: out[32 r][64 d] = P @ Wm; wave: rows (wave&1)*16, d (wave>>1)*32 ----
  const bf16* whp = wmt_h + (size_t)bh * 16384;
  const bf16* wlp = wmt_l + (size_t)bh * 16384;
  int wd = tid >> 2, wc = (tid & 3) * 8;
  int iw = wave & 1, dw = (wave >> 1) * 32;
  f32x4 accp[2] = {};
  for (int kc = 0; kc < 256; kc += 32) {
    __syncthreads();   // protect Wh/Wl from overwrite while prior MFMA reads (and P-write on first iter)
    *(u16x8*)&Wh[wd][wc] = *(const u16x8*)(whp + (size_t)wd * 256 + kc + wc);
    *(u16x8*)&Wl[wd][wc] = *(const u16x8*)(wlp + (size_t)wd * 256 + kc + wc);
    __syncthreads();
    bf16x8 ah = *(const bf16x8*)&Pb[(iw * 16 + l15) * 264 + kc + quad * 8];
    bf16x8 al = *(const bf16x8*)&Pb[8448 + (iw * 16 + l15) * 264 + kc + quad * 8];
    #pragma unroll
    for (int jj = 0; jj < 2; jj++) {
      bf16x8 bh2 = *(const bf16x8*)&Wh[dw + jj * 16 + l15][quad * 8];
      bf16x8 bl2 = *(const bf16x8*)&Wl[dw + jj * 16 + l15][quad * 8];
      accp[jj] = __builtin_amdgcn_mfma_f32_16x16x32_bf16(ah, bh2, accp[jj], 0, 0, 0);
      accp[jj] = __builtin_amdgcn_mfma_f32_16x16x32_bf16(ah, bl2, accp[jj], 0, 0, 0);
      accp[jj] = __builtin_amdgcn_mfma_f32_16x16x32_bf16(al, bh2, accp[jj], 0, 0, 0);
    }
  }
  #pragma unroll
  for (int jj = 0; jj < 2; jj++)
    #pragma unroll
    for (int reg = 0; reg < 4; reg++) {
      int r = iw * 16 + quad * 4 + reg;
      int d = dw + jj * 16 + l15;
      int n = n0 + r;
      p1f[((size_t)bhl * NN + n) * 64 + d] = accp[jj][reg];
    }
}

// ---- depthwise conv (33) residual add: y = p1f32 + conv(v), 4-bh chunk ----
__global__ __launch_bounds__(256) void conv_add_kernel(
    const float* __restrict__ p1, const bf16* __restrict__ v,
    const void* __restrict__ wres, bf16* __restrict__ y, const int* __restrict__ dflag,
    int bh0) {
  __shared__ __align__(16) unsigned short Vs[96][64];
  int f = *dflag;
  int tid = threadIdx.x;
  int bhl = blockIdx.y, bh = bh0 + bhl;
  int n0 = blockIdx.x * 64;
  int h = bh & 3, b_ = bh >> 2;
  const bf16* vb = v + (size_t)bh * (NN * 64);
  for (int rr = tid; rr < 384; rr += 256) {
    int r = rr >> 2, s = (rr & 3) * 16;
    int n = n0 - 16 + r;
    if (n >= 0 && n < NN) {
      *(u16x8*)&Vs[r][s] = *(const u16x8*)(vb + (size_t)n * 64 + s);
      *(u16x8*)&Vs[r][s + 8] = *(const u16x8*)(vb + (size_t)n * 64 + s + 8);
    } else {
      u16x8 z = {};
      *(u16x8*)&Vs[r][s] = z; *(u16x8*)&Vs[r][s + 8] = z;
    }
  }
  float w33[33];
  #pragma unroll
  for (int kk = 0; kk < 33; kk++) w33[kk] = ldf(wres, h * 33 + kk, f);
  __syncthreads();
  int d = tid & 63, rb = tid >> 6;
  for (int ii = 0; ii < 16; ii++) {
    int nl = ii * 4 + rb;
    float cv = 0;
    #pragma unroll
    for (int kk = 0; kk < 33; kk++) cv += w33[kk] * u2f(Vs[nl + kk][d]);
    int n = n0 + nl;
    float pv = p1[((size_t)bhl * NN + n) * 64 + d];
    y[((size_t)b_ * NN + n) * 256 + h * 64 + d] = __float2bfloat16(pv + cv);
  }
}

extern "C" void kernel_launch(void* const* d_in, const int* in_sizes, int n_in,
                              void* d_out, int out_size, void* d_ws, size_t ws_size,
                              hipStream_t stream) {
  const void* x     = d_in[0];
  const void* ln_g  = d_in[1];
  const void* ln_b  = d_in[2];
  const void* w_qkv = d_in[3];
  const void* w_out = d_in[4];
  const void* b_out = d_in[5];
  const void* w_res = d_in[6];

  // ---- ws layout (~67.4 MiB; round-4 proved >= ~81 MiB available) ----
  float* ws    = (float*)d_ws;
  float* gmax  = ws;                                   // 2 f
  int*   dflag = (int*)(ws + 2);                       // 1 int
  float* stats = ws + 256;                             // 65536 f
  bf16*  woutT = (bf16*)(stats + 65536);               // 131072 bf16
  float* qlf   = (float*)(stats + 65536 + 65536);      // 524288 f
  float* klf   = qlf + 524288;                         // 524288 f
  bf16*  qlbf  = (bf16*)(klf + 524288);                // 524288 bf16
  bf16*  klbf  = qlbf + 524288;                        // 524288 bf16
  float* a3v   = (float*)(klbf + 524288);              // 524288 f
  float* Wm    = a3v + 524288;                         // 524288 f
  float* a2    = Wm + 524288;                          // 2097152 f (vT scratch alias)
  bf16*  q     = (bf16*)(a2 + 2097152);                // 8388608 bf16
  bf16*  k     = q + 8388608;                          // 8388608 bf16 (y alias)
  bf16*  v     = k + 8388608;                          // 8388608 bf16
  bf16*  y     = k;                                    // alias (k dead after sim3)
  bf16*  vTbuf = (bf16*)a2;                            // 4 MiB chunk scratch in a2 region
  bf16*  wmt_h = (bf16*)a2;                            // 1 MiB (a2 dead after pinv/Wm)
  bf16*  wmt_l = wmt_h + 524288;                       // 1 MiB

  // ---- d_out scratch (<= 32 MiB at all times) ----
  char* dob = (char*)d_out;
  bf16* wqkvT = (bf16*)dob;                            // phase A
  bf16* S3    = (bf16*)dob;                            // 16 MiB
  bf16* P3    = (bf16*)(dob + (16u << 20));            // 16 MiB
  float* W0   = (float*)dob;                           // pinv: 4 x 8 MiB
  float* W1   = (float*)(dob + (8u << 20));
  float* W2   = (float*)(dob + (16u << 20));
  float* W3   = (float*)(dob + (24u << 20));
  float* p1f  = (float*)(dob + (16u << 20));           // 4 MiB  (4 bh chunk, f32)

  detect_kernel<<<1, 256, 0, stream>>>(x, dflag);
  hipMemsetAsync(gmax, 0, 2 * sizeof(float), stream);
  ln_stats_kernel<<<ROWS, 256, 0, stream>>>(x, stats, dflag);

  // weight transposes
  transpose_kernel<<<1536, 256, 0, stream>>>(w_qkv, wqkvT, 512, 768, 0, 0, dflag, -1);
  transpose_kernel<<<512, 256, 0, stream>>>(w_out, woutT, 256, 512, 0, 0, dflag, -1);

  // QKV (LN fused)
  gemm_qkv<<<dim3(256, 6), 256, 0, stream>>>(x, stats, ln_g, ln_b, wqkvT, q, k, v, dflag);

  // landmarks (f32 + bf16)
  landmark_kernel<<<2048, 256, 0, stream>>>(q, qlf, qlbf);
  landmark_kernel<<<2048, 256, 0, stream>>>(k, klf, klbf);

  // sim3 -> softmax -> @v (4 chunks of 8 bh), a3v via split-K f32 atomics
  hipMemsetAsync(a3v, 0, 524288 * sizeof(float), stream);
  for (int c = 0; c < 4; c++) {
    transpose_kernel<<<8192, 256, 0, stream>>>(v + (size_t)c * 8 * 262144, vTbuf,
                                               4096, 64, 262144, 262144, dflag, 0);
    gemm_bt<<<dim3(8, 2, 32), 256, 0, stream>>>(
        qlbf + (size_t)c * 8 * 16384, 64, 16384,
        k + (size_t)c * 8 * 262144, 64, 262144,
        S3, 4096, 1048576, 4096, 64, 32, 1, nullptr, nullptr, dflag);
    softmax3_kernel<<<2048, 256, 0, stream>>>(S3, P3);
    gemm_bt<<<dim3(8, 2, 16), 256, 0, stream>>>(
        P3, 4096, 1048576, vTbuf, 4096, 262144,
        a3v + (size_t)c * 131072, 64, 16384, 64, 256, 1, 2, nullptr, nullptr, dflag);
  }

  // a2 path (f32 landmarks) + pinv in d_out
  a2_kernel<<<8192, 256, 0, stream>>>(qlf, klf, a2);
  colsum_max_kernel<<<32, 256, 0, stream>>>(a2, gmax);
  zinit_kernel<<<8192, 256, 0, stream>>>(a2, gmax, W0);

  float* zi = W0; float* f1 = W1; float* f2 = W2; float* f3 = W3;
  for (int it = 0; it < 6; it++) {
    bmm64_mfma<<<dim3(32, 4, 4), 256, 0, stream>>>(a2, zi, f1, 256, 256, 65536, 65536, 65536, 0.f, 1.f, 0.f, 1.f);
    bmm64_mfma<<<dim3(32, 4, 4), 256, 0, stream>>>(f1, f1, f2, 256, 256, 65536, 65536, 65536, 15.f, -1.f, 7.f, -1.f);
    bmm64_mfma<<<dim3(32, 4, 4), 256, 0, stream>>>(f1, f2, f3, 256, 256, 65536, 65536, 65536, 13.f, -1.f, 0.f, 1.f);
    bmm64_mfma<<<dim3(32, 4, 4), 256, 0, stream>>>(zi, f3, f2, 256, 256, 65536, 65536, 65536, 0.f, 0.25f, 0.f, 1.f);
    float* nzi = f2; f2 = f1; f1 = zi; zi = nzi;
  }

  // Wm = z6 @ a3v -> f32 in ws (before d_out reuse)
  bmm64_mfma<<<dim3(32, 4, 1), 256, 0, stream>>>(zi, a3v, Wm, 64, 256, 65536, 16384, 16384, 0.f, 1.f, 0.f, 1.f);

  // WmT hi/lo bf16 (a2 region now dead)
  wmsplit_kernel<<<2048, 256, 0, stream>>>(Wm, wmt_h, wmt_l);

  // fused a1 softmax + PV (f32 p1f) + conv residual, 8 chunks of 4 bh
  for (int c = 0; c < 8; c++) {
    attn1_pv_kernel<<<dim3(128, 4), 256, 0, stream>>>(q, klbf, wmt_h, wmt_l, p1f, c * 4);
    conv_add_kernel<<<dim3(64, 4), 256, 0, stream>>>(p1f, v, w_res, y, dflag, c * 4);
  }

  // out = y @ w_out + b_out + x -> d_out (dtype-adaptive)
  gemm_bt<<<dim3(1, 256, 4), 256, 0, stream>>>(
      y, 256, 0, woutT, 256, 0,
      d_out, 512, 0, 512, 256, 4, 3, b_out, x, dflag);
}

// Round 6
// 903.801 us; speedup vs baseline: 1.9461x; 1.2404x over previous
//
#include <hip/hip_runtime.h>
#include <hip/hip_bf16.h>
#include <string.h>

typedef __hip_bfloat16 bf16;
typedef __attribute__((ext_vector_type(8))) __bf16 bf16x8;
typedef __attribute__((ext_vector_type(4))) float f32x4;
typedef __attribute__((ext_vector_type(8))) unsigned short u16x8;

#define NN 4096
#define DD 512
#define MM 256
#define ROWS 32768

__device__ __forceinline__ float b2f(bf16 x) { return __bfloat162float(x); }
__device__ __forceinline__ float u2f(unsigned short u) {
  return __uint_as_float(((unsigned int)u) << 16);
}
__device__ __forceinline__ unsigned short f2bu(float v) {
  bf16 h = __float2bfloat16(v);
  return *reinterpret_cast<unsigned short*>(&h);
}
// adaptive input load / output store (f==1 -> float32, f==0 -> bf16)
__device__ __forceinline__ float ldf(const void* p, size_t i, int f) {
  return f ? ((const float*)p)[i] : __bfloat162float(((const bf16*)p)[i]);
}
__device__ __forceinline__ void stf(void* p, size_t i, float v, int f) {
  if (f) ((float*)p)[i] = v;
  else ((bf16*)p)[i] = __float2bfloat16(v);
}

// ---- dtype detection ----
__global__ void detect_kernel(const void* x, int* flag) {
  __shared__ int red[256];
  int tid = threadIdx.x;
  const unsigned short* u = (const unsigned short*)x;
  int local = 0;
  for (int i = 0; i < 32; i++) {
    unsigned short e = (u[tid * 32 + i] >> 7) & 0xFF;
    if (e >= 0xC8) local++;
  }
  red[tid] = local; __syncthreads();
  #pragma unroll
  for (int s = 128; s > 0; s >>= 1) {
    if (tid < s) red[tid] += red[tid + s];
    __syncthreads();
  }
  if (tid == 0) *flag = (red[0] > 32) ? 1 : 0;
}

// ---- block reductions ----
__device__ __forceinline__ float bred_max(float v, float* red) {
  int tid = threadIdx.x;
  red[tid] = v; __syncthreads();
  #pragma unroll
  for (int s = 128; s > 0; s >>= 1) {
    if (tid < s) red[tid] = fmaxf(red[tid], red[tid + s]);
    __syncthreads();
  }
  float r = red[0]; __syncthreads();
  return r;
}
__device__ __forceinline__ float bred_sum(float v, float* red) {
  int tid = threadIdx.x;
  red[tid] = v; __syncthreads();
  #pragma unroll
  for (int s = 128; s > 0; s >>= 1) {
    if (tid < s) red[tid] += red[tid + s];
    __syncthreads();
  }
  float r = red[0]; __syncthreads();
  return r;
}

// ---- LayerNorm stats ----
__global__ void ln_stats_kernel(const void* __restrict__ x, float* __restrict__ stats,
                                const int* dflag) {
  __shared__ float red[256];
  int f = *dflag;
  int row = blockIdx.x, tid = threadIdx.x;
  size_t base = (size_t)row * DD;
  float v0 = ldf(x, base + tid, f);
  float v1 = ldf(x, base + tid + 256, f);
  float mean = bred_sum(v0 + v1, red) * (1.0f / DD);
  float d0 = v0 - mean, d1 = v1 - mean;
  float var = bred_sum(d0 * d0 + d1 * d1, red) * (1.0f / DD);
  if (tid == 0) {
    stats[row * 2] = mean;
    stats[row * 2 + 1] = rsqrtf(var + 1e-5f);
  }
}

// ---- generic transpose -> bf16 out: out[b][c][r] = in[b][r][c] ----
__global__ void transpose_kernel(const void* __restrict__ in, bf16* __restrict__ out,
                                 int R, int Cc, long sIn, long sOut,
                                 const int* dflag, int ovr) {
  int f = (ovr >= 0) ? ovr : *dflag;
  size_t o = (size_t)blockIdx.x * 256 + threadIdx.x;
  size_t per = (size_t)R * Cc;
  size_t b = o / per, rem = o % per;
  size_t c = rem / R, r = rem % R;
  out[b * sOut + c * (size_t)R + r] = __float2bfloat16(ldf(in, b * sIn + r * (size_t)Cc + c, f));
}

// ---- QKV GEMM: MFMA, LN fused on A-stage (vectorized), scatter epilogue ----
__global__ __launch_bounds__(256) void gemm_qkv(
    const void* __restrict__ x, const float* __restrict__ stats,
    const void* __restrict__ g, const void* __restrict__ bb,
    const bf16* __restrict__ wT,  // [768][512]
    bf16* __restrict__ q, bf16* __restrict__ k, bf16* __restrict__ v,
    const int* __restrict__ dflag) {
  __shared__ __align__(16) unsigned short As[128][40];
  __shared__ __align__(16) unsigned short Bs[128][40];
  __shared__ __align__(16) float gls[512];
  __shared__ __align__(16) float bls[512];
  int f = *dflag;
  int tid = threadIdx.x;
  // one-time g/bb stage into LDS
  {
    int c0 = tid, c1 = tid + 256;
    gls[c0] = ldf(g, c0, f);  gls[c1] = ldf(g, c1, f);
    bls[c0] = ldf(bb, c0, f); bls[c1] = ldf(bb, c1, f);
  }
  int m0 = blockIdx.x * 128, n0 = blockIdx.y * 128;
  int sr = tid >> 1, sh = (tid & 1) * 16;
  int wave = tid >> 6, lane = tid & 63;
  int wm = (wave & 1) * 64, wn = (wave >> 1) * 64;
  int l15 = lane & 15, quad = lane >> 4;
  int r = m0 + sr;
  float mu = stats[r * 2], rs = stats[r * 2 + 1];   // loop-invariant
  const float* xf = (const float*)x + (size_t)r * DD;
  const bf16*  xb = (const bf16*)x  + (size_t)r * DD;
  __syncthreads();  // gls/bls ready
  f32x4 acc[4][4] = {};
  for (int k0 = 0; k0 < 512; k0 += 32) {
    {
      // vectorized x load
      float xv[16];
      if (f) {
        const float* src = xf + k0 + sh;
        float4 t0 = *(const float4*)(src);
        float4 t1 = *(const float4*)(src + 4);
        float4 t2 = *(const float4*)(src + 8);
        float4 t3 = *(const float4*)(src + 12);
        xv[0] = t0.x; xv[1] = t0.y; xv[2]  = t0.z; xv[3]  = t0.w;
        xv[4] = t1.x; xv[5] = t1.y; xv[6]  = t1.z; xv[7]  = t1.w;
        xv[8] = t2.x; xv[9] = t2.y; xv[10] = t2.z; xv[11] = t2.w;
        xv[12] = t3.x; xv[13] = t3.y; xv[14] = t3.z; xv[15] = t3.w;
      } else {
        const bf16* src = xb + k0 + sh;
        u16x8 t0 = *(const u16x8*)(src);
        u16x8 t1 = *(const u16x8*)(src + 8);
        #pragma unroll
        for (int e = 0; e < 8; e++) { xv[e] = u2f(t0[e]); xv[8 + e] = u2f(t1[e]); }
      }
      // LN as 2 FMA/elem: a = rs*g;  out = x*a + (bb - mu*a)
      float gv[16], bv[16];
      {
        const float* gp = &gls[k0 + sh];
        const float* bp = &bls[k0 + sh];
        #pragma unroll
        for (int e4 = 0; e4 < 4; e4++) {
          float4 gt = *(const float4*)(gp + e4 * 4);
          float4 bt = *(const float4*)(bp + e4 * 4);
          gv[e4 * 4 + 0] = gt.x; gv[e4 * 4 + 1] = gt.y; gv[e4 * 4 + 2] = gt.z; gv[e4 * 4 + 3] = gt.w;
          bv[e4 * 4 + 0] = bt.x; bv[e4 * 4 + 1] = bt.y; bv[e4 * 4 + 2] = bt.z; bv[e4 * 4 + 3] = bt.w;
        }
      }
      u16x8 w0, w1;
      #pragma unroll
      for (int e = 0; e < 8; e++) {
        float a0 = rs * gv[e];
        float a1 = rs * gv[e + 8];
        w0[e] = f2bu(xv[e] * a0 + (bv[e] - mu * a0));
        w1[e] = f2bu(xv[e + 8] * a1 + (bv[e + 8] - mu * a1));
      }
      *(u16x8*)&As[sr][sh] = w0;
      *(u16x8*)&As[sr][sh + 8] = w1;
    }
    {
      const bf16* src = wT + (size_t)(n0 + sr) * 512 + k0 + sh;
      *(u16x8*)&Bs[sr][sh] = *(const u16x8*)src;
      *(u16x8*)&Bs[sr][sh + 8] = *(const u16x8*)(src + 8);
    }
    __syncthreads();
    bf16x8 af[4], bfr[4];
    #pragma unroll
    for (int i = 0; i < 4; i++) af[i] = *(const bf16x8*)&As[wm + i * 16 + l15][quad * 8];
    #pragma unroll
    for (int j = 0; j < 4; j++) bfr[j] = *(const bf16x8*)&Bs[wn + j * 16 + l15][quad * 8];
    #pragma unroll
    for (int i = 0; i < 4; i++)
      #pragma unroll
      for (int j = 0; j < 4; j++)
        acc[i][j] = __builtin_amdgcn_mfma_f32_16x16x32_bf16(af[i], bfr[j], acc[i][j], 0, 0, 0);
    __syncthreads();
  }
  #pragma unroll
  for (int i = 0; i < 4; i++)
    #pragma unroll
    for (int j = 0; j < 4; j++)
      #pragma unroll
      for (int reg = 0; reg < 4; reg++) {
        int row = m0 + wm + i * 16 + quad * 4 + reg;
        int c = n0 + wn + j * 16 + l15;
        int which = c >> 8, within = c & 255, h = within >> 6, d = within & 63;
        int b_ = row >> 12, n = row & 4095;
        size_t idx = ((size_t)(b_ * 4 + h) * NN + n) * 64 + d;
        float val = acc[i][j][reg];
        if (which == 0) q[idx] = __float2bfloat16(val * 0.125f);
        else if (which == 1) k[idx] = __float2bfloat16(val);
        else v[idx] = __float2bfloat16(val);
      }
}

// ---- generic batched MFMA GEMM: C = A[M x K] @ Bt[N x K]^T ----
// modes: 0=f32 store, 1=bf16 store, 2=f32 atomicAdd (split-K), 3=bias+residual+dtype store
__global__ __launch_bounds__(256) void gemm_bt(
    const bf16* __restrict__ A, long ldA, long sA,
    const bf16* __restrict__ Bt, long ldB, long sB,
    void* __restrict__ C, long ldC, long sC,
    int N, int kLen, int nTiles, int mode,
    const void* __restrict__ bias, const void* __restrict__ resid,
    const int* __restrict__ dflag) {
  __shared__ __align__(16) unsigned short As[128][40];
  __shared__ __align__(16) unsigned short Bs[128][40];
  int tid = threadIdx.x;
  int b = blockIdx.x;
  int m0 = blockIdx.y * 128;
  int nt = blockIdx.z % nTiles, ks = blockIdx.z / nTiles;
  int n0 = nt * 128;
  long k0b = (long)ks * kLen;
  const bf16* Ab = A + (size_t)b * sA;
  const bf16* Bb = Bt + (size_t)b * sB;
  int sr = tid >> 1, sh = (tid & 1) * 16;
  int wave = tid >> 6, lane = tid & 63;
  int wm = (wave & 1) * 64, wn = (wave >> 1) * 64;
  int l15 = lane & 15, quad = lane >> 4;
  f32x4 acc[4][4] = {};
  for (int kc = 0; kc < kLen; kc += 32) {
    long k0 = k0b + kc;
    {
      const bf16* src = Ab + (size_t)(m0 + sr) * ldA + k0 + sh;
      *(u16x8*)&As[sr][sh] = *(const u16x8*)src;
      *(u16x8*)&As[sr][sh + 8] = *(const u16x8*)(src + 8);
    }
    if (n0 + sr < N) {
      const bf16* src = Bb + (size_t)(n0 + sr) * ldB + k0 + sh;
      *(u16x8*)&Bs[sr][sh] = *(const u16x8*)src;
      *(u16x8*)&Bs[sr][sh + 8] = *(const u16x8*)(src + 8);
    } else {
      u16x8 z = {};
      *(u16x8*)&Bs[sr][sh] = z;
      *(u16x8*)&Bs[sr][sh + 8] = z;
    }
    __syncthreads();
    bf16x8 af[4], bfr[4];
    #pragma unroll
    for (int i = 0; i < 4; i++) af[i] = *(const bf16x8*)&As[wm + i * 16 + l15][quad * 8];
    #pragma unroll
    for (int j = 0; j < 4; j++) bfr[j] = *(const bf16x8*)&Bs[wn + j * 16 + l15][quad * 8];
    #pragma unroll
    for (int i = 0; i < 4; i++)
      #pragma unroll
      for (int j = 0; j < 4; j++)
        acc[i][j] = __builtin_amdgcn_mfma_f32_16x16x32_bf16(af[i], bfr[j], acc[i][j], 0, 0, 0);
    __syncthreads();
  }
  int f = (mode == 3) ? *dflag : 0;
  #pragma unroll
  for (int i = 0; i < 4; i++)
    #pragma unroll
    for (int j = 0; j < 4; j++)
      #pragma unroll
      for (int reg = 0; reg < 4; reg++) {
        int row = m0 + wm + i * 16 + quad * 4 + reg;
        int col = n0 + wn + j * 16 + l15;
        if (col < N) {
          float val = acc[i][j][reg];
          size_t off = (size_t)row * ldC + col;
          if (mode == 0) (((float*)C) + (size_t)b * sC)[off] = val;
          else if (mode == 1) (((bf16*)C) + (size_t)b * sC)[off] = __float2bfloat16(val);
          else if (mode == 2) atomicAdd(((float*)C) + (size_t)b * sC + off, val);
          else {
            val += ldf(bias, col, f) + ldf(resid, off, f);
            stf(C, off, val, f);
          }
        }
      }
}

// ---- landmark means: bf16 src -> f32 dst (for a2/pinv) AND bf16 dst (for MFMA) ----
__global__ void landmark_kernel(const bf16* __restrict__ src, float* __restrict__ dstf,
                                bf16* __restrict__ dstb) {
  int idx = blockIdx.x * 256 + threadIdx.x;  // 524288
  int d = idx & 63, j = (idx >> 6) & 255, bh = idx >> 14;
  const bf16* s = src + ((size_t)bh * NN + j * 16) * 64 + d;
  float a = 0;
  #pragma unroll
  for (int i = 0; i < 16; i++) a += b2f(s[i * 64]);
  a *= (1.0f / 16);
  dstf[idx] = a;
  dstb[idx] = __float2bfloat16(a);
}

// ---- a2 = softmax(ql @ kl^T) f32, f32 inputs (pinv-sensitive path) ----
__global__ void a2_kernel(const float* __restrict__ ql, const float* __restrict__ kl,
                          float* __restrict__ a2) {
  __shared__ float qs[64];
  __shared__ float red[256];
  int bh = blockIdx.x >> 8, i = blockIdx.x & 255, tid = threadIdx.x;
  if (tid < 64) qs[tid] = ql[((size_t)bh * MM + i) * 64 + tid];
  __syncthreads();
  const float* kr = kl + ((size_t)bh * MM + tid) * 64;
  float s = 0;
  #pragma unroll
  for (int d = 0; d < 64; d++) s += qs[d] * kr[d];
  float mx = bred_max(s, red);
  float e = __expf(s - mx);
  float sm = bred_sum(e, red);
  a2[((size_t)bh * MM + i) * MM + tid] = e / sm;
}

// ---- max over column-sums of a2 (row-sums of softmax are exactly 1, skipped) ----
// 32 blocks (one per bh); thread j owns column j (coalesced); 1 atomic per block.
__global__ void colsum_max_kernel(const float* __restrict__ a2, float* __restrict__ gmax) {
  __shared__ float red[256];
  int bh = blockIdx.x, tid = threadIdx.x;
  const float* base = a2 + (size_t)bh * MM * MM + tid;
  float s0 = 0, s1 = 0, s2 = 0, s3 = 0, s4 = 0, s5 = 0, s6 = 0, s7 = 0;
  for (int i = 0; i < 256; i += 8) {
    s0 += base[(size_t)(i + 0) * MM];
    s1 += base[(size_t)(i + 1) * MM];
    s2 += base[(size_t)(i + 2) * MM];
    s3 += base[(size_t)(i + 3) * MM];
    s4 += base[(size_t)(i + 4) * MM];
    s5 += base[(size_t)(i + 5) * MM];
    s6 += base[(size_t)(i + 6) * MM];
    s7 += base[(size_t)(i + 7) * MM];
  }
  float tot = ((s0 + s1) + (s2 + s3)) + ((s4 + s5) + (s6 + s7));
  float mx = bred_max(tot, red);
  if (tid == 0) atomicMax((int*)gmax + 1, __float_as_int(mx));
}

__global__ void zinit_kernel(const float* __restrict__ a2, const float* __restrict__ gmax,
                             float* __restrict__ z) {
  int idx = blockIdx.x * 256 + threadIdx.x;
  int j = idx & 255, i = (idx >> 8) & 255, bh = idx >> 16;
  float scale = 1.0f / gmax[1];   // max(row-sums) == 1 exactly (softmax rows)
  z[idx] = a2[((size_t)bh * MM + j) * MM + i] * scale;
}

// ---- MFMA split-bf16 batched 64x64-tile GEMM (drop-in replacement for bmm64) ----
// C = alpha*I + beta*(A @ (gbA*I + gbB*B)); A [M][Kk] f32 row-major (ld=Kk),
// B [Kk][Nn] f32 row-major (ld=Nn). Split-3 bf16 MFMA: A=Ah+Al, B'=Bh+Bl,
// acc += Ah*Bh + Ah*Bl + Al*Bh  (dropped Al*Bl ~2^-18 rel => f32-class accuracy).
// B transposed into LDS at stage time (scalar b16 writes).
// NOTE (historical): a round-6 "Nn-guard" here was an LDS-OOB bug; do not reintroduce.
__global__ __launch_bounds__(256) void bmm64_mfma(
    const float* __restrict__ A, const float* __restrict__ B_,
    float* __restrict__ C,
    int Nn, int Kk, long sA, long sB, long sC,
    float alpha, float beta, float gbA, float gbB) {
  __shared__ __align__(16) unsigned short Ah[64][40];
  __shared__ __align__(16) unsigned short Al[64][40];
  __shared__ __align__(16) unsigned short Bh[64][40];
  __shared__ __align__(16) unsigned short Bl[64][40];
  int bh = blockIdx.x;
  int row0 = blockIdx.y * 64, col0 = blockIdx.z * 64;
  const float* Ab = A + (size_t)bh * sA;
  const float* Bb = B_ + (size_t)bh * sB;
  int tid = threadIdx.x;
  int wave = tid >> 6, lane = tid & 63, l15 = lane & 15, quad = lane >> 4;
  int wm = (wave & 1) * 32, wn = (wave >> 1) * 32;
  int ar2 = tid >> 2, kq = (tid & 3) * 8;   // A-stage: 64 rows x 32 k
  int kr = tid >> 3, n8 = (tid & 7) * 8;    // B-stage: 32 k-rows x 64 n
  f32x4 acc[2][2] = {};
  for (int k0 = 0; k0 < Kk; k0 += 32) {
    {
      const float* src = Ab + (size_t)(row0 + ar2) * Kk + k0 + kq;
      u16x8 hi, lo;
      #pragma unroll
      for (int e = 0; e < 8; e++) {
        float a = src[e];
        unsigned short h = f2bu(a);
        hi[e] = h;
        lo[e] = f2bu(a - u2f(h));
      }
      *(u16x8*)&Ah[ar2][kq] = hi;
      *(u16x8*)&Al[ar2][kq] = lo;
    }
    {
      const float* src = Bb + (size_t)(k0 + kr) * Nn + col0 + n8;
      int kk = k0 + kr;
      #pragma unroll
      for (int e = 0; e < 8; e++) {
        float b = gbB * src[e];
        if (kk == col0 + n8 + e) b += gbA;
        unsigned short h = f2bu(b);
        Bh[n8 + e][kr] = h;
        Bl[n8 + e][kr] = f2bu(b - u2f(h));
      }
    }
    __syncthreads();
    bf16x8 ah[2], al[2], bhf[2], blf[2];
    #pragma unroll
    for (int i = 0; i < 2; i++) {
      ah[i]  = *(const bf16x8*)&Ah[wm + i * 16 + l15][quad * 8];
      al[i]  = *(const bf16x8*)&Al[wm + i * 16 + l15][quad * 8];
      bhf[i] = *(const bf16x8*)&Bh[wn + i * 16 + l15][quad * 8];
      blf[i] = *(const bf16x8*)&Bl[wn + i * 16 + l15][quad * 8];
    }
    #pragma unroll
    for (int i = 0; i < 2; i++)
      #pragma unroll
      for (int j = 0; j < 2; j++) {
        acc[i][j] = __builtin_amdgcn_mfma_f32_16x16x32_bf16(ah[i], bhf[j], acc[i][j], 0, 0, 0);
        acc[i][j] = __builtin_amdgcn_mfma_f32_16x16x32_bf16(ah[i], blf[j], acc[i][j], 0, 0, 0);
        acc[i][j] = __builtin_amdgcn_mfma_f32_16x16x32_bf16(al[i], bhf[j], acc[i][j], 0, 0, 0);
      }
    __syncthreads();
  }
  #pragma unroll
  for (int i = 0; i < 2; i++)
    #pragma unroll
    for (int j = 0; j < 2; j++)
      #pragma unroll
      for (int reg = 0; reg < 4; reg++) {
        int r = row0 + wm + i * 16 + quad * 4 + reg;
        int cc = col0 + wn + j * 16 + l15;
        C[(size_t)bh * sC + (size_t)r * Nn + cc] = alpha * (r == cc) + beta * acc[i][j][reg];
      }
}

// ---- Wm split: f32 [bh][c=256][d=64] -> transposed hi/lo bf16 [bh][d][c] ----
__global__ void wmsplit_kernel(const float* __restrict__ Wm, bf16* __restrict__ h,
                               bf16* __restrict__ l) {
  int o = blockIdx.x * 256 + threadIdx.x;  // 524288
  int c = o & 255, d = (o >> 8) & 63, bh = o >> 14;
  float w = Wm[(((size_t)bh << 8) + c) * 64 + d];
  unsigned short hh = f2bu(w);
  h[o] = __float2bfloat16(w);  // == hh bits
  l[o] = __float2bfloat16(w - u2f(hh));
}

// ---- FUSED flash sim3: a3v = softmax(q_l @ k^T) @ v, per (lm-tile 32, bh) ----
// 8 waves, each owns 512 kv; chunk=64 kv. S^T = mfma(K-direct-global, Q_lds);
// online softmax in-register (lm on l15 axis => quad-shuffle reductions only);
// P -> wave-private LDS bf16 -> PV A-frags; V^T B-frags direct from global vT.
// Barrier-free main loop; 8-wave m/l/O combine via LDS at the end.
__global__ __launch_bounds__(512) void sim3_flash_kernel(
    const bf16* __restrict__ qlbf, const bf16* __restrict__ k,
    const bf16* __restrict__ vT, float* __restrict__ a3v) {
  __shared__ __align__(16) unsigned short Qs[32][72];
  __shared__ __align__(16) unsigned short Pl[8][32][72];
  __shared__ __align__(16) float OW[32][64];
  __shared__ float mW[8][32];
  __shared__ float lW[8][32];
  int tid = threadIdx.x;
  int lt = blockIdx.x;    // lm-tile 0..7
  int bh = blockIdx.y;    // 0..31
  int lm0 = lt * 32;
  if (tid < 256) {
    int r = tid >> 3, s = (tid & 7) * 8;
    *(u16x8*)&Qs[r][s] = *(const u16x8*)(qlbf + ((size_t)bh * 256 + lm0 + r) * 64 + s);
  }
  {
    float4 z = {};
    ((float4*)OW)[tid] = z;   // 512 * 16B = 8192B
  }
  __syncthreads();
  int wid = tid >> 6, lane = tid & 63, l15 = lane & 15, quad = lane >> 4;
  const bf16* kb = k + (size_t)bh * (NN * 64);
  const bf16* vb = vT + (size_t)bh * 262144;
  unsigned short* Pw = &Pl[wid][0][0];
  float m_[2] = {-1e30f, -1e30f};
  float l_[2] = {0.f, 0.f};
  f32x4 acc_o[2][4] = {};
  for (int ch = 0; ch < 8; ch++) {
    int kvb = wid * 512 + ch * 64;
    // ---- S^T[64 kv][32 lm] = K_chunk @ Q^T ----
    f32x4 acc_s[4][2] = {};
    #pragma unroll
    for (int kc = 0; kc < 2; kc++) {
      bf16x8 kf[4], qf[2];
      #pragma unroll
      for (int i = 0; i < 4; i++)
        kf[i] = *(const bf16x8*)(kb + (size_t)(kvb + i * 16 + l15) * 64 + kc * 32 + quad * 8);
      #pragma unroll
      for (int j = 0; j < 2; j++)
        qf[j] = *(const bf16x8*)&Qs[j * 16 + l15][kc * 32 + quad * 8];
      #pragma unroll
      for (int i = 0; i < 4; i++)
        #pragma unroll
        for (int j = 0; j < 2; j++)
          acc_s[i][j] = __builtin_amdgcn_mfma_f32_16x16x32_bf16(kf[i], qf[j], acc_s[i][j], 0, 0, 0);
    }
    // ---- online softmax per lm (= l15 within j_s tile) ----
    float scl[2];
    #pragma unroll
    for (int js = 0; js < 2; js++) {
      float cm = acc_s[0][js][0];
      #pragma unroll
      for (int i = 0; i < 4; i++)
        #pragma unroll
        for (int reg = 0; reg < 4; reg++) cm = fmaxf(cm, acc_s[i][js][reg]);
      cm = fmaxf(cm, __shfl_xor(cm, 16));
      cm = fmaxf(cm, __shfl_xor(cm, 32));
      float mn = fmaxf(m_[js], cm);
      scl[js] = __expf(m_[js] - mn);
      m_[js] = mn;
    }
    // rescale O accumulator (row lm = io*16 + quad*4 + reg; scale lives at lane quad*4+reg)
    #pragma unroll
    for (int io = 0; io < 2; io++)
      #pragma unroll
      for (int reg = 0; reg < 4; reg++) {
        float sb = __shfl(scl[io], quad * 4 + reg);
        #pragma unroll
        for (int jd = 0; jd < 4; jd++) acc_o[io][jd][reg] *= sb;
      }
    // P = exp(S - m), write bf16 to wave-private LDS [lm][kv]
    #pragma unroll
    for (int js = 0; js < 2; js++) {
      float cs = 0;
      #pragma unroll
      for (int i = 0; i < 4; i++)
        #pragma unroll
        for (int reg = 0; reg < 4; reg++) {
          float p = __expf(acc_s[i][js][reg] - m_[js]);
          cs += p;
          Pw[(js * 16 + l15) * 72 + i * 16 + quad * 4 + reg] = f2bu(p);
        }
      cs += __shfl_xor(cs, 16);
      cs += __shfl_xor(cs, 32);
      l_[js] = l_[js] * scl[js] + cs;
    }
    // ---- PV: O[32 lm][64 d] += P @ V_chunk ----
    #pragma unroll
    for (int kc2 = 0; kc2 < 2; kc2++) {
      bf16x8 pf[2], vf[4];
      #pragma unroll
      for (int io = 0; io < 2; io++)
        pf[io] = *(const bf16x8*)&Pw[(io * 16 + l15) * 72 + kc2 * 32 + quad * 8];
      #pragma unroll
      for (int jd = 0; jd < 4; jd++)
        vf[jd] = *(const bf16x8*)(vb + (size_t)(jd * 16 + l15) * 4096 + kvb + kc2 * 32 + quad * 8);
      #pragma unroll
      for (int io = 0; io < 2; io++)
        #pragma unroll
        for (int jd = 0; jd < 4; jd++)
          acc_o[io][jd] = __builtin_amdgcn_mfma_f32_16x16x32_bf16(pf[io], vf[jd], acc_o[io][jd], 0, 0, 0);
    }
  }
  // ---- 8-wave combine ----
  if (quad == 0) {
    mW[wid][l15] = m_[0]; mW[wid][16 + l15] = m_[1];
    lW[wid][l15] = l_[0]; lW[wid][16 + l15] = l_[1];
  }
  __syncthreads();
  #pragma unroll
  for (int io = 0; io < 2; io++)
    #pragma unroll
    for (int reg = 0; reg < 4; reg++) {
      int lm = io * 16 + quad * 4 + reg;
      float ms = mW[0][lm];
      #pragma unroll
      for (int w = 1; w < 8; w++) ms = fmaxf(ms, mW[w][lm]);
      float ls = 0;
      #pragma unroll
      for (int w = 0; w < 8; w++) ls += __expf(mW[w][lm] - ms) * lW[w][lm];
      float fac = __expf(mW[wid][lm] - ms) / ls;
      #pragma unroll
      for (int jd = 0; jd < 4; jd++)
        atomicAdd(&OW[lm][jd * 16 + l15], acc_o[io][jd][reg] * fac);
    }
  __syncthreads();
  {
    float4 o = ((float4*)OW)[tid];
    *(float4*)(a3v + (size_t)bh * 16384 + (size_t)lm0 * 64 + tid * 4) = o;
  }
}

// ---- FUSED sim1 + softmax + PV (P @ Wm) -> p1f f32 [32][4096][64] ----
// QBLK=32 rows per block. P (32x256) built in registers, split hi/lo bf16 into
// LDS (overlaying dead Ks buffer), then MFMA vs precomputed WmT hi/lo tiles.
// 3-term split => same 2^-17 error class as bmm64_mfma.
__global__ __launch_bounds__(256) void attn1_pv_kernel(
    const bf16* __restrict__ q, const bf16* __restrict__ klbf,
    const bf16* __restrict__ wmt_h, const bf16* __restrict__ wmt_l,
    float* __restrict__ p1f, int bh0) {
  __shared__ __align__(16) unsigned short Qs[32][72];
  __shared__ __align__(16) unsigned short Ks[256][72];   // Ph/Pl overlay after QK^T
  __shared__ __align__(16) unsigned short Wh[64][40];
  __shared__ __align__(16) unsigned short Wl[64][40];
  __shared__ float redm[4][32];
  __shared__ float reds[4][32];
  int tid = threadIdx.x;
  int bhl = blockIdx.y, bh = bh0 + bhl;
  int n0 = blockIdx.x * 32;
  const bf16* qb = q + ((size_t)bh * NN + n0) * 64;
  const bf16* kb = klbf + (size_t)bh * 16384;
  {
    int r = tid >> 3, s = (tid & 7) * 8;
    *(u16x8*)&Qs[r][s] = *(const u16x8*)(qb + (size_t)r * 64 + s);
  }
  {
    const bf16* src = kb + (size_t)tid * 64;
    #pragma unroll
    for (int s8 = 0; s8 < 8; s8++) *(u16x8*)&Ks[tid][s8 * 8] = *(const u16x8*)(src + s8 * 8);
  }
  __syncthreads();
  int wave = tid >> 6, lane = tid & 63, l15 = lane & 15, quad = lane >> 4;
  // ---- QK^T: 32 rows x 256 landmark cols (wave owns 64 cols) ----
  f32x4 acc[2][4] = {};
  #pragma unroll
  for (int kc = 0; kc < 64; kc += 32) {
    bf16x8 af[2], bfr[4];
    #pragma unroll
    for (int i = 0; i < 2; i++) af[i] = *(const bf16x8*)&Qs[i * 16 + l15][kc + quad * 8];
    #pragma unroll
    for (int j = 0; j < 4; j++) bfr[j] = *(const bf16x8*)&Ks[wave * 64 + j * 16 + l15][kc + quad * 8];
    #pragma unroll
    for (int i = 0; i < 2; i++)
      #pragma unroll
      for (int j = 0; j < 4; j++)
        acc[i][j] = __builtin_amdgcn_mfma_f32_16x16x32_bf16(af[i], bfr[j], acc[i][j], 0, 0, 0);
  }
  // ---- softmax over 256 cols ----
  float lm[2][4], ls[2][4], rinv[2][4];
  #pragma unroll
  for (int i = 0; i < 2; i++)
    #pragma unroll
    for (int reg = 0; reg < 4; reg++)
      lm[i][reg] = fmaxf(fmaxf(acc[i][0][reg], acc[i][1][reg]),
                         fmaxf(acc[i][2][reg], acc[i][3][reg]));
  #pragma unroll
  for (int off = 1; off < 16; off <<= 1)
    #pragma unroll
    for (int i = 0; i < 2; i++)
      #pragma unroll
      for (int reg = 0; reg < 4; reg++) lm[i][reg] = fmaxf(lm[i][reg], __shfl_xor(lm[i][reg], off));
  if (l15 == 0)
    #pragma unroll
    for (int i = 0; i < 2; i++)
      #pragma unroll
      for (int reg = 0; reg < 4; reg++) redm[wave][i * 16 + quad * 4 + reg] = lm[i][reg];
  __syncthreads();
  #pragma unroll
  for (int i = 0; i < 2; i++)
    #pragma unroll
    for (int reg = 0; reg < 4; reg++) {
      int r = i * 16 + quad * 4 + reg;
      rinv[i][reg] = fmaxf(fmaxf(redm[0][r], redm[1][r]), fmaxf(redm[2][r], redm[3][r]));
      ls[i][reg] = 0;
    }
  #pragma unroll
  for (int i = 0; i < 2; i++)
    #pragma unroll
    for (int j = 0; j < 4; j++)
      #pragma unroll
      for (int reg = 0; reg < 4; reg++) {
        float e = __expf(acc[i][j][reg] - rinv[i][reg]);
        acc[i][j][reg] = e;
        ls[i][reg] += e;
      }
  #pragma unroll
  for (int off = 1; off < 16; off <<= 1)
    #pragma unroll
    for (int i = 0; i < 2; i++)
      #pragma unroll
      for (int reg = 0; reg < 4; reg++) ls[i][reg] += __shfl_xor(ls[i][reg], off);
  if (l15 == 0)
    #pragma unroll
    for (int i = 0; i < 2; i++)
      #pragma unroll
      for (int reg = 0; reg < 4; reg++) reds[wave][i * 16 + quad * 4 + reg] = ls[i][reg];
  __syncthreads();
  #pragma unroll
  for (int i = 0; i < 2; i++)
    #pragma unroll
    for (int reg = 0; reg < 4; reg++) {
      int r = i * 16 + quad * 4 + reg;
      rinv[i][reg] = 1.0f / (reds[0][r] + reds[1][r] + reds[2][r] + reds[3][r]);
    }
  // ---- write P hi/lo bf16 into Ks overlay: Ph[32][264], Pl at +8448 u16 ----
  unsigned short* Pb = &Ks[0][0];
  #pragma unroll
  for (int i = 0; i < 2; i++)
    #pragma unroll
    for (int j = 0; j < 4; j++)
      #pragma unroll
      for (int reg = 0; reg < 4; reg++) {
        float pv = acc[i][j][reg] * rinv[i][reg];
        unsigned short h = f2bu(pv);
        int row = i * 16 + quad * 4 + reg;
        int col = wave * 64 + j * 16 + l15;
        Pb[row * 264 + col] = h;
        Pb[8448 + row * 264 + col] = f2bu(pv - u2f(h));
      }
  // ---- PV: out[32 r][64 d] = P @ Wm; wave: rows (wave&1)*16, d (wave>>1)*32 ----
  const bf16* whp = wmt_h + (size_t)bh * 16384;
  const bf16* wlp = wmt_l + (size_t)bh * 16384;
  int wd = tid >> 2, wc = (tid & 3) * 8;
  int iw = wave & 1, dw = (wave >> 1) * 32;
  f32x4 accp[2] = {};
  for (int kc = 0; kc < 256; kc += 32) {
    __syncthreads();   // protect Wh/Wl from overwrite while prior MFMA reads (and P-write on first iter)
    *(u16x8*)&Wh[wd][wc] = *(const u16x8*)(whp + (size_t)wd * 256 + kc + wc);
    *(u16x8*)&Wl[wd][wc] = *(const u16x8*)(wlp + (size_t)wd * 256 + kc + wc);
    __syncthreads();
    bf16x8 ah = *(const bf16x8*)&Pb[(iw * 16 + l15) * 264 + kc + quad * 8];
    bf16x8 al = *(const bf16x8*)&Pb[8448 + (iw * 16 + l15) * 264 + kc + quad * 8];
    #pragma unroll
    for (int jj = 0; jj < 2; jj++) {
      bf16x8 bh2 = *(const bf16x8*)&Wh[dw + jj * 16 + l15][quad * 8];
      bf16x8 bl2 = *(const bf16x8*)&Wl[dw + jj * 16 + l15][quad * 8];
      accp[jj] = __builtin_amdgcn_mfma_f32_16x16x32_bf16(ah, bh2, accp[jj], 0, 0, 0);
      accp[jj] = __builtin_amdgcn_mfma_f32_16x16x32_bf16(ah, bl2, accp[jj], 0, 0, 0);
      accp[jj] = __builtin_amdgcn_mfma_f32_16x16x32_bf16(al, bh2, accp[jj], 0, 0, 0);
    }
  }
  #pragma unroll
  for (int jj = 0; jj < 2; jj++)
    #pragma unroll
    for (int reg = 0; reg < 4; reg++) {
      int r = iw * 16 + quad * 4 + reg;
      int d = dw + jj * 16 + l15;
      int n = n0 + r;
      p1f[((size_t)bhl * NN + n) * 64 + d] = accp[jj][reg];
    }
}

// ---- depthwise conv (33) residual add: y = p1f32 + conv(v) ----
__global__ __launch_bounds__(256) void conv_add_kernel(
    const float* __restrict__ p1, const bf16* __restrict__ v,
    const void* __restrict__ wres, bf16* __restrict__ y, const int* __restrict__ dflag,
    int bh0) {
  __shared__ __align__(16) unsigned short Vs[96][64];
  int f = *dflag;
  int tid = threadIdx.x;
  int bhl = blockIdx.y, bh = bh0 + bhl;
  int n0 = blockIdx.x * 64;
  int h = bh & 3, b_ = bh >> 2;
  const bf16* vb = v + (size_t)bh * (NN * 64);
  for (int rr = tid; rr < 384; rr += 256) {
    int r = rr >> 2, s = (rr & 3) * 16;
    int n = n0 - 16 + r;
    if (n >= 0 && n < NN) {
      *(u16x8*)&Vs[r][s] = *(const u16x8*)(vb + (size_t)n * 64 + s);
      *(u16x8*)&Vs[r][s + 8] = *(const u16x8*)(vb + (size_t)n * 64 + s + 8);
    } else {
      u16x8 z = {};
      *(u16x8*)&Vs[r][s] = z; *(u16x8*)&Vs[r][s + 8] = z;
    }
  }
  float w33[33];
  #pragma unroll
  for (int kk = 0; kk < 33; kk++) w33[kk] = ldf(wres, h * 33 + kk, f);
  __syncthreads();
  int d = tid & 63, rb = tid >> 6;
  for (int ii = 0; ii < 16; ii++) {
    int nl = ii * 4 + rb;
    float cv = 0;
    #pragma unroll
    for (int kk = 0; kk < 33; kk++) cv += w33[kk] * u2f(Vs[nl + kk][d]);
    int n = n0 + nl;
    float pv = p1[((size_t)bhl * NN + n) * 64 + d];
    y[((size_t)b_ * NN + n) * 256 + h * 64 + d] = __float2bfloat16(pv + cv);
  }
}

extern "C" void kernel_launch(void* const* d_in, const int* in_sizes, int n_in,
                              void* d_out, int out_size, void* d_ws, size_t ws_size,
                              hipStream_t stream) {
  const void* x     = d_in[0];
  const void* ln_g  = d_in[1];
  const void* ln_b  = d_in[2];
  const void* w_qkv = d_in[3];
  const void* w_out = d_in[4];
  const void* b_out = d_in[5];
  const void* w_res = d_in[6];

  // ---- ws layout (~67.4 MiB) ----
  float* ws    = (float*)d_ws;
  float* gmax  = ws;                                   // 2 f
  int*   dflag = (int*)(ws + 2);                       // 1 int
  float* stats = ws + 256;                             // 65536 f
  bf16*  woutT = (bf16*)(stats + 65536);               // 131072 bf16
  float* qlf   = (float*)(stats + 65536 + 65536);      // 524288 f
  float* klf   = qlf + 524288;                         // 524288 f
  bf16*  qlbf  = (bf16*)(klf + 524288);                // 524288 bf16
  bf16*  klbf  = qlbf + 524288;                        // 524288 bf16
  float* a3v   = (float*)(klbf + 524288);              // 524288 f
  float* Wm    = a3v + 524288;                         // 524288 f
  float* a2    = Wm + 524288;                          // 2097152 f
  bf16*  q     = (bf16*)(a2 + 2097152);                // 8388608 bf16
  bf16*  k     = q + 8388608;                          // 8388608 bf16 (y alias)
  bf16*  v     = k + 8388608;                          // 8388608 bf16
  bf16*  y     = k;                                    // alias (k dead after sim3)
  bf16*  wmt_h = (bf16*)a2;                            // 1 MiB (a2 dead after pinv/Wm)
  bf16*  wmt_l = wmt_h + 524288;                       // 1 MiB

  // ---- d_out scratch (<= 32 MiB guaranteed) ----
  char* dob = (char*)d_out;
  bf16* wqkvT = (bf16*)dob;                            // phase A
  bf16* vTfull = (bf16*)dob;                           // 16 MiB (flash phase)
  float* W0   = (float*)dob;                           // pinv: 4 x 8 MiB
  float* W1   = (float*)(dob + (8u << 20));
  float* W2   = (float*)(dob + (16u << 20));
  float* W3   = (float*)(dob + (24u << 20));
  float* p1f  = (float*)dob;                           // 32 MiB (attn phase, W* dead)

  detect_kernel<<<1, 256, 0, stream>>>(x, dflag);
  hipMemsetAsync(gmax, 0, 2 * sizeof(float), stream);
  ln_stats_kernel<<<ROWS, 256, 0, stream>>>(x, stats, dflag);

  // weight transposes
  transpose_kernel<<<1536, 256, 0, stream>>>(w_qkv, wqkvT, 512, 768, 0, 0, dflag, -1);
  transpose_kernel<<<512, 256, 0, stream>>>(w_out, woutT, 256, 512, 0, 0, dflag, -1);

  // QKV (LN fused)
  gemm_qkv<<<dim3(256, 6), 256, 0, stream>>>(x, stats, ln_g, ln_b, wqkvT, q, k, v, dflag);

  // landmarks (f32 + bf16)
  landmark_kernel<<<2048, 256, 0, stream>>>(q, qlf, qlbf);
  landmark_kernel<<<2048, 256, 0, stream>>>(k, klf, klbf);

  // sim3 flash: vT (full, d_out) + fused softmax(q_l@k^T)@v -> a3v f32
  transpose_kernel<<<32768, 256, 0, stream>>>(v, vTfull, 4096, 64, 262144, 262144, dflag, 0);
  sim3_flash_kernel<<<dim3(8, 32), 512, 0, stream>>>(qlbf, k, vTfull, a3v);

  // a2 path (f32 landmarks) + pinv in d_out
  a2_kernel<<<8192, 256, 0, stream>>>(qlf, klf, a2);
  colsum_max_kernel<<<32, 256, 0, stream>>>(a2, gmax);
  zinit_kernel<<<8192, 256, 0, stream>>>(a2, gmax, W0);

  float* zi = W0; float* f1 = W1; float* f2 = W2; float* f3 = W3;
  for (int it = 0; it < 6; it++) {
    bmm64_mfma<<<dim3(32, 4, 4), 256, 0, stream>>>(a2, zi, f1, 256, 256, 65536, 65536, 65536, 0.f, 1.f, 0.f, 1.f);
    bmm64_mfma<<<dim3(32, 4, 4), 256, 0, stream>>>(f1, f1, f2, 256, 256, 65536, 65536, 65536, 15.f, -1.f, 7.f, -1.f);
    bmm64_mfma<<<dim3(32, 4, 4), 256, 0, stream>>>(f1, f2, f3, 256, 256, 65536, 65536, 65536, 13.f, -1.f, 0.f, 1.f);
    bmm64_mfma<<<dim3(32, 4, 4), 256, 0, stream>>>(zi, f3, f2, 256, 256, 65536, 65536, 65536, 0.f, 0.25f, 0.f, 1.f);
    float* nzi = f2; f2 = f1; f1 = zi; zi = nzi;
  }

  // Wm = z6 @ a3v -> f32 in ws (before d_out reuse)
  bmm64_mfma<<<dim3(32, 4, 1), 256, 0, stream>>>(zi, a3v, Wm, 64, 256, 65536, 16384, 16384, 0.f, 1.f, 0.f, 1.f);

  // WmT hi/lo bf16 (a2 region now dead)
  wmsplit_kernel<<<2048, 256, 0, stream>>>(Wm, wmt_h, wmt_l);

  // fused a1 softmax + PV (f32 p1f, full 32 bh) + conv residual
  attn1_pv_kernel<<<dim3(128, 32), 256, 0, stream>>>(q, klbf, wmt_h, wmt_l, p1f, 0);
  conv_add_kernel<<<dim3(64, 32), 256, 0, stream>>>(p1f, v, w_res, y, dflag, 0);

  // out = y @ w_out + b_out + x -> d_out (dtype-adaptive)
  gemm_bt<<<dim3(1, 256, 4), 256, 0, stream>>>(
      y, 256, 0, woutT, 256, 0,
      d_out, 512, 0, 512, 256, 4, 3, b_out, x, dflag);
}

// Round 7
// 850.067 us; speedup vs baseline: 2.0691x; 1.0632x over previous
//
#include <hip/hip_runtime.h>
#include <hip/hip_bf16.h>
#include <string.h>

typedef __hip_bfloat16 bf16;
typedef __attribute__((ext_vector_type(8))) __bf16 bf16x8;
typedef __attribute__((ext_vector_type(4))) float f32x4;
typedef __attribute__((ext_vector_type(8))) unsigned short u16x8;

#define NN 4096
#define DD 512
#define MM 256
#define ROWS 32768

__device__ __forceinline__ float b2f(bf16 x) { return __bfloat162float(x); }
__device__ __forceinline__ float u2f(unsigned short u) {
  return __uint_as_float(((unsigned int)u) << 16);
}
__device__ __forceinline__ unsigned short f2bu(float v) {
  bf16 h = __float2bfloat16(v);
  return *reinterpret_cast<unsigned short*>(&h);
}
// adaptive input load / output store (f==1 -> float32, f==0 -> bf16)
__device__ __forceinline__ float ldf(const void* p, size_t i, int f) {
  return f ? ((const float*)p)[i] : __bfloat162float(((const bf16*)p)[i]);
}
__device__ __forceinline__ void stf(void* p, size_t i, float v, int f) {
  if (f) ((float*)p)[i] = v;
  else ((bf16*)p)[i] = __float2bfloat16(v);
}

// ---- dtype detection ----
__global__ void detect_kernel(const void* x, int* flag) {
  __shared__ int red[256];
  int tid = threadIdx.x;
  const unsigned short* u = (const unsigned short*)x;
  int local = 0;
  for (int i = 0; i < 32; i++) {
    unsigned short e = (u[tid * 32 + i] >> 7) & 0xFF;
    if (e >= 0xC8) local++;
  }
  red[tid] = local; __syncthreads();
  #pragma unroll
  for (int s = 128; s > 0; s >>= 1) {
    if (tid < s) red[tid] += red[tid + s];
    __syncthreads();
  }
  if (tid == 0) *flag = (red[0] > 32) ? 1 : 0;
}

// ---- block reductions ----
__device__ __forceinline__ float bred_max(float v, float* red) {
  int tid = threadIdx.x;
  red[tid] = v; __syncthreads();
  #pragma unroll
  for (int s = 128; s > 0; s >>= 1) {
    if (tid < s) red[tid] = fmaxf(red[tid], red[tid + s]);
    __syncthreads();
  }
  float r = red[0]; __syncthreads();
  return r;
}
__device__ __forceinline__ float bred_sum(float v, float* red) {
  int tid = threadIdx.x;
  red[tid] = v; __syncthreads();
  #pragma unroll
  for (int s = 128; s > 0; s >>= 1) {
    if (tid < s) red[tid] += red[tid + s];
    __syncthreads();
  }
  float r = red[0]; __syncthreads();
  return r;
}

// ---- LayerNorm stats: 1 wave/row, shuffle-only reduce, vector loads ----
__global__ void ln_stats_kernel(const void* __restrict__ x, float* __restrict__ stats,
                                const int* dflag) {
  int f = *dflag;
  int wave = threadIdx.x >> 6, lane = threadIdx.x & 63;
  int row = blockIdx.x * 4 + wave;
  size_t base = (size_t)row * DD + lane * 8;
  float v[8];
  if (f) {
    const float* xp = (const float*)x + base;
    float4 a = *(const float4*)xp;
    float4 b = *(const float4*)(xp + 4);
    v[0] = a.x; v[1] = a.y; v[2] = a.z; v[3] = a.w;
    v[4] = b.x; v[5] = b.y; v[6] = b.z; v[7] = b.w;
  } else {
    const bf16* xp = (const bf16*)x + base;
    u16x8 t = *(const u16x8*)xp;
    #pragma unroll
    for (int e = 0; e < 8; e++) v[e] = u2f(t[e]);
  }
  float s = 0, s2 = 0;
  #pragma unroll
  for (int e = 0; e < 8; e++) { s += v[e]; s2 += v[e] * v[e]; }
  #pragma unroll
  for (int off = 1; off < 64; off <<= 1) {
    s += __shfl_xor(s, off);
    s2 += __shfl_xor(s2, off);
  }
  if (lane == 0) {
    float mean = s * (1.0f / DD);
    float var = s2 * (1.0f / DD) - mean * mean;
    stats[row * 2] = mean;
    stats[row * 2 + 1] = rsqrtf(var + 1e-5f);
  }
}

// ---- generic transpose -> bf16 out: out[b][c][r] = in[b][r][c] ----
__global__ void transpose_kernel(const void* __restrict__ in, bf16* __restrict__ out,
                                 int R, int Cc, long sIn, long sOut,
                                 const int* dflag, int ovr) {
  int f = (ovr >= 0) ? ovr : *dflag;
  size_t o = (size_t)blockIdx.x * 256 + threadIdx.x;
  size_t per = (size_t)R * Cc;
  size_t b = o / per, rem = o % per;
  size_t c = rem / R, r = rem % R;
  out[b * sOut + c * (size_t)R + r] = __float2bfloat16(ldf(in, b * sIn + r * (size_t)Cc + c, f));
}

// ---- QKV GEMM: MFMA, LN fused on A-stage (vectorized), vectorized scatter epilogue ----
__global__ __launch_bounds__(256) void gemm_qkv(
    const void* __restrict__ x, const float* __restrict__ stats,
    const void* __restrict__ g, const void* __restrict__ bb,
    const bf16* __restrict__ wT,  // [768][512]
    bf16* __restrict__ q, bf16* __restrict__ k, bf16* __restrict__ v,
    const int* __restrict__ dflag) {
  __shared__ __align__(16) unsigned short As[128][40];
  __shared__ __align__(16) unsigned short Bs[128][40];
  __shared__ __align__(16) float gls[512];
  __shared__ __align__(16) float bls[512];
  int f = *dflag;
  int tid = threadIdx.x;
  // one-time g/bb stage into LDS
  {
    int c0 = tid, c1 = tid + 256;
    gls[c0] = ldf(g, c0, f);  gls[c1] = ldf(g, c1, f);
    bls[c0] = ldf(bb, c0, f); bls[c1] = ldf(bb, c1, f);
  }
  int m0 = blockIdx.x * 128, n0 = blockIdx.y * 128;
  int sr = tid >> 1, sh = (tid & 1) * 16;
  int wave = tid >> 6, lane = tid & 63;
  int wm = (wave & 1) * 64, wn = (wave >> 1) * 64;
  int l15 = lane & 15, quad = lane >> 4;
  int r = m0 + sr;
  float mu = stats[r * 2], rs = stats[r * 2 + 1];   // loop-invariant
  const float* xf = (const float*)x + (size_t)r * DD;
  const bf16*  xb = (const bf16*)x  + (size_t)r * DD;
  __syncthreads();  // gls/bls ready
  f32x4 acc[4][4] = {};
  for (int k0 = 0; k0 < 512; k0 += 32) {
    {
      // vectorized x load
      float xv[16];
      if (f) {
        const float* src = xf + k0 + sh;
        float4 t0 = *(const float4*)(src);
        float4 t1 = *(const float4*)(src + 4);
        float4 t2 = *(const float4*)(src + 8);
        float4 t3 = *(const float4*)(src + 12);
        xv[0] = t0.x; xv[1] = t0.y; xv[2]  = t0.z; xv[3]  = t0.w;
        xv[4] = t1.x; xv[5] = t1.y; xv[6]  = t1.z; xv[7]  = t1.w;
        xv[8] = t2.x; xv[9] = t2.y; xv[10] = t2.z; xv[11] = t2.w;
        xv[12] = t3.x; xv[13] = t3.y; xv[14] = t3.z; xv[15] = t3.w;
      } else {
        const bf16* src = xb + k0 + sh;
        u16x8 t0 = *(const u16x8*)(src);
        u16x8 t1 = *(const u16x8*)(src + 8);
        #pragma unroll
        for (int e = 0; e < 8; e++) { xv[e] = u2f(t0[e]); xv[8 + e] = u2f(t1[e]); }
      }
      // LN as 2 FMA/elem: a = rs*g;  out = x*a + (bb - mu*a)
      float gv[16], bv[16];
      {
        const float* gp = &gls[k0 + sh];
        const float* bp = &bls[k0 + sh];
        #pragma unroll
        for (int e4 = 0; e4 < 4; e4++) {
          float4 gt = *(const float4*)(gp + e4 * 4);
          float4 bt = *(const float4*)(bp + e4 * 4);
          gv[e4 * 4 + 0] = gt.x; gv[e4 * 4 + 1] = gt.y; gv[e4 * 4 + 2] = gt.z; gv[e4 * 4 + 3] = gt.w;
          bv[e4 * 4 + 0] = bt.x; bv[e4 * 4 + 1] = bt.y; bv[e4 * 4 + 2] = bt.z; bv[e4 * 4 + 3] = bt.w;
        }
      }
      u16x8 w0, w1;
      #pragma unroll
      for (int e = 0; e < 8; e++) {
        float a0 = rs * gv[e];
        float a1 = rs * gv[e + 8];
        w0[e] = f2bu(xv[e] * a0 + (bv[e] - mu * a0));
        w1[e] = f2bu(xv[e + 8] * a1 + (bv[e + 8] - mu * a1));
      }
      *(u16x8*)&As[sr][sh] = w0;
      *(u16x8*)&As[sr][sh + 8] = w1;
    }
    {
      const bf16* src = wT + (size_t)(n0 + sr) * 512 + k0 + sh;
      *(u16x8*)&Bs[sr][sh] = *(const u16x8*)src;
      *(u16x8*)&Bs[sr][sh + 8] = *(const u16x8*)(src + 8);
    }
    __syncthreads();
    bf16x8 af[4], bfr[4];
    #pragma unroll
    for (int i = 0; i < 4; i++) af[i] = *(const bf16x8*)&As[wm + i * 16 + l15][quad * 8];
    #pragma unroll
    for (int j = 0; j < 4; j++) bfr[j] = *(const bf16x8*)&Bs[wn + j * 16 + l15][quad * 8];
    #pragma unroll
    for (int i = 0; i < 4; i++)
      #pragma unroll
      for (int j = 0; j < 4; j++)
        acc[i][j] = __builtin_amdgcn_mfma_f32_16x16x32_bf16(af[i], bfr[j], acc[i][j], 0, 0, 0);
    __syncthreads();
  }
  // ---- vectorized epilogue: LDS-transpose 16-row passes, u16x8 stores ----
  float* eps = (float*)&As[0][0];   // [16][132] f32 overlay (8448 B <= 10240 B)
  int half = wave & 1;
  int er = tid >> 4, ec8 = (tid & 15) * 8;
  for (int p = 0; p < 8; p++) {
    if (half == (p >> 2)) {
      int i = p & 3;
      #pragma unroll
      for (int j = 0; j < 4; j++)
        #pragma unroll
        for (int reg = 0; reg < 4; reg++)
          eps[(quad * 4 + reg) * 132 + wn + j * 16 + l15] = acc[i][j][reg];
    }
    __syncthreads();
    {
      int row = m0 + p * 16 + er;
      int c = n0 + ec8;
      int which = c >> 8, h = (c >> 6) & 3, d = c & 63;
      int b_ = row >> 12, n = row & 4095;
      const float* src = &eps[er * 132 + ec8];
      float scale = (which == 0) ? 0.125f : 1.0f;
      u16x8 o;
      #pragma unroll
      for (int e = 0; e < 8; e++) o[e] = f2bu(src[e] * scale);
      bf16* dst = (which == 0) ? q : (which == 1) ? k : v;
      *(u16x8*)(dst + ((size_t)(b_ * 4 + h) * NN + n) * 64 + d) = o;
    }
    __syncthreads();
  }
}

// ---- generic batched MFMA GEMM: C = A[M x K] @ Bt[N x K]^T ----
// modes: 0=f32 store, 1=bf16 store, 2=f32 atomicAdd (split-K), 3=bias+residual+dtype store
// mode 3 uses a vectorized LDS-transpose epilogue (requires full 128-col tiles, ldC%8==0).
__global__ __launch_bounds__(256) void gemm_bt(
    const bf16* __restrict__ A, long ldA, long sA,
    const bf16* __restrict__ Bt, long ldB, long sB,
    void* __restrict__ C, long ldC, long sC,
    int N, int kLen, int nTiles, int mode,
    const void* __restrict__ bias, const void* __restrict__ resid,
    const int* __restrict__ dflag) {
  __shared__ __align__(16) unsigned short As[128][40];
  __shared__ __align__(16) unsigned short Bs[128][40];
  int tid = threadIdx.x;
  int b = blockIdx.x;
  int m0 = blockIdx.y * 128;
  int nt = blockIdx.z % nTiles, ks = blockIdx.z / nTiles;
  int n0 = nt * 128;
  long k0b = (long)ks * kLen;
  const bf16* Ab = A + (size_t)b * sA;
  const bf16* Bb = Bt + (size_t)b * sB;
  int sr = tid >> 1, sh = (tid & 1) * 16;
  int wave = tid >> 6, lane = tid & 63;
  int wm = (wave & 1) * 64, wn = (wave >> 1) * 64;
  int l15 = lane & 15, quad = lane >> 4;
  f32x4 acc[4][4] = {};
  for (int kc = 0; kc < kLen; kc += 32) {
    long k0 = k0b + kc;
    {
      const bf16* src = Ab + (size_t)(m0 + sr) * ldA + k0 + sh;
      *(u16x8*)&As[sr][sh] = *(const u16x8*)src;
      *(u16x8*)&As[sr][sh + 8] = *(const u16x8*)(src + 8);
    }
    if (n0 + sr < N) {
      const bf16* src = Bb + (size_t)(n0 + sr) * ldB + k0 + sh;
      *(u16x8*)&Bs[sr][sh] = *(const u16x8*)src;
      *(u16x8*)&Bs[sr][sh + 8] = *(const u16x8*)(src + 8);
    } else {
      u16x8 z = {};
      *(u16x8*)&Bs[sr][sh] = z;
      *(u16x8*)&Bs[sr][sh + 8] = z;
    }
    __syncthreads();
    bf16x8 af[4], bfr[4];
    #pragma unroll
    for (int i = 0; i < 4; i++) af[i] = *(const bf16x8*)&As[wm + i * 16 + l15][quad * 8];
    #pragma unroll
    for (int j = 0; j < 4; j++) bfr[j] = *(const bf16x8*)&Bs[wn + j * 16 + l15][quad * 8];
    #pragma unroll
    for (int i = 0; i < 4; i++)
      #pragma unroll
      for (int j = 0; j < 4; j++)
        acc[i][j] = __builtin_amdgcn_mfma_f32_16x16x32_bf16(af[i], bfr[j], acc[i][j], 0, 0, 0);
    __syncthreads();
  }
  if (mode == 3) {
    // ---- vectorized epilogue: bias + residual + dtype store, 8-wide per thread ----
    int f = *dflag;
    float* eps = (float*)&As[0][0];   // [16][132] f32 overlay
    int half = wave & 1;
    int er = tid >> 4, ec8 = (tid & 15) * 8;
    int colb = n0 + ec8;
    float bias8[8];
    #pragma unroll
    for (int e = 0; e < 8; e++) bias8[e] = ldf(bias, colb + e, f);
    for (int p = 0; p < 8; p++) {
      if (half == (p >> 2)) {
        int i = p & 3;
        #pragma unroll
        for (int j = 0; j < 4; j++)
          #pragma unroll
          for (int reg = 0; reg < 4; reg++)
            eps[(quad * 4 + reg) * 132 + wn + j * 16 + l15] = acc[i][j][reg];
      }
      __syncthreads();
      {
        int row = m0 + p * 16 + er;
        size_t off = (size_t)row * ldC + colb;
        const float* src = &eps[er * 132 + ec8];
        if (f) {
          float* Cp = (float*)C + off;
          const float* xr = (const float*)resid + off;
          float4 r0 = *(const float4*)xr;
          float4 r1 = *(const float4*)(xr + 4);
          float4 o0, o1;
          o0.x = src[0] + bias8[0] + r0.x; o0.y = src[1] + bias8[1] + r0.y;
          o0.z = src[2] + bias8[2] + r0.z; o0.w = src[3] + bias8[3] + r0.w;
          o1.x = src[4] + bias8[4] + r1.x; o1.y = src[5] + bias8[5] + r1.y;
          o1.z = src[6] + bias8[6] + r1.z; o1.w = src[7] + bias8[7] + r1.w;
          *(float4*)Cp = o0;
          *(float4*)(Cp + 4) = o1;
        } else {
          bf16* Cp = (bf16*)C + off;
          const bf16* xr = (const bf16*)resid + off;
          u16x8 rv = *(const u16x8*)xr;
          u16x8 o;
          #pragma unroll
          for (int e = 0; e < 8; e++) o[e] = f2bu(src[e] + bias8[e] + u2f(rv[e]));
          *(u16x8*)Cp = o;
        }
      }
      __syncthreads();
    }
    return;
  }
  #pragma unroll
  for (int i = 0; i < 4; i++)
    #pragma unroll
    for (int j = 0; j < 4; j++)
      #pragma unroll
      for (int reg = 0; reg < 4; reg++) {
        int row = m0 + wm + i * 16 + quad * 4 + reg;
        int col = n0 + wn + j * 16 + l15;
        if (col < N) {
          float val = acc[i][j][reg];
          size_t off = (size_t)row * ldC + col;
          if (mode == 0) (((float*)C) + (size_t)b * sC)[off] = val;
          else if (mode == 1) (((bf16*)C) + (size_t)b * sC)[off] = __float2bfloat16(val);
          else atomicAdd(((float*)C) + (size_t)b * sC + off, val);
        }
      }
}

// ---- landmark means: bf16 src -> f32 dst (for a2/pinv) AND bf16 dst (for MFMA) ----
__global__ void landmark_kernel(const bf16* __restrict__ src, float* __restrict__ dstf,
                                bf16* __restrict__ dstb) {
  int idx = blockIdx.x * 256 + threadIdx.x;  // 524288
  int d = idx & 63, j = (idx >> 6) & 255, bh = idx >> 14;
  const bf16* s = src + ((size_t)bh * NN + j * 16) * 64 + d;
  float a = 0;
  #pragma unroll
  for (int i = 0; i < 16; i++) a += b2f(s[i * 64]);
  a *= (1.0f / 16);
  dstf[idx] = a;
  dstb[idx] = __float2bfloat16(a);
}

// ---- a2 = softmax(ql @ kl^T) f32, f32 inputs (pinv-sensitive path) ----
__global__ void a2_kernel(const float* __restrict__ ql, const float* __restrict__ kl,
                          float* __restrict__ a2) {
  __shared__ float qs[64];
  __shared__ float red[256];
  int bh = blockIdx.x >> 8, i = blockIdx.x & 255, tid = threadIdx.x;
  if (tid < 64) qs[tid] = ql[((size_t)bh * MM + i) * 64 + tid];
  __syncthreads();
  const float* kr = kl + ((size_t)bh * MM + tid) * 64;
  float s = 0;
  #pragma unroll
  for (int d = 0; d < 64; d++) s += qs[d] * kr[d];
  float mx = bred_max(s, red);
  float e = __expf(s - mx);
  float sm = bred_sum(e, red);
  a2[((size_t)bh * MM + i) * MM + tid] = e / sm;
}

// ---- max over column-sums of a2 (row-sums of softmax are exactly 1, skipped) ----
// 32 blocks (one per bh); thread j owns column j (coalesced); 1 atomic per block.
__global__ void colsum_max_kernel(const float* __restrict__ a2, float* __restrict__ gmax) {
  __shared__ float red[256];
  int bh = blockIdx.x, tid = threadIdx.x;
  const float* base = a2 + (size_t)bh * MM * MM + tid;
  float s0 = 0, s1 = 0, s2 = 0, s3 = 0, s4 = 0, s5 = 0, s6 = 0, s7 = 0;
  for (int i = 0; i < 256; i += 8) {
    s0 += base[(size_t)(i + 0) * MM];
    s1 += base[(size_t)(i + 1) * MM];
    s2 += base[(size_t)(i + 2) * MM];
    s3 += base[(size_t)(i + 3) * MM];
    s4 += base[(size_t)(i + 4) * MM];
    s5 += base[(size_t)(i + 5) * MM];
    s6 += base[(size_t)(i + 6) * MM];
    s7 += base[(size_t)(i + 7) * MM];
  }
  float tot = ((s0 + s1) + (s2 + s3)) + ((s4 + s5) + (s6 + s7));
  float mx = bred_max(tot, red);
  if (tid == 0) atomicMax((int*)gmax + 1, __float_as_int(mx));
}

__global__ void zinit_kernel(const float* __restrict__ a2, const float* __restrict__ gmax,
                             float* __restrict__ z) {
  int idx = blockIdx.x * 256 + threadIdx.x;
  int j = idx & 255, i = (idx >> 8) & 255, bh = idx >> 16;
  float scale = 1.0f / gmax[1];   // max(row-sums) == 1 exactly (softmax rows)
  z[idx] = a2[((size_t)bh * MM + j) * MM + i] * scale;
}

// ---- MFMA split-bf16 batched 64x64-tile GEMM (drop-in replacement for bmm64) ----
// C = alpha*I + beta*(A @ (gbA*I + gbB*B)); A [M][Kk] f32 row-major (ld=Kk),
// B [Kk][Nn] f32 row-major (ld=Nn). Split-3 bf16 MFMA: A=Ah+Al, B'=Bh+Bl,
// acc += Ah*Bh + Ah*Bl + Al*Bh  (dropped Al*Bl ~2^-18 rel => f32-class accuracy).
// B transposed into LDS at stage time (scalar b16 writes).
// NOTE (historical): a round-6 "Nn-guard" here was an LDS-OOB bug; do not reintroduce.
__global__ __launch_bounds__(256) void bmm64_mfma(
    const float* __restrict__ A, const float* __restrict__ B_,
    float* __restrict__ C,
    int Nn, int Kk, long sA, long sB, long sC,
    float alpha, float beta, float gbA, float gbB) {
  __shared__ __align__(16) unsigned short Ah[64][40];
  __shared__ __align__(16) unsigned short Al[64][40];
  __shared__ __align__(16) unsigned short Bh[64][40];
  __shared__ __align__(16) unsigned short Bl[64][40];
  int bh = blockIdx.x;
  int row0 = blockIdx.y * 64, col0 = blockIdx.z * 64;
  const float* Ab = A + (size_t)bh * sA;
  const float* Bb = B_ + (size_t)bh * sB;
  int tid = threadIdx.x;
  int wave = tid >> 6, lane = tid & 63, l15 = lane & 15, quad = lane >> 4;
  int wm = (wave & 1) * 32, wn = (wave >> 1) * 32;
  int ar2 = tid >> 2, kq = (tid & 3) * 8;   // A-stage: 64 rows x 32 k
  int kr = tid >> 3, n8 = (tid & 7) * 8;    // B-stage: 32 k-rows x 64 n
  f32x4 acc[2][2] = {};
  for (int k0 = 0; k0 < Kk; k0 += 32) {
    {
      const float* src = Ab + (size_t)(row0 + ar2) * Kk + k0 + kq;
      u16x8 hi, lo;
      #pragma unroll
      for (int e = 0; e < 8; e++) {
        float a = src[e];
        unsigned short h = f2bu(a);
        hi[e] = h;
        lo[e] = f2bu(a - u2f(h));
      }
      *(u16x8*)&Ah[ar2][kq] = hi;
      *(u16x8*)&Al[ar2][kq] = lo;
    }
    {
      const float* src = Bb + (size_t)(k0 + kr) * Nn + col0 + n8;
      int kk = k0 + kr;
      #pragma unroll
      for (int e = 0; e < 8; e++) {
        float b = gbB * src[e];
        if (kk == col0 + n8 + e) b += gbA;
        unsigned short h = f2bu(b);
        Bh[n8 + e][kr] = h;
        Bl[n8 + e][kr] = f2bu(b - u2f(h));
      }
    }
    __syncthreads();
    bf16x8 ah[2], al[2], bhf[2], blf[2];
    #pragma unroll
    for (int i = 0; i < 2; i++) {
      ah[i]  = *(const bf16x8*)&Ah[wm + i * 16 + l15][quad * 8];
      al[i]  = *(const bf16x8*)&Al[wm + i * 16 + l15][quad * 8];
      bhf[i] = *(const bf16x8*)&Bh[wn + i * 16 + l15][quad * 8];
      blf[i] = *(const bf16x8*)&Bl[wn + i * 16 + l15][quad * 8];
    }
    #pragma unroll
    for (int i = 0; i < 2; i++)
      #pragma unroll
      for (int j = 0; j < 2; j++) {
        acc[i][j] = __builtin_amdgcn_mfma_f32_16x16x32_bf16(ah[i], bhf[j], acc[i][j], 0, 0, 0);
        acc[i][j] = __builtin_amdgcn_mfma_f32_16x16x32_bf16(ah[i], blf[j], acc[i][j], 0, 0, 0);
        acc[i][j] = __builtin_amdgcn_mfma_f32_16x16x32_bf16(al[i], bhf[j], acc[i][j], 0, 0, 0);
      }
    __syncthreads();
  }
  #pragma unroll
  for (int i = 0; i < 2; i++)
    #pragma unroll
    for (int j = 0; j < 2; j++)
      #pragma unroll
      for (int reg = 0; reg < 4; reg++) {
        int r = row0 + wm + i * 16 + quad * 4 + reg;
        int cc = col0 + wn + j * 16 + l15;
        C[(size_t)bh * sC + (size_t)r * Nn + cc] = alpha * (r == cc) + beta * acc[i][j][reg];
      }
}

// ---- Wm split: f32 [bh][c=256][d=64] -> transposed hi/lo bf16 [bh][d][c] ----
__global__ void wmsplit_kernel(const float* __restrict__ Wm, bf16* __restrict__ h,
                               bf16* __restrict__ l) {
  int o = blockIdx.x * 256 + threadIdx.x;  // 524288
  int c = o & 255, d = (o >> 8) & 63, bh = o >> 14;
  float w = Wm[(((size_t)bh << 8) + c) * 64 + d];
  unsigned short hh = f2bu(w);
  h[o] = __float2bfloat16(w);  // == hh bits
  l[o] = __float2bfloat16(w - u2f(hh));
}

// ---- FUSED flash sim3: a3v = softmax(q_l @ k^T) @ v, per (lm-tile 32, bh) ----
// 8 waves, each owns 512 kv; chunk=64 kv. S^T = mfma(K-direct-global, Q_lds);
// online softmax in-register (lm on l15 axis => quad-shuffle reductions only);
// P -> wave-private LDS bf16 -> PV A-frags; V^T B-frags direct from global vT.
// Barrier-free main loop; 8-wave m/l/O combine via LDS at the end.
__global__ __launch_bounds__(512) void sim3_flash_kernel(
    const bf16* __restrict__ qlbf, const bf16* __restrict__ k,
    const bf16* __restrict__ vT, float* __restrict__ a3v) {
  __shared__ __align__(16) unsigned short Qs[32][72];
  __shared__ __align__(16) unsigned short Pl[8][32][72];
  __shared__ __align__(16) float OW[32][64];
  __shared__ float mW[8][32];
  __shared__ float lW[8][32];
  int tid = threadIdx.x;
  int lt = blockIdx.x;    // lm-tile 0..7
  int bh = blockIdx.y;    // 0..31
  int lm0 = lt * 32;
  if (tid < 256) {
    int r = tid >> 3, s = (tid & 7) * 8;
    *(u16x8*)&Qs[r][s] = *(const u16x8*)(qlbf + ((size_t)bh * 256 + lm0 + r) * 64 + s);
  }
  {
    float4 z = {};
    ((float4*)OW)[tid] = z;   // 512 * 16B = 8192B
  }
  __syncthreads();
  int wid = tid >> 6, lane = tid & 63, l15 = lane & 15, quad = lane >> 4;
  const bf16* kb = k + (size_t)bh * (NN * 64);
  const bf16* vb = vT + (size_t)bh * 262144;
  unsigned short* Pw = &Pl[wid][0][0];
  float m_[2] = {-1e30f, -1e30f};
  float l_[2] = {0.f, 0.f};
  f32x4 acc_o[2][4] = {};
  for (int ch = 0; ch < 8; ch++) {
    int kvb = wid * 512 + ch * 64;
    // ---- S^T[64 kv][32 lm] = K_chunk @ Q^T ----
    f32x4 acc_s[4][2] = {};
    #pragma unroll
    for (int kc = 0; kc < 2; kc++) {
      bf16x8 kf[4], qf[2];
      #pragma unroll
      for (int i = 0; i < 4; i++)
        kf[i] = *(const bf16x8*)(kb + (size_t)(kvb + i * 16 + l15) * 64 + kc * 32 + quad * 8);
      #pragma unroll
      for (int j = 0; j < 2; j++)
        qf[j] = *(const bf16x8*)&Qs[j * 16 + l15][kc * 32 + quad * 8];
      #pragma unroll
      for (int i = 0; i < 4; i++)
        #pragma unroll
        for (int j = 0; j < 2; j++)
          acc_s[i][j] = __builtin_amdgcn_mfma_f32_16x16x32_bf16(kf[i], qf[j], acc_s[i][j], 0, 0, 0);
    }
    // ---- online softmax per lm (= l15 within j_s tile) ----
    float scl[2];
    #pragma unroll
    for (int js = 0; js < 2; js++) {
      float cm = acc_s[0][js][0];
      #pragma unroll
      for (int i = 0; i < 4; i++)
        #pragma unroll
        for (int reg = 0; reg < 4; reg++) cm = fmaxf(cm, acc_s[i][js][reg]);
      cm = fmaxf(cm, __shfl_xor(cm, 16));
      cm = fmaxf(cm, __shfl_xor(cm, 32));
      float mn = fmaxf(m_[js], cm);
      scl[js] = __expf(m_[js] - mn);
      m_[js] = mn;
    }
    // rescale O accumulator (row lm = io*16 + quad*4 + reg; scale lives at lane quad*4+reg)
    #pragma unroll
    for (int io = 0; io < 2; io++)
      #pragma unroll
      for (int reg = 0; reg < 4; reg++) {
        float sb = __shfl(scl[io], quad * 4 + reg);
        #pragma unroll
        for (int jd = 0; jd < 4; jd++) acc_o[io][jd][reg] *= sb;
      }
    // P = exp(S - m), write bf16 to wave-private LDS [lm][kv]
    #pragma unroll
    for (int js = 0; js < 2; js++) {
      float cs = 0;
      #pragma unroll
      for (int i = 0; i < 4; i++)
        #pragma unroll
        for (int reg = 0; reg < 4; reg++) {
          float p = __expf(acc_s[i][js][reg] - m_[js]);
          cs += p;
          Pw[(js * 16 + l15) * 72 + i * 16 + quad * 4 + reg] = f2bu(p);
        }
      cs += __shfl_xor(cs, 16);
      cs += __shfl_xor(cs, 32);
      l_[js] = l_[js] * scl[js] + cs;
    }
    // ---- PV: O[32 lm][64 d] += P @ V_chunk ----
    #pragma unroll
    for (int kc2 = 0; kc2 < 2; kc2++) {
      bf16x8 pf[2], vf[4];
      #pragma unroll
      for (int io = 0; io < 2; io++)
        pf[io] = *(const bf16x8*)&Pw[(io * 16 + l15) * 72 + kc2 * 32 + quad * 8];
      #pragma unroll
      for (int jd = 0; jd < 4; jd++)
        vf[jd] = *(const bf16x8*)(vb + (size_t)(jd * 16 + l15) * 4096 + kvb + kc2 * 32 + quad * 8);
      #pragma unroll
      for (int io = 0; io < 2; io++)
        #pragma unroll
        for (int jd = 0; jd < 4; jd++)
          acc_o[io][jd] = __builtin_amdgcn_mfma_f32_16x16x32_bf16(pf[io], vf[jd], acc_o[io][jd], 0, 0, 0);
    }
  }
  // ---- 8-wave combine ----
  if (quad == 0) {
    mW[wid][l15] = m_[0]; mW[wid][16 + l15] = m_[1];
    lW[wid][l15] = l_[0]; lW[wid][16 + l15] = l_[1];
  }
  __syncthreads();
  #pragma unroll
  for (int io = 0; io < 2; io++)
    #pragma unroll
    for (int reg = 0; reg < 4; reg++) {
      int lm = io * 16 + quad * 4 + reg;
      float ms = mW[0][lm];
      #pragma unroll
      for (int w = 1; w < 8; w++) ms = fmaxf(ms, mW[w][lm]);
      float ls = 0;
      #pragma unroll
      for (int w = 0; w < 8; w++) ls += __expf(mW[w][lm] - ms) * lW[w][lm];
      float fac = __expf(mW[wid][lm] - ms) / ls;
      #pragma unroll
      for (int jd = 0; jd < 4; jd++)
        atomicAdd(&OW[lm][jd * 16 + l15], acc_o[io][jd][reg] * fac);
    }
  __syncthreads();
  {
    float4 o = ((float4*)OW)[tid];
    *(float4*)(a3v + (size_t)bh * 16384 + (size_t)lm0 * 64 + tid * 4) = o;
  }
}

// ---- FUSED sim1 + softmax + PV (P @ Wm) -> p1f f32 [32][4096][64] ----
// QBLK=32 rows per block. P (32x256) built in registers, split hi/lo bf16 into
// LDS (overlaying dead Ks buffer), then MFMA vs precomputed WmT hi/lo tiles.
// 3-term split => same 2^-17 error class as bmm64_mfma.
__global__ __launch_bounds__(256) void attn1_pv_kernel(
    const bf16* __restrict__ q, const bf16* __restrict__ klbf,
    const bf16* __restrict__ wmt_h, const bf16* __restrict__ wmt_l,
    float* __restrict__ p1f, int bh0) {
  __shared__ __align__(16) unsigned short Qs[32][72];
  __shared__ __align__(16) unsigned short Ks[256][72];   // Ph/Pl overlay after QK^T
  __shared__ __align__(16) unsigned short Wh[64][40];
  __shared__ __align__(16) unsigned short Wl[64][40];
  __shared__ float redm[4][32];
  __shared__ float reds[4][32];
  int tid = threadIdx.x;
  int bhl = blockIdx.y, bh = bh0 + bhl;
  int n0 = blockIdx.x * 32;
  const bf16* qb = q + ((size_t)bh * NN + n0) * 64;
  const bf16* kb = klbf + (size_t)bh * 16384;
  {
    int r = tid >> 3, s = (tid & 7) * 8;
    *(u16x8*)&Qs[r][s] = *(const u16x8*)(qb + (size_t)r * 64 + s);
  }
  {
    const bf16* src = kb + (size_t)tid * 64;
    #pragma unroll
    for (int s8 = 0; s8 < 8; s8++) *(u16x8*)&Ks[tid][s8 * 8] = *(const u16x8*)(src + s8 * 8);
  }
  __syncthreads();
  int wave = tid >> 6, lane = tid & 63, l15 = lane & 15, quad = lane >> 4;
  // ---- QK^T: 32 rows x 256 landmark cols (wave owns 64 cols) ----
  f32x4 acc[2][4] = {};
  #pragma unroll
  for (int kc = 0; kc < 64; kc += 32) {
    bf16x8 af[2], bfr[4];
    #pragma unroll
    for (int i = 0; i < 2; i++) af[i] = *(const bf16x8*)&Qs[i * 16 + l15][kc + quad * 8];
    #pragma unroll
    for (int j = 0; j < 4; j++) bfr[j] = *(const bf16x8*)&Ks[wave * 64 + j * 16 + l15][kc + quad * 8];
    #pragma unroll
    for (int i = 0; i < 2; i++)
      #pragma unroll
      for (int j = 0; j < 4; j++)
        acc[i][j] = __builtin_amdgcn_mfma_f32_16x16x32_bf16(af[i], bfr[j], acc[i][j], 0, 0, 0);
  }
  // ---- softmax over 256 cols ----
  float lm[2][4], ls[2][4], rinv[2][4];
  #pragma unroll
  for (int i = 0; i < 2; i++)
    #pragma unroll
    for (int reg = 0; reg < 4; reg++)
      lm[i][reg] = fmaxf(fmaxf(acc[i][0][reg], acc[i][1][reg]),
                         fmaxf(acc[i][2][reg], acc[i][3][reg]));
  #pragma unroll
  for (int off = 1; off < 16; off <<= 1)
    #pragma unroll
    for (int i = 0; i < 2; i++)
      #pragma unroll
      for (int reg = 0; reg < 4; reg++) lm[i][reg] = fmaxf(lm[i][reg], __shfl_xor(lm[i][reg], off));
  if (l15 == 0)
    #pragma unroll
    for (int i = 0; i < 2; i++)
      #pragma unroll
      for (int reg = 0; reg < 4; reg++) redm[wave][i * 16 + quad * 4 + reg] = lm[i][reg];
  __syncthreads();
  #pragma unroll
  for (int i = 0; i < 2; i++)
    #pragma unroll
    for (int reg = 0; reg < 4; reg++) {
      int r = i * 16 + quad * 4 + reg;
      rinv[i][reg] = fmaxf(fmaxf(redm[0][r], redm[1][r]), fmaxf(redm[2][r], redm[3][r]));
      ls[i][reg] = 0;
    }
  #pragma unroll
  for (int i = 0; i < 2; i++)
    #pragma unroll
    for (int j = 0; j < 4; j++)
      #pragma unroll
      for (int reg = 0; reg < 4; reg++) {
        float e = __expf(acc[i][j][reg] - rinv[i][reg]);
        acc[i][j][reg] = e;
        ls[i][reg] += e;
      }
  #pragma unroll
  for (int off = 1; off < 16; off <<= 1)
    #pragma unroll
    for (int i = 0; i < 2; i++)
      #pragma unroll
      for (int reg = 0; reg < 4; reg++) ls[i][reg] += __shfl_xor(ls[i][reg], off);
  if (l15 == 0)
    #pragma unroll
    for (int i = 0; i < 2; i++)
      #pragma unroll
      for (int reg = 0; reg < 4; reg++) reds[wave][i * 16 + quad * 4 + reg] = ls[i][reg];
  __syncthreads();
  #pragma unroll
  for (int i = 0; i < 2; i++)
    #pragma unroll
    for (int reg = 0; reg < 4; reg++) {
      int r = i * 16 + quad * 4 + reg;
      rinv[i][reg] = 1.0f / (reds[0][r] + reds[1][r] + reds[2][r] + reds[3][r]);
    }
  // ---- write P hi/lo bf16 into Ks overlay: Ph[32][264], Pl at +8448 u16 ----
  unsigned short* Pb = &Ks[0][0];
  #pragma unroll
  for (int i = 0; i < 2; i++)
    #pragma unroll
    for (int j = 0; j < 4; j++)
      #pragma unroll
      for (int reg = 0; reg < 4; reg++) {
        float pv = acc[i][j][reg] * rinv[i][reg];
        unsigned short h = f2bu(pv);
        int row = i * 16 + quad * 4 + reg;
        int col = wave * 64 + j * 16 + l15;
        Pb[row * 264 + col] = h;
        Pb[8448 + row * 264 + col] = f2bu(pv - u2f(h));
      }
  // ---- PV: out[32 r][64 d] = P @ Wm; wave: rows (wave&1)*16, d (wave>>1)*32 ----
  const bf16* whp = wmt_h + (size_t)bh * 16384;
  const bf16* wlp = wmt_l + (size_t)bh * 16384;
  int wd = tid >> 2, wc = (tid & 3) * 8;
  int iw = wave & 1, dw = (wave >> 1) * 32;
  f32x4 accp[2] = {};
  for (int kc = 0; kc < 256; kc += 32) {
    __syncthreads();   // protect Wh/Wl from overwrite while prior MFMA reads (and P-write on first iter)
    *(u16x8*)&Wh[wd][wc] = *(const u16x8*)(whp + (size_t)wd * 256 + kc + wc);
    *(u16x8*)&Wl[wd][wc] = *(const u16x8*)(wlp + (size_t)wd * 256 + kc + wc);
    __syncthreads();
    bf16x8 ah = *(const bf16x8*)&Pb[(iw * 16 + l15) * 264 + kc + quad * 8];
    bf16x8 al = *(const bf16x8*)&Pb[8448 + (iw * 16 + l15) * 264 + kc + quad * 8];
    #pragma unroll
    for (int jj = 0; jj < 2; jj++) {
      bf16x8 bh2 = *(const bf16x8*)&Wh[dw + jj * 16 + l15][quad * 8];
      bf16x8 bl2 = *(const bf16x8*)&Wl[dw + jj * 16 + l15][quad * 8];
      accp[jj] = __builtin_amdgcn_mfma_f32_16x16x32_bf16(ah, bh2, accp[jj], 0, 0, 0);
      accp[jj] = __builtin_amdgcn_mfma_f32_16x16x32_bf16(ah, bl2, accp[jj], 0, 0, 0);
      accp[jj] = __builtin_amdgcn_mfma_f32_16x16x32_bf16(al, bh2, accp[jj], 0, 0, 0);
    }
  }
  #pragma unroll
  for (int jj = 0; jj < 2; jj++)
    #pragma unroll
    for (int reg = 0; reg < 4; reg++) {
      int r = iw * 16 + quad * 4 + reg;
      int d = dw + jj * 16 + l15;
      int n = n0 + r;
      p1f[((size_t)bhl * NN + n) * 64 + d] = accp[jj][reg];
    }
}

// ---- depthwise conv (33) residual add: y = p1f32 + conv(v) ----
__global__ __launch_bounds__(256) void conv_add_kernel(
    const float* __restrict__ p1, const bf16* __restrict__ v,
    const void* __restrict__ wres, bf16* __restrict__ y, const int* __restrict__ dflag,
    int bh0) {
  __shared__ __align__(16) unsigned short Vs[96][64];
  int f = *dflag;
  int tid = threadIdx.x;
  int bhl = blockIdx.y, bh = bh0 + bhl;
  int n0 = blockIdx.x * 64;
  int h = bh & 3, b_ = bh >> 2;
  const bf16* vb = v + (size_t)bh * (NN * 64);
  for (int rr = tid; rr < 384; rr += 256) {
    int r = rr >> 2, s = (rr & 3) * 16;
    int n = n0 - 16 + r;
    if (n >= 0 && n < NN) {
      *(u16x8*)&Vs[r][s] = *(const u16x8*)(vb + (size_t)n * 64 + s);
      *(u16x8*)&Vs[r][s + 8] = *(const u16x8*)(vb + (size_t)n * 64 + s + 8);
    } else {
      u16x8 z = {};
      *(u16x8*)&Vs[r][s] = z; *(u16x8*)&Vs[r][s + 8] = z;
    }
  }
  float w33[33];
  #pragma unroll
  for (int kk = 0; kk < 33; kk++) w33[kk] = ldf(wres, h * 33 + kk, f);
  __syncthreads();
  int d = tid & 63, rb = tid >> 6;
  for (int ii = 0; ii < 16; ii++) {
    int nl = ii * 4 + rb;
    float cv = 0;
    #pragma unroll
    for (int kk = 0; kk < 33; kk++) cv += w33[kk] * u2f(Vs[nl + kk][d]);
    int n = n0 + nl;
    float pv = p1[((size_t)bhl * NN + n) * 64 + d];
    y[((size_t)b_ * NN + n) * 256 + h * 64 + d] = __float2bfloat16(pv + cv);
  }
}

extern "C" void kernel_launch(void* const* d_in, const int* in_sizes, int n_in,
                              void* d_out, int out_size, void* d_ws, size_t ws_size,
                              hipStream_t stream) {
  const void* x     = d_in[0];
  const void* ln_g  = d_in[1];
  const void* ln_b  = d_in[2];
  const void* w_qkv = d_in[3];
  const void* w_out = d_in[4];
  const void* b_out = d_in[5];
  const void* w_res = d_in[6];

  // ---- ws layout (~67.4 MiB) ----
  float* ws    = (float*)d_ws;
  float* gmax  = ws;                                   // 2 f
  int*   dflag = (int*)(ws + 2);                       // 1 int
  float* stats = ws + 256;                             // 65536 f
  bf16*  woutT = (bf16*)(stats + 65536);               // 131072 bf16
  float* qlf   = (float*)(stats + 65536 + 65536);      // 524288 f
  float* klf   = qlf + 524288;                         // 524288 f
  bf16*  qlbf  = (bf16*)(klf + 524288);                // 524288 bf16
  bf16*  klbf  = qlbf + 524288;                        // 524288 bf16
  float* a3v   = (float*)(klbf + 524288);              // 524288 f
  float* Wm    = a3v + 524288;                         // 524288 f
  float* a2    = Wm + 524288;                          // 2097152 f
  bf16*  q     = (bf16*)(a2 + 2097152);                // 8388608 bf16
  bf16*  k     = q + 8388608;                          // 8388608 bf16 (y alias)
  bf16*  v     = k + 8388608;                          // 8388608 bf16
  bf16*  y     = k;                                    // alias (k dead after sim3)
  bf16*  wmt_h = (bf16*)a2;                            // 1 MiB (a2 dead after pinv/Wm)
  bf16*  wmt_l = wmt_h + 524288;                       // 1 MiB

  // ---- d_out scratch (<= 32 MiB guaranteed) ----
  char* dob = (char*)d_out;
  bf16* wqkvT = (bf16*)dob;                            // phase A
  bf16* vTfull = (bf16*)dob;                           // 16 MiB (flash phase)
  float* W0   = (float*)dob;                           // pinv: 4 x 8 MiB
  float* W1   = (float*)(dob + (8u << 20));
  float* W2   = (float*)(dob + (16u << 20));
  float* W3   = (float*)(dob + (24u << 20));
  float* p1f  = (float*)dob;                           // 32 MiB (attn phase, W* dead)

  detect_kernel<<<1, 256, 0, stream>>>(x, dflag);
  hipMemsetAsync(gmax, 0, 2 * sizeof(float), stream);
  ln_stats_kernel<<<8192, 256, 0, stream>>>(x, stats, dflag);

  // weight transposes
  transpose_kernel<<<1536, 256, 0, stream>>>(w_qkv, wqkvT, 512, 768, 0, 0, dflag, -1);
  transpose_kernel<<<512, 256, 0, stream>>>(w_out, woutT, 256, 512, 0, 0, dflag, -1);

  // QKV (LN fused)
  gemm_qkv<<<dim3(256, 6), 256, 0, stream>>>(x, stats, ln_g, ln_b, wqkvT, q, k, v, dflag);

  // landmarks (f32 + bf16)
  landmark_kernel<<<2048, 256, 0, stream>>>(q, qlf, qlbf);
  landmark_kernel<<<2048, 256, 0, stream>>>(k, klf, klbf);

  // sim3 flash: vT (full, d_out) + fused softmax(q_l@k^T)@v -> a3v f32
  transpose_kernel<<<32768, 256, 0, stream>>>(v, vTfull, 4096, 64, 262144, 262144, dflag, 0);
  sim3_flash_kernel<<<dim3(8, 32), 512, 0, stream>>>(qlbf, k, vTfull, a3v);

  // a2 path (f32 landmarks) + pinv in d_out
  a2_kernel<<<8192, 256, 0, stream>>>(qlf, klf, a2);
  colsum_max_kernel<<<32, 256, 0, stream>>>(a2, gmax);
  zinit_kernel<<<8192, 256, 0, stream>>>(a2, gmax, W0);

  float* zi = W0; float* f1 = W1; float* f2 = W2; float* f3 = W3;
  for (int it = 0; it < 6; it++) {
    bmm64_mfma<<<dim3(32, 4, 4), 256, 0, stream>>>(a2, zi, f1, 256, 256, 65536, 65536, 65536, 0.f, 1.f, 0.f, 1.f);
    bmm64_mfma<<<dim3(32, 4, 4), 256, 0, stream>>>(f1, f1, f2, 256, 256, 65536, 65536, 65536, 15.f, -1.f, 7.f, -1.f);
    bmm64_mfma<<<dim3(32, 4, 4), 256, 0, stream>>>(f1, f2, f3, 256, 256, 65536, 65536, 65536, 13.f, -1.f, 0.f, 1.f);
    bmm64_mfma<<<dim3(32, 4, 4), 256, 0, stream>>>(zi, f3, f2, 256, 256, 65536, 65536, 65536, 0.f, 0.25f, 0.f, 1.f);
    float* nzi = f2; f2 = f1; f1 = zi; zi = nzi;
  }

  // Wm = z6 @ a3v -> f32 in ws (before d_out reuse)
  bmm64_mfma<<<dim3(32, 4, 1), 256, 0, stream>>>(zi, a3v, Wm, 64, 256, 65536, 16384, 16384, 0.f, 1.f, 0.f, 1.f);

  // WmT hi/lo bf16 (a2 region now dead)
  wmsplit_kernel<<<2048, 256, 0, stream>>>(Wm, wmt_h, wmt_l);

  // fused a1 softmax + PV (f32 p1f, full 32 bh) + conv residual
  attn1_pv_kernel<<<dim3(128, 32), 256, 0, stream>>>(q, klbf, wmt_h, wmt_l, p1f, 0);
  conv_add_kernel<<<dim3(64, 32), 256, 0, stream>>>(p1f, v, w_res, y, dflag, 0);

  // out = y @ w_out + b_out + x -> d_out (dtype-adaptive)
  gemm_bt<<<dim3(1, 256, 4), 256, 0, stream>>>(
      y, 256, 0, woutT, 256, 0,
      d_out, 512, 0, 512, 256, 4, 3, b_out, x, dflag);
}